// Round 3
// baseline (4158.849 us; speedup 1.0000x reference)
//
#include <hip/hip_runtime.h>
#include <hip/hip_bf16.h>

// ---------------------------------------------------------------------------
// MwAN forward, MI355X. B=8, QL=128, PL=256, AL=10, E=128, EMB=256.
// Inputs fp32 (per reference jnp.float32); internal compute fp32 in d_ws;
// output fp32 (reference logits are float32).
// ---------------------------------------------------------------------------

#define BB 8
#define QL 128
#define PL 256
#define AL 10
#define EE 128
#define EMB 256
#define G3 384   // 3*H gates
#define HH 128   // hidden

// ---- ws layout (in floats) ----
#define O_XPASS   ((size_t)0)        // (8,256,256)
#define O_XQUERY  ((size_t)524288)   // (8,128,256)
#define O_XCAND   ((size_t)786432)   // 3 x (8,10,256), chunk 20480
#define O_PREQ    ((size_t)847872)   // (2,8,256,384)
#define O_PREP    ((size_t)2420736)  // (2,8,128,384)
#define O_PREA    ((size_t)3207168)  // 3 x (2,8,10,384), chunk 61440
#define O_PREG    ((size_t)3391488)  // (2,8,128,384)
#define O_HQ      ((size_t)4177920)  // (8,256,256)
#define O_HP      ((size_t)4702208)  // (8,128,256)
#define O_HCAND   ((size_t)4964352)  // 3 x (8,10,256), chunk 20480
#define O_AEMB    ((size_t)5025792)  // (8,3,256)
#define O_AQ      ((size_t)5031936)  // (8,256,128)
#define O_AP      ((size_t)5294080)  // (8,128,128)
#define O_BQ      ((size_t)5425152)  // (8,256,256)
#define O_AGG     ((size_t)5949440)  // (8,128,1536)
#define O_AGGREP  ((size_t)7522304)  // (8,128,256)
#define O_CQ      ((size_t)7784448)  // (8,256,128)
#define O_GP      ((size_t)8046592)  // (8,128,128)
#define O_RQ      ((size_t)8177664)  // (8,256)
#define O_RQW     ((size_t)8179712)  // (8,128)
#define O_RP      ((size_t)8180736)  // (8,256)

__device__ __forceinline__ float tanh_fast(float x){
    x = fminf(fmaxf(x, -20.f), 20.f);
    float e = __expf(2.f * x);
    return (e - 1.f) / (e + 1.f);
}
__device__ __forceinline__ float sig_fast(float x){
    return 1.f / (1.f + __expf(-x));
}

// softmax over sc[0..255] (callers pad unused entries with -1e30), 256 lanes work
__device__ __forceinline__ void softmax256(float* sc, float* red, int tid){
    float v = (tid < 256) ? sc[tid] : -1e30f;
    if (tid < 256) red[tid] = v;
    __syncthreads();
    for (int s = 128; s > 0; s >>= 1){
        if (tid < s) red[tid] = fmaxf(red[tid], red[tid + s]);
        __syncthreads();
    }
    float m = red[0];
    __syncthreads();
    float e = (tid < 256) ? __expf(v - m) : 0.f;
    if (tid < 256) red[tid] = e;
    __syncthreads();
    for (int s = 128; s > 0; s >>= 1){
        if (tid < s) red[tid] += red[tid + s];
        __syncthreads();
    }
    float inv = 1.f / red[0];
    __syncthreads();
    if (tid < 256) sc[tid] = e * inv;
    __syncthreads();
}

// ---------------------------------------------------------------------------
// embedding gather: out[i,:] = emb[ids[i],:]
__global__ __launch_bounds__(256) void k_gather(const int* __restrict__ ids,
                                                const float* __restrict__ emb,
                                                float* __restrict__ out){
    int i = blockIdx.x, e = threadIdx.x;
    int id = ids[i];
    out[(size_t)i * EMB + e] = emb[(size_t)id * EMB + e];
}

// ---------------------------------------------------------------------------
// C[m,n] = sum_k A[m,k]*B[n,k] + bias[n];  all fp32.
// blockIdx.z indexes direction (B += z*strideB etc).
__global__ __launch_bounds__(256) void k_gemm_nt(const float* __restrict__ A,
                                                 const float* __restrict__ Bm,
                                                 const float* __restrict__ bias,
                                                 float* __restrict__ C,
                                                 int M, int N, int K,
                                                 long long strideB, long long strideC,
                                                 long long strideBias){
    int z = blockIdx.z;
    Bm += (size_t)z * strideB;
    C  += (size_t)z * strideC;
    if (bias) bias += (size_t)z * strideBias;
    __shared__ float As[16][17], Bs[16][17];
    int tx = threadIdx.x, ty = threadIdx.y;
    int row = blockIdx.y * 16 + ty;
    int col = blockIdx.x * 16 + tx;
    float acc = 0.f;
    for (int k0 = 0; k0 < K; k0 += 16){
        As[ty][tx] = (row < M) ? A[(size_t)row * K + k0 + tx] : 0.f;
        int brow = blockIdx.x * 16 + ty;
        Bs[ty][tx] = (brow < N) ? Bm[(size_t)brow * K + k0 + tx] : 0.f;
        __syncthreads();
        #pragma unroll
        for (int kk = 0; kk < 16; ++kk) acc += As[ty][kk] * Bs[tx][kk];
        __syncthreads();
    }
    if (row < M && col < N){
        float b = bias ? bias[col] : 0.f;
        C[(size_t)row * N + col] = acc + b;
    }
}

// ---------------------------------------------------------------------------
// GRU scan. One workgroup per (chunk, b, dir). 768 threads: g=tid>>1, half=tid&1.
// pre: (2, 8, T, 384) fp32 (+ chunk), Whh: (2,384,128) fp32, bhh: (2,384) fp32.
// out: (8, T, 256) fp32 (+ chunk), fwd half at [0:128], bwd at [128:256].
__global__ __launch_bounds__(768) void k_gru_scan(const float* __restrict__ pre,
                                                  const float* __restrict__ Whh,
                                                  const float* __restrict__ bhh,
                                                  float* __restrict__ out,
                                                  int T, int preChunk, int outChunk){
    int idx = blockIdx.x;
    int c = idx >> 4, bd = idx & 15, b = bd >> 1, d = bd & 1;
    pre += (size_t)c * preChunk;
    out += (size_t)c * outChunk;

    int tid = threadIdx.x;
    int g = tid >> 1, half = tid & 1;

    // preload this thread's half-row of Whh into registers
    float wf[64];
    {
        const float4* wp = (const float4*)(Whh + ((size_t)d * G3 + g) * HH + half * 64);
        #pragma unroll
        for (int j = 0; j < 16; ++j){
            float4 u = wp[j];
            wf[j*4+0] = u.x; wf[j*4+1] = u.y; wf[j*4+2] = u.z; wf[j*4+3] = u.w;
        }
    }
    float bg = bhh[d * G3 + g];

    __shared__ __align__(16) float h_s[HH];
    __shared__ float r_s[HH], z_s[HH];
    if (tid < HH) h_s[tid] = 0.f;
    __syncthreads();

    const float* ptB = pre + ((size_t)d * BB + b) * (size_t)T * G3;
    float* ob = out + ((size_t)b * T) * 256 + d * HH;

    for (int step = 0; step < T; ++step){
        int t = d ? (T - 1 - step) : step;
        // gh = Whh[g,:] . h  + bhh[g]
        float a0=0.f, a1=0.f, a2=0.f, a3=0.f;
        const float4* hp4 = (const float4*)&h_s[half * 64];
        #pragma unroll
        for (int j = 0; j < 16; ++j){
            float4 hv = hp4[j];
            a0 += wf[j*4+0] * hv.x;  a1 += wf[j*4+1] * hv.y;
            a2 += wf[j*4+2] * hv.z;  a3 += wf[j*4+3] * hv.w;
        }
        float acc = (a0 + a1) + (a2 + a3);
        acc += __shfl_xor(acc, 1);
        float gh = acc + bg;

        const float* pt = ptB + (size_t)t * G3;
        float pv = 0.f;
        if (half == 0) pv = pt[g];
        if (half == 0){
            if (g < HH)            r_s[g]       = sig_fast(pv + gh);
            else if (g < 2 * HH)   z_s[g - HH]  = sig_fast(pv + gh);
        }
        __syncthreads();
        if (half == 0 && g >= 2 * HH){
            int j = g - 2 * HH;
            float n  = tanh_fast(pv + r_s[j] * gh);
            float z  = z_s[j];
            float hn = n + z * (h_s[j] - n);   // (1-z)n + z h
            h_s[j] = hn;
            ob[(size_t)t * 256 + j] = hn;
        }
        __syncthreads();
    }
}

// ---------------------------------------------------------------------------
// candidate attention pooling: a_emb[b,c,:] = sum_t softmax_t(h.a_att) * h
__global__ __launch_bounds__(256) void k_cand_att(const float* __restrict__ h,
                                                  const float* __restrict__ a_att,
                                                  float* __restrict__ a_emb){
    int c = blockIdx.x / BB, b = blockIdx.x % BB, tid = threadIdx.x;
    __shared__ float att[256], sc[AL], sw[AL];
    att[tid] = a_att[tid];
    __syncthreads();
    const float* hb = h + (size_t)c * (BB*AL*256) + (size_t)b * (AL*256);
    if (tid < AL){
        float s = 0.f;
        for (int e = 0; e < 256; ++e) s += hb[tid*256 + e] * att[e];
        sc[tid] = s;
    }
    __syncthreads();
    if (tid == 0){
        float m = -1e30f;
        for (int t = 0; t < AL; ++t) m = fmaxf(m, sc[t]);
        float s = 0.f;
        for (int t = 0; t < AL; ++t){ sw[t] = __expf(sc[t] - m); s += sw[t]; }
        float inv = 1.f / s;
        for (int t = 0; t < AL; ++t) sw[t] *= inv;
    }
    __syncthreads();
    float o = 0.f;
    for (int t = 0; t < AL; ++t) o += sw[t] * hb[t*256 + tid];
    a_emb[((size_t)b*3 + c) * 256 + tid] = o;
}

// ---------------------------------------------------------------------------
// concat attention: score[p] = sum_e vc[e]*tanh(Aq[b,p,e]+Ap[b,q,e]); qtc -> agg+512
__global__ __launch_bounds__(256) void k_att_c(const float* __restrict__ Aq,
                                               const float* __restrict__ Ap,
                                               const float* __restrict__ vc,
                                               const float* __restrict__ hq,
                                               float* __restrict__ agg){
    int b = blockIdx.x >> 7, q = blockIdx.x & 127, tid = threadIdx.x;
    __shared__ float apv[EE], vcv[EE], sc[256], red[256];
    if (tid < EE){
        apv[tid] = Ap[((size_t)b*QL + q)*EE + tid];
        vcv[tid] = vc[tid];
    }
    __syncthreads();
    const float* aqp = Aq + ((size_t)b*PL + tid)*EE;
    float s = 0.f;
    #pragma unroll 4
    for (int e = 0; e < EE; ++e) s += vcv[e] * tanh_fast(aqp[e] + apv[e]);
    sc[tid] = s;
    __syncthreads();
    softmax256(sc, red, tid);
    float o = 0.f;
    const float* hqb = hq + (size_t)b*PL*256;
    for (int p = 0; p < PL; ++p) o += sc[p] * hqb[(size_t)p*256 + tid];
    agg[((size_t)b*QL + q)*1536 + 512 + tid] = o;
}

// bilinear attention: score[p] = hp[b,q,:] . Bq[b,p,:]; qtb -> agg+1024
__global__ __launch_bounds__(256) void k_att_b(const float* __restrict__ Bq,
                                               const float* __restrict__ hp,
                                               const float* __restrict__ hq,
                                               float* __restrict__ agg){
    int b = blockIdx.x >> 7, q = blockIdx.x & 127, tid = threadIdx.x;
    __shared__ float xq[256], sc[256], red[256];
    xq[tid] = hp[((size_t)b*QL + q)*256 + tid];
    __syncthreads();
    const float* bq = Bq + ((size_t)b*PL + tid)*256;
    float s = 0.f;
    #pragma unroll 4
    for (int e = 0; e < 256; ++e) s += xq[e] * bq[e];
    sc[tid] = s;
    __syncthreads();
    softmax256(sc, red, tid);
    float o = 0.f;
    const float* hqb = hq + (size_t)b*PL*256;
    for (int p = 0; p < PL; ++p) o += sc[p] * hqb[(size_t)p*256 + tid];
    agg[((size_t)b*QL + q)*1536 + 1024 + tid] = o;
}

// ---------------------------------------------------------------------------
// dot/minus/self attention: score[p] = v . tanh(W @ (kv_p op x_q)); qt -> agg+outOff
// mode 0: elementwise product, mode 1: difference. 512 threads: e=tid>>2, qt=tid&3.
__global__ __launch_bounds__(512) void k_att_dms(const float* __restrict__ kv, int P,
                                                 const float* __restrict__ W,
                                                 const float* __restrict__ v,
                                                 const float* __restrict__ hp,
                                                 int mode, int outOff,
                                                 float* __restrict__ agg){
    int b = blockIdx.x >> 7, q = blockIdx.x & 127, tid = threadIdx.x;
    int e = tid >> 2, qt = tid & 3;
    __shared__ __align__(16) float prod[256];
    __shared__ float xq[256], sc[256], red[256], wpart[8];

    float wf[64];
    {
        const float4* wp = (const float4*)(W + (size_t)e*256 + qt*64);
        #pragma unroll
        for (int j = 0; j < 16; ++j){
            float4 u = wp[j];
            wf[j*4+0] = u.x; wf[j*4+1] = u.y; wf[j*4+2] = u.z; wf[j*4+3] = u.w;
        }
    }
    float ve = v[e];

    if (tid < 256){
        xq[tid] = hp[((size_t)b*QL + q)*256 + tid];
        sc[tid] = -1e30f;
    }
    __syncthreads();

    const float* kvb = kv + (size_t)b*P*256;
    for (int p = 0; p < P; ++p){
        if (tid < 256){
            float t = kvb[(size_t)p*256 + tid];
            prod[tid] = mode ? (t - xq[tid]) : (t * xq[tid]);
        }
        __syncthreads();
        const float4* pr4 = (const float4*)&prod[qt*64];
        float a0=0.f, a1=0.f, a2=0.f, a3=0.f;
        #pragma unroll
        for (int j = 0; j < 16; ++j){
            float4 pv = pr4[j];
            a0 += wf[j*4+0]*pv.x;  a1 += wf[j*4+1]*pv.y;
            a2 += wf[j*4+2]*pv.z;  a3 += wf[j*4+3]*pv.w;
        }
        float acc = (a0+a1)+(a2+a3);
        acc += __shfl_xor(acc, 1);
        acc += __shfl_xor(acc, 2);
        float sval = (qt == 0) ? tanh_fast(acc) * ve : 0.f;
        #pragma unroll
        for (int off = 4; off < 64; off <<= 1) sval += __shfl_xor(sval, off);
        if ((tid & 63) == 0) wpart[tid >> 6] = sval;
        __syncthreads();
        if (tid == 0){
            float s = 0.f;
            #pragma unroll
            for (int i = 0; i < 8; ++i) s += wpart[i];
            sc[p] = s;
        }
        __syncthreads();
    }
    softmax256(sc, red, tid);
    if (tid < 256){
        float o = 0.f;
        for (int p = 0; p < P; ++p) o += sc[p] * kvb[(size_t)p*256 + tid];
        agg[((size_t)b*QL + q)*1536 + outOff + tid] = o;
    }
}

// copy hp into agg[...,0:256]
__global__ __launch_bounds__(256) void k_copy_hp(const float* __restrict__ hp,
                                                 float* __restrict__ agg){
    int i = blockIdx.x, tid = threadIdx.x;
    agg[(size_t)i*1536 + tid] = hp[(size_t)i*256 + tid];
}

// ---------------------------------------------------------------------------
// rq[b,:] = sum_p softmax_p( vq . tanh(Cq[b,p,:]) ) * hq[b,p,:]
__global__ __launch_bounds__(256) void k_q_att(const float* __restrict__ Cq,
                                               const float* __restrict__ vq,
                                               const float* __restrict__ hq,
                                               float* __restrict__ rq){
    int b = blockIdx.x, tid = threadIdx.x;
    __shared__ float vv[EE], sc[256], red[256];
    if (tid < EE) vv[tid] = vq[tid];
    __syncthreads();
    const float* cb = Cq + ((size_t)b*PL + tid)*EE;
    float s = 0.f;
    #pragma unroll 4
    for (int e = 0; e < EE; ++e) s += vv[e] * tanh_fast(cb[e]);
    sc[tid] = s;
    __syncthreads();
    softmax256(sc, red, tid);
    float o = 0.f;
    const float* hqb = hq + (size_t)b*PL*256;
    for (int p = 0; p < PL; ++p) o += sc[p] * hqb[(size_t)p*256 + tid];
    rq[(size_t)b*256 + tid] = o;
}

// rp[b,:] = sum_q softmax_q( vp . (Gp[b,q,:] + rqW[b,:]) ) * agg_rep[b,q,:]
__global__ __launch_bounds__(256) void k_p_att(const float* __restrict__ Gp,
                                               const float* __restrict__ vp,
                                               const float* __restrict__ rqW,
                                               const float* __restrict__ agg_rep,
                                               float* __restrict__ rp){
    int b = blockIdx.x, tid = threadIdx.x;
    __shared__ float vv[EE], rw[EE], sc[256], red[256];
    if (tid < EE){
        vv[tid] = vp[tid];
        rw[tid] = rqW[(size_t)b*EE + tid];
    }
    if (tid >= 128) sc[tid] = -1e30f;
    __syncthreads();
    if (tid < QL){
        const float* gp = Gp + ((size_t)b*QL + tid)*EE;
        float s = 0.f;
        for (int e = 0; e < EE; ++e) s += vv[e] * (gp[e] + rw[e]);
        sc[tid] = s;
    }
    __syncthreads();
    softmax256(sc, red, tid);
    float o = 0.f;
    const float* ab = agg_rep + (size_t)b*QL*256;
    for (int q = 0; q < QL; ++q) o += sc[q] * ab[(size_t)q*256 + tid];
    rp[(size_t)b*256 + tid] = o;
}

// enc = leaky_relu(Wpred @ rp); logits[b,c] = a_emb[b,c,:] . enc  (fp32 out)
__global__ __launch_bounds__(256) void k_final(const float* __restrict__ rp,
                                               const float* __restrict__ Wpred,
                                               const float* __restrict__ a_emb,
                                               float* __restrict__ out){
    int b = blockIdx.x, tid = threadIdx.x;
    __shared__ float rpv[256], enc[256];
    rpv[tid] = rp[(size_t)b*256 + tid];
    __syncthreads();
    const float* wr = Wpred + (size_t)tid*256;
    float s = 0.f;
    #pragma unroll 4
    for (int e = 0; e < 256; ++e) s += wr[e] * rpv[e];
    enc[tid] = (s > 0.f) ? s : 0.01f * s;
    __syncthreads();
    if (tid < 3){
        const float* ae = a_emb + ((size_t)b*3 + tid)*256;
        float o = 0.f;
        for (int e = 0; e < 256; ++e) o += ae[e] * enc[e];
        out[b*3 + tid] = o;
    }
}

// ---------------------------------------------------------------------------
extern "C" void kernel_launch(void* const* d_in, const int* in_sizes, int n_in,
                              void* d_out, int out_size, void* d_ws, size_t ws_size,
                              hipStream_t stream){
    const float* emb   = (const float*)d_in[0];
    const float* a_att = (const float*)d_in[1];
    const float* Wc1   = (const float*)d_in[2];
    const float* Wc2   = (const float*)d_in[3];
    const float* vc    = (const float*)d_in[4];
    const float* Wb    = (const float*)d_in[5];
    const float* Wd    = (const float*)d_in[6];
    const float* vd    = (const float*)d_in[7];
    const float* Wm    = (const float*)d_in[8];
    const float* vm    = (const float*)d_in[9];
    const float* Ws    = (const float*)d_in[10];
    const float* vs    = (const float*)d_in[11];
    const float* Wq    = (const float*)d_in[12];
    const float* vq    = (const float*)d_in[13];
    const float* Wp1   = (const float*)d_in[14];
    const float* Wp2   = (const float*)d_in[15];
    const float* vp    = (const float*)d_in[16];
    const float* Wpred = (const float*)d_in[17];
    const float* q_Wih = (const float*)d_in[18];
    const float* q_Whh = (const float*)d_in[19];
    const float* q_bih = (const float*)d_in[20];
    const float* q_bhh = (const float*)d_in[21];
    const float* p_Wih = (const float*)d_in[22];
    const float* p_Whh = (const float*)d_in[23];
    const float* p_bih = (const float*)d_in[24];
    const float* p_bhh = (const float*)d_in[25];
    const float* a_Wih = (const float*)d_in[26];
    const float* a_Whh = (const float*)d_in[27];
    const float* a_bih = (const float*)d_in[28];
    const float* a_bhh = (const float*)d_in[29];
    const float* g_Wih = (const float*)d_in[30];
    const float* g_Whh = (const float*)d_in[31];
    const float* g_bih = (const float*)d_in[32];
    const float* g_bhh = (const float*)d_in[33];
    const int* query   = (const int*)d_in[34];
    const int* passage = (const int*)d_in[35];
    const int* cneg    = (const int*)d_in[36];
    const int* cpos    = (const int*)d_in[37];
    const int* cna     = (const int*)d_in[38];

    float* ws = (float*)d_ws;
    dim3 t16(16,16);

    // 1. embedding gathers
    k_gather<<<BB*PL, 256, 0, stream>>>(passage, emb, ws + O_XPASS);
    k_gather<<<BB*QL, 256, 0, stream>>>(query,   emb, ws + O_XQUERY);
    k_gather<<<BB*AL, 256, 0, stream>>>(cneg, emb, ws + O_XCAND + 0*20480);
    k_gather<<<BB*AL, 256, 0, stream>>>(cpos, emb, ws + O_XCAND + 1*20480);
    k_gather<<<BB*AL, 256, 0, stream>>>(cna,  emb, ws + O_XCAND + 2*20480);

    // 2. input preactivations (x @ Wih^T + bih), z = direction
    k_gemm_nt<<<dim3(24,128,2), t16, 0, stream>>>(ws+O_XPASS, q_Wih, q_bih, ws+O_PREQ,
                                                  2048, 384, 256, 98304LL, 786432LL, 384LL);
    k_gemm_nt<<<dim3(24,64,2), t16, 0, stream>>>(ws+O_XQUERY, p_Wih, p_bih, ws+O_PREP,
                                                 1024, 384, 256, 98304LL, 393216LL, 384LL);
    for (int c = 0; c < 3; ++c)
        k_gemm_nt<<<dim3(24,5,2), t16, 0, stream>>>(ws+O_XCAND + c*20480, a_Wih, a_bih,
                                                    ws+O_PREA + c*61440,
                                                    80, 384, 256, 98304LL, 30720LL, 384LL);

    // 3. GRU scans
    k_gru_scan<<<16, 768, 0, stream>>>(ws+O_PREQ, q_Whh, q_bhh, ws+O_HQ, 256, 0, 0);
    k_gru_scan<<<16, 768, 0, stream>>>(ws+O_PREP, p_Whh, p_bhh, ws+O_HP, 128, 0, 0);
    k_gru_scan<<<48, 768, 0, stream>>>(ws+O_PREA, a_Whh, a_bhh, ws+O_HCAND, 10, 61440, 20480);

    // 4. candidate pooling
    k_cand_att<<<24, 256, 0, stream>>>(ws+O_HCAND, a_att, ws+O_AEMB);

    // 5. projection GEMMs
    k_gemm_nt<<<dim3(8,128,1),  t16, 0, stream>>>(ws+O_HQ, Wc1, nullptr, ws+O_AQ, 2048,128,256, 0,0,0);
    k_gemm_nt<<<dim3(8,64,1),   t16, 0, stream>>>(ws+O_HP, Wc2, nullptr, ws+O_AP, 1024,128,256, 0,0,0);
    k_gemm_nt<<<dim3(16,128,1), t16, 0, stream>>>(ws+O_HQ, Wb,  nullptr, ws+O_BQ, 2048,256,256, 0,0,0);
    k_gemm_nt<<<dim3(8,128,1),  t16, 0, stream>>>(ws+O_HQ, Wq,  nullptr, ws+O_CQ, 2048,128,256, 0,0,0);

    // 6. attention blocks -> agg slices
    k_att_c<<<1024, 256, 0, stream>>>(ws+O_AQ, ws+O_AP, vc, ws+O_HQ, ws+O_AGG);
    k_att_b<<<1024, 256, 0, stream>>>(ws+O_BQ, ws+O_HP, ws+O_HQ, ws+O_AGG);
    k_att_dms<<<1024, 512, 0, stream>>>(ws+O_HQ, 256, Wd, vd, ws+O_HP, 0,  768, ws+O_AGG);
    k_att_dms<<<1024, 512, 0, stream>>>(ws+O_HQ, 256, Wm, vm, ws+O_HP, 1, 1280, ws+O_AGG);
    k_att_dms<<<1024, 512, 0, stream>>>(ws+O_HP, 128, Ws, vs, ws+O_HP, 0,  256, ws+O_AGG);
    k_copy_hp<<<1024, 256, 0, stream>>>(ws+O_HP, ws+O_AGG);

    // 7. aggregation bigru
    k_gemm_nt<<<dim3(24,64,2), t16, 0, stream>>>(ws+O_AGG, g_Wih, g_bih, ws+O_PREG,
                                                 1024, 384, 1536, 589824LL, 393216LL, 384LL);
    k_gru_scan<<<16, 768, 0, stream>>>(ws+O_PREG, g_Whh, g_bhh, ws+O_AGGREP, 128, 0, 0);

    // 8. pooling + prediction
    k_q_att<<<8, 256, 0, stream>>>(ws+O_CQ, vq, ws+O_HQ, ws+O_RQ);
    k_gemm_nt<<<dim3(8,64,1), t16, 0, stream>>>(ws+O_AGGREP, Wp1, nullptr, ws+O_GP, 1024,128,256, 0,0,0);
    k_gemm_nt<<<dim3(8,1,1),  t16, 0, stream>>>(ws+O_RQ, Wp2, nullptr, ws+O_RQW, 8,128,256, 0,0,0);
    k_p_att<<<8, 256, 0, stream>>>(ws+O_GP, vp, ws+O_RQW, ws+O_AGGREP, ws+O_RP);
    k_final<<<8, 256, 0, stream>>>(ws+O_RP, Wpred, ws+O_AEMB, (float*)d_out);
}

// Round 4
// 1800.790 us; speedup vs baseline: 2.3095x; 2.3095x over previous
//
#include <hip/hip_runtime.h>
#include <hip/hip_bf16.h>

// ---------------------------------------------------------------------------
// MwAN forward, MI355X. B=8, QL=128, PL=256, AL=10, E=128, EMB=256.
// Inputs fp32; internal compute fp32 in d_ws; output fp32.
// R4: register-tiled dms-score GEMM (was 16-way LDS bank conflicts + barrier
// storm, 4e8 conflicts, 3000us) and 64x64-tile GEMM (was 16x16 naive).
// ---------------------------------------------------------------------------

#define BB 8
#define QL 128
#define PL 256
#define AL 10
#define EE 128
#define EMB 256
#define G3 384   // 3*H gates
#define HH 128   // hidden

// ---- ws layout (in floats) ----
#define O_XPASS   ((size_t)0)        // (8,256,256)  -- dead after pre-GEMMs; reused for dms scores
#define O_XQUERY  ((size_t)524288)   // (8,128,256)
#define O_XCAND   ((size_t)786432)   // 3 x (8,10,256), chunk 20480
#define O_PREQ    ((size_t)847872)   // (2,8,256,384)
#define O_PREP    ((size_t)2420736)  // (2,8,128,384)
#define O_PREA    ((size_t)3207168)  // 3 x (2,8,10,384), chunk 61440
#define O_PREG    ((size_t)3391488)  // (2,8,128,384)
#define O_HQ      ((size_t)4177920)  // (8,256,256)
#define O_HP      ((size_t)4702208)  // (8,128,256)
#define O_HCAND   ((size_t)4964352)  // 3 x (8,10,256), chunk 20480
#define O_AEMB    ((size_t)5025792)  // (8,3,256)
#define O_AQ      ((size_t)5031936)  // (8,256,128)
#define O_AP      ((size_t)5294080)  // (8,128,128)
#define O_BQ      ((size_t)5425152)  // (8,256,256)
#define O_AGG     ((size_t)5949440)  // (8,128,1536)
#define O_AGGREP  ((size_t)7522304)  // (8,128,256)
#define O_CQ      ((size_t)7784448)  // (8,256,128)
#define O_GP      ((size_t)8046592)  // (8,128,128)
#define O_RQ      ((size_t)8177664)  // (8,256)
#define O_RQW     ((size_t)8179712)  // (8,128)
#define O_RP      ((size_t)8180736)  // (8,256)
#define O_SCORE   O_XPASS            // (8,128,256) scores, reuse dead region

__device__ __forceinline__ float tanh_fast(float x){
    x = fminf(fmaxf(x, -20.f), 20.f);
    float e = __expf(2.f * x);
    return (e - 1.f) / (e + 1.f);
}
__device__ __forceinline__ float sig_fast(float x){
    return 1.f / (1.f + __expf(-x));
}

// softmax over sc[0..255] (callers pad unused entries with -1e30), 256 lanes work
__device__ __forceinline__ void softmax256(float* sc, float* red, int tid){
    float v = sc[tid];
    red[tid] = v;
    __syncthreads();
    for (int s = 128; s > 0; s >>= 1){
        if (tid < s) red[tid] = fmaxf(red[tid], red[tid + s]);
        __syncthreads();
    }
    float m = red[0];
    __syncthreads();
    float e = __expf(v - m);
    red[tid] = e;
    __syncthreads();
    for (int s = 128; s > 0; s >>= 1){
        if (tid < s) red[tid] += red[tid + s];
        __syncthreads();
    }
    float inv = 1.f / red[0];
    __syncthreads();
    sc[tid] = e * inv;
    __syncthreads();
}

// ---------------------------------------------------------------------------
// embedding gather: out[i,:] = emb[ids[i],:]
__global__ __launch_bounds__(256) void k_gather(const int* __restrict__ ids,
                                                const float* __restrict__ emb,
                                                float* __restrict__ out){
    int i = blockIdx.x, e = threadIdx.x;
    int id = ids[i];
    out[(size_t)i * EMB + e] = emb[(size_t)id * EMB + e];
}

// ---------------------------------------------------------------------------
// Register-tiled GEMM-NT: C[m,n] = sum_k A[m,k]*B[n,k] + bias[n].
// 64x64 C-tile / wg, 256 threads as 16x16, 4x4 fragment, K-chunk 32.
// Requires K%32==0, N%64==0. M arbitrary (guarded). blockIdx.z = direction.
__global__ __launch_bounds__(256) void k_gemm_v2(const float* __restrict__ A,
                                                 const float* __restrict__ Bm,
                                                 const float* __restrict__ bias,
                                                 float* __restrict__ C,
                                                 int M, int N, int K,
                                                 long long strideB, long long strideC,
                                                 long long strideBias){
    int z = blockIdx.z;
    Bm += (size_t)z * strideB;
    C  += (size_t)z * strideC;
    if (bias) bias += (size_t)z * strideBias;

    __shared__ float As[32][68];   // [k][m], stride 68 (=4 mod 32)
    __shared__ float Bs[32][68];   // [k][n]

    int tid = threadIdx.x;
    int i = tid & 15;              // m-fragment
    int j = tid >> 4;              // n-fragment
    int m0 = blockIdx.y * 64;
    int n0 = blockIdx.x * 64;

    int sm = tid & 63;             // staging row
    int sk = (tid >> 6) * 8;       // staging k-offset (8 floats)

    float acc[4][4];
    #pragma unroll
    for (int r = 0; r < 4; ++r)
        #pragma unroll
        for (int c = 0; c < 4; ++c) acc[r][c] = 0.f;

    for (int k0 = 0; k0 < K; k0 += 32){
        // stage A (guard rows)
        float4 a0 = make_float4(0,0,0,0), a1 = make_float4(0,0,0,0);
        if (m0 + sm < M){
            const float* ap = A + (size_t)(m0 + sm) * K + k0 + sk;
            a0 = *(const float4*)ap;
            a1 = *(const float4*)(ap + 4);
        }
        As[sk+0][sm] = a0.x; As[sk+1][sm] = a0.y; As[sk+2][sm] = a0.z; As[sk+3][sm] = a0.w;
        As[sk+4][sm] = a1.x; As[sk+5][sm] = a1.y; As[sk+6][sm] = a1.z; As[sk+7][sm] = a1.w;
        // stage B (N%64==0, no guard)
        {
            const float* bp = Bm + (size_t)(n0 + sm) * K + k0 + sk;
            float4 b0 = *(const float4*)bp;
            float4 b1 = *(const float4*)(bp + 4);
            Bs[sk+0][sm] = b0.x; Bs[sk+1][sm] = b0.y; Bs[sk+2][sm] = b0.z; Bs[sk+3][sm] = b0.w;
            Bs[sk+4][sm] = b1.x; Bs[sk+5][sm] = b1.y; Bs[sk+6][sm] = b1.z; Bs[sk+7][sm] = b1.w;
        }
        __syncthreads();
        #pragma unroll
        for (int f = 0; f < 32; ++f){
            float4 av = *(const float4*)&As[f][i*4];
            float4 bv = *(const float4*)&Bs[f][j*4];
            float ar[4] = {av.x, av.y, av.z, av.w};
            float bc[4] = {bv.x, bv.y, bv.z, bv.w};
            #pragma unroll
            for (int r = 0; r < 4; ++r)
                #pragma unroll
                for (int c = 0; c < 4; ++c)
                    acc[r][c] += ar[r] * bc[c];
        }
        __syncthreads();
    }

    float4 bv = make_float4(0,0,0,0);
    if (bias) bv = *(const float4*)&bias[n0 + j*4];
    #pragma unroll
    for (int r = 0; r < 4; ++r){
        int row = m0 + i*4 + r;
        if (row < M){
            float4 o;
            o.x = acc[r][0] + bv.x;
            o.y = acc[r][1] + bv.y;
            o.z = acc[r][2] + bv.z;
            o.w = acc[r][3] + bv.w;
            *(float4*)&C[(size_t)row * N + n0 + j*4] = o;
        }
    }
}

// ---------------------------------------------------------------------------
// GRU scan. One workgroup per (chunk, b, dir). 768 threads: g=tid>>1, half=tid&1.
__global__ __launch_bounds__(768) void k_gru_scan(const float* __restrict__ pre,
                                                  const float* __restrict__ Whh,
                                                  const float* __restrict__ bhh,
                                                  float* __restrict__ out,
                                                  int T, int preChunk, int outChunk){
    int idx = blockIdx.x;
    int c = idx >> 4, bd = idx & 15, b = bd >> 1, d = bd & 1;
    pre += (size_t)c * preChunk;
    out += (size_t)c * outChunk;

    int tid = threadIdx.x;
    int g = tid >> 1, half = tid & 1;

    float wf[64];
    {
        const float4* wp = (const float4*)(Whh + ((size_t)d * G3 + g) * HH + half * 64);
        #pragma unroll
        for (int j = 0; j < 16; ++j){
            float4 u = wp[j];
            wf[j*4+0] = u.x; wf[j*4+1] = u.y; wf[j*4+2] = u.z; wf[j*4+3] = u.w;
        }
    }
    float bg = bhh[d * G3 + g];

    __shared__ __align__(16) float h_s[HH];
    __shared__ float r_s[HH], z_s[HH];
    if (tid < HH) h_s[tid] = 0.f;
    __syncthreads();

    const float* ptB = pre + ((size_t)d * BB + b) * (size_t)T * G3;
    float* ob = out + ((size_t)b * T) * 256 + d * HH;

    for (int step = 0; step < T; ++step){
        int t = d ? (T - 1 - step) : step;
        float a0=0.f, a1=0.f, a2=0.f, a3=0.f;
        const float4* hp4 = (const float4*)&h_s[half * 64];
        #pragma unroll
        for (int j = 0; j < 16; ++j){
            float4 hv = hp4[j];
            a0 += wf[j*4+0] * hv.x;  a1 += wf[j*4+1] * hv.y;
            a2 += wf[j*4+2] * hv.z;  a3 += wf[j*4+3] * hv.w;
        }
        float acc = (a0 + a1) + (a2 + a3);
        acc += __shfl_xor(acc, 1);
        float gh = acc + bg;

        const float* pt = ptB + (size_t)t * G3;
        float pv = 0.f;
        if (half == 0) pv = pt[g];
        if (half == 0){
            if (g < HH)            r_s[g]       = sig_fast(pv + gh);
            else if (g < 2 * HH)   z_s[g - HH]  = sig_fast(pv + gh);
        }
        __syncthreads();
        if (half == 0 && g >= 2 * HH){
            int j = g - 2 * HH;
            float n  = tanh_fast(pv + r_s[j] * gh);
            float z  = z_s[j];
            float hn = n + z * (h_s[j] - n);
            h_s[j] = hn;
            ob[(size_t)t * 256 + j] = hn;
        }
        __syncthreads();
    }
}

// ---------------------------------------------------------------------------
// candidate attention pooling
__global__ __launch_bounds__(256) void k_cand_att(const float* __restrict__ h,
                                                  const float* __restrict__ a_att,
                                                  float* __restrict__ a_emb){
    int c = blockIdx.x / BB, b = blockIdx.x % BB, tid = threadIdx.x;
    __shared__ float att[256], sc[AL], sw[AL];
    att[tid] = a_att[tid];
    __syncthreads();
    const float* hb = h + (size_t)c * (BB*AL*256) + (size_t)b * (AL*256);
    if (tid < AL){
        float s = 0.f;
        for (int e = 0; e < 256; ++e) s += hb[tid*256 + e] * att[e];
        sc[tid] = s;
    }
    __syncthreads();
    if (tid == 0){
        float m = -1e30f;
        for (int t = 0; t < AL; ++t) m = fmaxf(m, sc[t]);
        float s = 0.f;
        for (int t = 0; t < AL; ++t){ sw[t] = __expf(sc[t] - m); s += sw[t]; }
        float inv = 1.f / s;
        for (int t = 0; t < AL; ++t) sw[t] *= inv;
    }
    __syncthreads();
    float o = 0.f;
    for (int t = 0; t < AL; ++t) o += sw[t] * hb[t*256 + tid];
    a_emb[((size_t)b*3 + c) * 256 + tid] = o;
}

// ---------------------------------------------------------------------------
// concat attention: score[p] = sum_e vc[e]*tanh(Aq[b,p,e]+Ap[b,q,e]); qtc -> agg+512
__global__ __launch_bounds__(256) void k_att_c(const float* __restrict__ Aq,
                                               const float* __restrict__ Ap,
                                               const float* __restrict__ vc,
                                               const float* __restrict__ hq,
                                               float* __restrict__ agg){
    int b = blockIdx.x >> 7, q = blockIdx.x & 127, tid = threadIdx.x;
    __shared__ float apv[EE], vcv[EE], sc[256], red[256];
    if (tid < EE){
        apv[tid] = Ap[((size_t)b*QL + q)*EE + tid];
        vcv[tid] = vc[tid];
    }
    __syncthreads();
    const float* aqp = Aq + ((size_t)b*PL + tid)*EE;
    float s = 0.f;
    #pragma unroll 4
    for (int e = 0; e < EE; ++e) s += vcv[e] * tanh_fast(aqp[e] + apv[e]);
    sc[tid] = s;
    __syncthreads();
    softmax256(sc, red, tid);
    float o = 0.f;
    const float* hqb = hq + (size_t)b*PL*256;
    for (int p = 0; p < PL; ++p) o += sc[p] * hqb[(size_t)p*256 + tid];
    agg[((size_t)b*QL + q)*1536 + 512 + tid] = o;
}

// bilinear attention: score[p] = hp[b,q,:] . Bq[b,p,:]; qtb -> agg+1024
__global__ __launch_bounds__(256) void k_att_b(const float* __restrict__ Bq,
                                               const float* __restrict__ hp,
                                               const float* __restrict__ hq,
                                               float* __restrict__ agg){
    int b = blockIdx.x >> 7, q = blockIdx.x & 127, tid = threadIdx.x;
    __shared__ float xq[256], sc[256], red[256];
    xq[tid] = hp[((size_t)b*QL + q)*256 + tid];
    __syncthreads();
    const float* bq = Bq + ((size_t)b*PL + tid)*256;
    float s = 0.f;
    #pragma unroll 4
    for (int e = 0; e < 256; ++e) s += xq[e] * bq[e];
    sc[tid] = s;
    __syncthreads();
    softmax256(sc, red, tid);
    float o = 0.f;
    const float* hqb = hq + (size_t)b*PL*256;
    for (int p = 0; p < PL; ++p) o += sc[p] * hqb[(size_t)p*256 + tid];
    agg[((size_t)b*QL + q)*1536 + 1024 + tid] = o;
}

// ---------------------------------------------------------------------------
// dms scores: sc[b,q,p] = sum_e v[e]*tanh( sum_f W[e,f]*(kv[b,p,f] op xq[b,q,f]) )
// mode 0: product, mode 1: difference. Grid (P/64, QL, BB), 256 threads.
// Register-tiled: 64p x 128e tile, 4x8 fragment/thread, f-chunk 32.
__global__ __launch_bounds__(256) void k_dms_score(const float* __restrict__ kv, int P,
                                                   const float* __restrict__ W,
                                                   const float* __restrict__ v,
                                                   const float* __restrict__ xsrc,
                                                   int mode,
                                                   float* __restrict__ sc){
    int pt = blockIdx.x, q = blockIdx.y, b = blockIdx.z;
    int tid = threadIdx.x;
    int i = tid & 15;     // p-fragment (4 p's)
    int j = tid >> 4;     // e-fragment (8 e's)

    __shared__ float xq[256];
    __shared__ float vv[128];
    __shared__ float As[32][68];    // [f][p]
    __shared__ float Ws[32][132];   // [f][e]
    __shared__ float sred[64][17];

    xq[tid] = xsrc[((size_t)b*QL + q)*256 + tid];
    if (tid < 128) vv[tid] = v[tid];

    const float* kvb = kv + ((size_t)b*P + pt*64) * 256;

    float acc[4][8];
    #pragma unroll
    for (int r = 0; r < 4; ++r)
        #pragma unroll
        for (int c = 0; c < 8; ++c) acc[r][c] = 0.f;

    int sm = tid & 63, sf = (tid >> 6) * 8;       // A staging: 64 rows x 8 f
    int se = tid & 127, sfw = (tid >> 7) * 16;    // W staging: 128 rows x 16 f

    __syncthreads();  // xq ready

    for (int f0 = 0; f0 < 256; f0 += 32){
        // stage A = kv op xq
        {
            const float* ap = kvb + (size_t)sm * 256 + f0 + sf;
            float4 a0 = *(const float4*)ap;
            float4 a1 = *(const float4*)(ap + 4);
            const float* xp = &xq[f0 + sf];
            if (mode == 0){
                a0.x *= xp[0]; a0.y *= xp[1]; a0.z *= xp[2]; a0.w *= xp[3];
                a1.x *= xp[4]; a1.y *= xp[5]; a1.z *= xp[6]; a1.w *= xp[7];
            } else {
                a0.x -= xp[0]; a0.y -= xp[1]; a0.z -= xp[2]; a0.w -= xp[3];
                a1.x -= xp[4]; a1.y -= xp[5]; a1.z -= xp[6]; a1.w -= xp[7];
            }
            As[sf+0][sm] = a0.x; As[sf+1][sm] = a0.y; As[sf+2][sm] = a0.z; As[sf+3][sm] = a0.w;
            As[sf+4][sm] = a1.x; As[sf+5][sm] = a1.y; As[sf+6][sm] = a1.z; As[sf+7][sm] = a1.w;
        }
        // stage W
        {
            const float* wp = W + (size_t)se * 256 + f0 + sfw;
            #pragma unroll
            for (int k4 = 0; k4 < 4; ++k4){
                float4 w4 = *(const float4*)(wp + k4*4);
                Ws[sfw+k4*4+0][se] = w4.x; Ws[sfw+k4*4+1][se] = w4.y;
                Ws[sfw+k4*4+2][se] = w4.z; Ws[sfw+k4*4+3][se] = w4.w;
            }
        }
        __syncthreads();
        #pragma unroll
        for (int f = 0; f < 32; ++f){
            float4 av = *(const float4*)&As[f][i*4];
            float4 b0 = *(const float4*)&Ws[f][j*8];
            float4 b1 = *(const float4*)&Ws[f][j*8+4];
            float ar[4] = {av.x, av.y, av.z, av.w};
            float bc[8] = {b0.x,b0.y,b0.z,b0.w,b1.x,b1.y,b1.z,b1.w};
            #pragma unroll
            for (int r = 0; r < 4; ++r)
                #pragma unroll
                for (int c = 0; c < 8; ++c)
                    acc[r][c] += ar[r] * bc[c];
        }
        __syncthreads();
    }

    // epilogue: s[p-frag] = sum over this thread's 8 e's of v[e]*tanh(acc)
    #pragma unroll
    for (int r = 0; r < 4; ++r){
        float s = 0.f;
        #pragma unroll
        for (int c = 0; c < 8; ++c) s += vv[j*8 + c] * tanh_fast(acc[r][c]);
        sred[i*4 + r][j] = s;
    }
    __syncthreads();
    if (tid < 64){
        float s = 0.f;
        #pragma unroll
        for (int jj = 0; jj < 16; ++jj) s += sred[tid][jj];
        sc[((size_t)b*QL + q)*P + pt*64 + tid] = s;
    }
}

// softmax over scores + weighted sum: agg[b,q,outOff+e] = sum_p w[p]*kv[b,p,e]
__global__ __launch_bounds__(256) void k_att_apply(const float* __restrict__ sc,
                                                   const float* __restrict__ kv, int P,
                                                   int outOff, float* __restrict__ agg){
    int b = blockIdx.x >> 7, q = blockIdx.x & 127, tid = threadIdx.x;
    __shared__ float w[256], red[256];
    w[tid] = (tid < P) ? sc[((size_t)b*QL + q)*P + tid] : -1e30f;
    __syncthreads();
    softmax256(w, red, tid);
    const float* kvb = kv + (size_t)b*P*256;
    float o = 0.f;
    #pragma unroll 4
    for (int p = 0; p < P; ++p) o += w[p] * kvb[(size_t)p*256 + tid];
    agg[((size_t)b*QL + q)*1536 + outOff + tid] = o;
}

// copy hp into agg[...,0:256]
__global__ __launch_bounds__(256) void k_copy_hp(const float* __restrict__ hp,
                                                 float* __restrict__ agg){
    int i = blockIdx.x, tid = threadIdx.x;
    agg[(size_t)i*1536 + tid] = hp[(size_t)i*256 + tid];
}

// ---------------------------------------------------------------------------
// rq[b,:] = sum_p softmax_p( vq . tanh(Cq[b,p,:]) ) * hq[b,p,:]
__global__ __launch_bounds__(256) void k_q_att(const float* __restrict__ Cq,
                                               const float* __restrict__ vq,
                                               const float* __restrict__ hq,
                                               float* __restrict__ rq){
    int b = blockIdx.x, tid = threadIdx.x;
    __shared__ float vv[EE], sc[256], red[256];
    if (tid < EE) vv[tid] = vq[tid];
    __syncthreads();
    const float* cb = Cq + ((size_t)b*PL + tid)*EE;
    float s = 0.f;
    #pragma unroll 4
    for (int e = 0; e < EE; ++e) s += vv[e] * tanh_fast(cb[e]);
    sc[tid] = s;
    __syncthreads();
    softmax256(sc, red, tid);
    float o = 0.f;
    const float* hqb = hq + (size_t)b*PL*256;
    for (int p = 0; p < PL; ++p) o += sc[p] * hqb[(size_t)p*256 + tid];
    rq[(size_t)b*256 + tid] = o;
}

// rp[b,:] = sum_q softmax_q( vp . (Gp[b,q,:] + rqW[b,:]) ) * agg_rep[b,q,:]
__global__ __launch_bounds__(256) void k_p_att(const float* __restrict__ Gp,
                                               const float* __restrict__ vp,
                                               const float* __restrict__ rqW,
                                               const float* __restrict__ agg_rep,
                                               float* __restrict__ rp){
    int b = blockIdx.x, tid = threadIdx.x;
    __shared__ float vv[EE], rw[EE], sc[256], red[256];
    if (tid < EE){
        vv[tid] = vp[tid];
        rw[tid] = rqW[(size_t)b*EE + tid];
    }
    if (tid >= 128) sc[tid] = -1e30f;
    __syncthreads();
    if (tid < QL){
        const float* gp = Gp + ((size_t)b*QL + tid)*EE;
        float s = 0.f;
        for (int e = 0; e < EE; ++e) s += vv[e] * (gp[e] + rw[e]);
        sc[tid] = s;
    }
    __syncthreads();
    softmax256(sc, red, tid);
    float o = 0.f;
    const float* ab = agg_rep + (size_t)b*QL*256;
    for (int q = 0; q < QL; ++q) o += sc[q] * ab[(size_t)q*256 + tid];
    rp[(size_t)b*256 + tid] = o;
}

// enc = leaky_relu(Wpred @ rp); logits[b,c] = a_emb[b,c,:] . enc  (fp32 out)
__global__ __launch_bounds__(256) void k_final(const float* __restrict__ rp,
                                               const float* __restrict__ Wpred,
                                               const float* __restrict__ a_emb,
                                               float* __restrict__ out){
    int b = blockIdx.x, tid = threadIdx.x;
    __shared__ float rpv[256], enc[256];
    rpv[tid] = rp[(size_t)b*256 + tid];
    __syncthreads();
    const float* wr = Wpred + (size_t)tid*256;
    float s = 0.f;
    #pragma unroll 4
    for (int e = 0; e < 256; ++e) s += wr[e] * rpv[e];
    enc[tid] = (s > 0.f) ? s : 0.01f * s;
    __syncthreads();
    if (tid < 3){
        const float* ae = a_emb + ((size_t)b*3 + tid)*256;
        float o = 0.f;
        for (int e = 0; e < 256; ++e) o += ae[e] * enc[e];
        out[b*3 + tid] = o;
    }
}

// ---------------------------------------------------------------------------
extern "C" void kernel_launch(void* const* d_in, const int* in_sizes, int n_in,
                              void* d_out, int out_size, void* d_ws, size_t ws_size,
                              hipStream_t stream){
    const float* emb   = (const float*)d_in[0];
    const float* a_att = (const float*)d_in[1];
    const float* Wc1   = (const float*)d_in[2];
    const float* Wc2   = (const float*)d_in[3];
    const float* vc    = (const float*)d_in[4];
    const float* Wb    = (const float*)d_in[5];
    const float* Wd    = (const float*)d_in[6];
    const float* vd    = (const float*)d_in[7];
    const float* Wm    = (const float*)d_in[8];
    const float* vm    = (const float*)d_in[9];
    const float* Ws    = (const float*)d_in[10];
    const float* vs    = (const float*)d_in[11];
    const float* Wq    = (const float*)d_in[12];
    const float* vq    = (const float*)d_in[13];
    const float* Wp1   = (const float*)d_in[14];
    const float* Wp2   = (const float*)d_in[15];
    const float* vp    = (const float*)d_in[16];
    const float* Wpred = (const float*)d_in[17];
    const float* q_Wih = (const float*)d_in[18];
    const float* q_Whh = (const float*)d_in[19];
    const float* q_bih = (const float*)d_in[20];
    const float* q_bhh = (const float*)d_in[21];
    const float* p_Wih = (const float*)d_in[22];
    const float* p_Whh = (const float*)d_in[23];
    const float* p_bih = (const float*)d_in[24];
    const float* p_bhh = (const float*)d_in[25];
    const float* a_Wih = (const float*)d_in[26];
    const float* a_Whh = (const float*)d_in[27];
    const float* a_bih = (const float*)d_in[28];
    const float* a_bhh = (const float*)d_in[29];
    const float* g_Wih = (const float*)d_in[30];
    const float* g_Whh = (const float*)d_in[31];
    const float* g_bih = (const float*)d_in[32];
    const float* g_bhh = (const float*)d_in[33];
    const int* query   = (const int*)d_in[34];
    const int* passage = (const int*)d_in[35];
    const int* cneg    = (const int*)d_in[36];
    const int* cpos    = (const int*)d_in[37];
    const int* cna     = (const int*)d_in[38];

    float* ws = (float*)d_ws;

    // 1. embedding gathers
    k_gather<<<BB*PL, 256, 0, stream>>>(passage, emb, ws + O_XPASS);
    k_gather<<<BB*QL, 256, 0, stream>>>(query,   emb, ws + O_XQUERY);
    k_gather<<<BB*AL, 256, 0, stream>>>(cneg, emb, ws + O_XCAND + 0*20480);
    k_gather<<<BB*AL, 256, 0, stream>>>(cpos, emb, ws + O_XCAND + 1*20480);
    k_gather<<<BB*AL, 256, 0, stream>>>(cna,  emb, ws + O_XCAND + 2*20480);

    // 2. input preactivations (x @ Wih^T + bih), z = direction
    k_gemm_v2<<<dim3(6,32,2), 256, 0, stream>>>(ws+O_XPASS, q_Wih, q_bih, ws+O_PREQ,
                                                2048, 384, 256, 98304LL, 786432LL, 384LL);
    k_gemm_v2<<<dim3(6,16,2), 256, 0, stream>>>(ws+O_XQUERY, p_Wih, p_bih, ws+O_PREP,
                                                1024, 384, 256, 98304LL, 393216LL, 384LL);
    for (int c = 0; c < 3; ++c)
        k_gemm_v2<<<dim3(6,2,2), 256, 0, stream>>>(ws+O_XCAND + c*20480, a_Wih, a_bih,
                                                   ws+O_PREA + c*61440,
                                                   80, 384, 256, 98304LL, 30720LL, 384LL);

    // 3. GRU scans
    k_gru_scan<<<16, 768, 0, stream>>>(ws+O_PREQ, q_Whh, q_bhh, ws+O_HQ, 256, 0, 0);
    k_gru_scan<<<16, 768, 0, stream>>>(ws+O_PREP, p_Whh, p_bhh, ws+O_HP, 128, 0, 0);
    k_gru_scan<<<48, 768, 0, stream>>>(ws+O_PREA, a_Whh, a_bhh, ws+O_HCAND, 10, 61440, 20480);

    // 4. candidate pooling
    k_cand_att<<<24, 256, 0, stream>>>(ws+O_HCAND, a_att, ws+O_AEMB);

    // 5. projection GEMMs
    k_gemm_v2<<<dim3(2,32,1), 256, 0, stream>>>(ws+O_HQ, Wc1, nullptr, ws+O_AQ, 2048,128,256, 0,0,0);
    k_gemm_v2<<<dim3(2,16,1), 256, 0, stream>>>(ws+O_HP, Wc2, nullptr, ws+O_AP, 1024,128,256, 0,0,0);
    k_gemm_v2<<<dim3(4,32,1), 256, 0, stream>>>(ws+O_HQ, Wb,  nullptr, ws+O_BQ, 2048,256,256, 0,0,0);
    k_gemm_v2<<<dim3(2,32,1), 256, 0, stream>>>(ws+O_HQ, Wq,  nullptr, ws+O_CQ, 2048,128,256, 0,0,0);

    // 6. attention blocks -> agg slices
    k_att_c<<<1024, 256, 0, stream>>>(ws+O_AQ, ws+O_AP, vc, ws+O_HQ, ws+O_AGG);
    k_att_b<<<1024, 256, 0, stream>>>(ws+O_BQ, ws+O_HP, ws+O_HQ, ws+O_AGG);
    // dot (qtd -> 768)
    k_dms_score<<<dim3(4,128,8), 256, 0, stream>>>(ws+O_HQ, 256, Wd, vd, ws+O_HP, 0, ws+O_SCORE);
    k_att_apply<<<1024, 256, 0, stream>>>(ws+O_SCORE, ws+O_HQ, 256,  768, ws+O_AGG);
    // minus (qtm -> 1280)
    k_dms_score<<<dim3(4,128,8), 256, 0, stream>>>(ws+O_HQ, 256, Wm, vm, ws+O_HP, 1, ws+O_SCORE);
    k_att_apply<<<1024, 256, 0, stream>>>(ws+O_SCORE, ws+O_HQ, 256, 1280, ws+O_AGG);
    // self (qts -> 256)
    k_dms_score<<<dim3(2,128,8), 256, 0, stream>>>(ws+O_HP, 128, Ws, vs, ws+O_HP, 0, ws+O_SCORE);
    k_att_apply<<<1024, 256, 0, stream>>>(ws+O_SCORE, ws+O_HP, 128,  256, ws+O_AGG);
    k_copy_hp<<<1024, 256, 0, stream>>>(ws+O_HP, ws+O_AGG);

    // 7. aggregation bigru
    k_gemm_v2<<<dim3(6,16,2), 256, 0, stream>>>(ws+O_AGG, g_Wih, g_bih, ws+O_PREG,
                                                1024, 384, 1536, 589824LL, 393216LL, 384LL);
    k_gru_scan<<<16, 768, 0, stream>>>(ws+O_PREG, g_Whh, g_bhh, ws+O_AGGREP, 128, 0, 0);

    // 8. pooling + prediction
    k_q_att<<<8, 256, 0, stream>>>(ws+O_CQ, vq, ws+O_HQ, ws+O_RQ);
    k_gemm_v2<<<dim3(2,16,1), 256, 0, stream>>>(ws+O_AGGREP, Wp1, nullptr, ws+O_GP, 1024,128,256, 0,0,0);
    k_gemm_v2<<<dim3(2,1,1),  256, 0, stream>>>(ws+O_RQ, Wp2, nullptr, ws+O_RQW, 8,128,256, 0,0,0);
    k_p_att<<<8, 256, 0, stream>>>(ws+O_GP, vp, ws+O_RQW, ws+O_AGGREP, ws+O_RP);
    k_final<<<8, 256, 0, stream>>>(ws+O_RP, Wpred, ws+O_AEMB, (float*)d_out);
}

// Round 5
// 1543.929 us; speedup vs baseline: 2.6937x; 1.1664x over previous
//
#include <hip/hip_runtime.h>
#include <hip/hip_bf16.h>

// ---------------------------------------------------------------------------
// MwAN forward, MI355X. B=8, QL=128, PL=256, AL=10, E=128, EMB=256.
// Inputs fp32; internal compute fp32 in d_ws; output fp32.
// R5: (1) GRU scan gate-owner rewrite: 1 barrier/step (was 3), ping-pong h,
//     register prefetch of pre, no divergent tail. (2) minus-attention
//     factored through Wm linearity: dms GEMM (8.6 G MAC) -> 2 small GEMMs
//     + att_c-style kernel.
// ---------------------------------------------------------------------------

#define BB 8
#define QL 128
#define PL 256
#define AL 10
#define EE 128
#define EMB 256
#define G3 384   // 3*H gates
#define HH 128   // hidden

// ---- ws layout (in floats) ----
#define O_XPASS   ((size_t)0)        // (8,256,256)  -- dead after pre-GEMMs; reused
#define O_XQUERY  ((size_t)524288)   // (8,128,256)  -- dead after pre-GEMMs; reused for Mp
#define O_XCAND   ((size_t)786432)   // 3 x (8,10,256), chunk 20480
#define O_PREQ    ((size_t)847872)   // (2,8,256,384)
#define O_PREP    ((size_t)2420736)  // (2,8,128,384)
#define O_PREA    ((size_t)3207168)  // 3 x (2,8,10,384), chunk 61440
#define O_PREG    ((size_t)3391488)  // (2,8,128,384)
#define O_HQ      ((size_t)4177920)  // (8,256,256)
#define O_HP      ((size_t)4702208)  // (8,128,256)
#define O_HCAND   ((size_t)4964352)  // 3 x (8,10,256), chunk 20480
#define O_AEMB    ((size_t)5025792)  // (8,3,256)
#define O_AQ      ((size_t)5031936)  // (8,256,128)
#define O_AP      ((size_t)5294080)  // (8,128,128)
#define O_BQ      ((size_t)5425152)  // (8,256,256)
#define O_AGG     ((size_t)5949440)  // (8,128,1536)
#define O_AGGREP  ((size_t)7522304)  // (8,128,256)
#define O_CQ      ((size_t)7784448)  // (8,256,128)
#define O_GP      ((size_t)8046592)  // (8,128,128)
#define O_RQ      ((size_t)8177664)  // (8,256)
#define O_RQW     ((size_t)8179712)  // (8,128)
#define O_RP      ((size_t)8180736)  // (8,256)
#define O_SCORE   O_XPASS                    // (8,128,256) dot scores / then Mq
#define O_SCB     (O_XPASS + (size_t)262144) // (8,128,128) self scores
#define O_MP      O_XQUERY                   // (8,128,128) Mp = hp@Wm^T

__device__ __forceinline__ float tanh_fast(float x){
    x = fminf(fmaxf(x, -20.f), 20.f);
    float e = __expf(2.f * x);
    return (e - 1.f) / (e + 1.f);
}
__device__ __forceinline__ float sig_fast(float x){
    return 1.f / (1.f + __expf(-x));
}

// softmax over sc[0..255], 256 lanes
__device__ __forceinline__ void softmax256(float* sc, float* red, int tid){
    float v = sc[tid];
    red[tid] = v;
    __syncthreads();
    for (int s = 128; s > 0; s >>= 1){
        if (tid < s) red[tid] = fmaxf(red[tid], red[tid + s]);
        __syncthreads();
    }
    float m = red[0];
    __syncthreads();
    float e = __expf(v - m);
    red[tid] = e;
    __syncthreads();
    for (int s = 128; s > 0; s >>= 1){
        if (tid < s) red[tid] += red[tid + s];
        __syncthreads();
    }
    float inv = 1.f / red[0];
    __syncthreads();
    sc[tid] = e * inv;
    __syncthreads();
}

// ---------------------------------------------------------------------------
__global__ __launch_bounds__(256) void k_gather(const int* __restrict__ ids,
                                                const float* __restrict__ emb,
                                                float* __restrict__ out){
    int i = blockIdx.x, e = threadIdx.x;
    int id = ids[i];
    out[(size_t)i * EMB + e] = emb[(size_t)id * EMB + e];
}

// ---------------------------------------------------------------------------
// Register-tiled GEMM-NT: C[m,n] = sum_k A[m,k]*B[n,k] + bias[n].
// 64x64 tile, 256 threads, 4x4 fragment, K-chunk 32. K%32==0, N%64==0.
__global__ __launch_bounds__(256) void k_gemm_v2(const float* __restrict__ A,
                                                 const float* __restrict__ Bm,
                                                 const float* __restrict__ bias,
                                                 float* __restrict__ C,
                                                 int M, int N, int K,
                                                 long long strideB, long long strideC,
                                                 long long strideBias){
    int z = blockIdx.z;
    Bm += (size_t)z * strideB;
    C  += (size_t)z * strideC;
    if (bias) bias += (size_t)z * strideBias;

    __shared__ float As[32][68];
    __shared__ float Bs[32][68];

    int tid = threadIdx.x;
    int i = tid & 15;
    int j = tid >> 4;
    int m0 = blockIdx.y * 64;
    int n0 = blockIdx.x * 64;

    int sm = tid & 63;
    int sk = (tid >> 6) * 8;

    float acc[4][4];
    #pragma unroll
    for (int r = 0; r < 4; ++r)
        #pragma unroll
        for (int c = 0; c < 4; ++c) acc[r][c] = 0.f;

    for (int k0 = 0; k0 < K; k0 += 32){
        float4 a0 = make_float4(0,0,0,0), a1 = make_float4(0,0,0,0);
        if (m0 + sm < M){
            const float* ap = A + (size_t)(m0 + sm) * K + k0 + sk;
            a0 = *(const float4*)ap;
            a1 = *(const float4*)(ap + 4);
        }
        As[sk+0][sm] = a0.x; As[sk+1][sm] = a0.y; As[sk+2][sm] = a0.z; As[sk+3][sm] = a0.w;
        As[sk+4][sm] = a1.x; As[sk+5][sm] = a1.y; As[sk+6][sm] = a1.z; As[sk+7][sm] = a1.w;
        {
            const float* bp = Bm + (size_t)(n0 + sm) * K + k0 + sk;
            float4 b0 = *(const float4*)bp;
            float4 b1 = *(const float4*)(bp + 4);
            Bs[sk+0][sm] = b0.x; Bs[sk+1][sm] = b0.y; Bs[sk+2][sm] = b0.z; Bs[sk+3][sm] = b0.w;
            Bs[sk+4][sm] = b1.x; Bs[sk+5][sm] = b1.y; Bs[sk+6][sm] = b1.z; Bs[sk+7][sm] = b1.w;
        }
        __syncthreads();
        #pragma unroll
        for (int f = 0; f < 32; ++f){
            float4 av = *(const float4*)&As[f][i*4];
            float4 bv = *(const float4*)&Bs[f][j*4];
            float ar[4] = {av.x, av.y, av.z, av.w};
            float bc[4] = {bv.x, bv.y, bv.z, bv.w};
            #pragma unroll
            for (int r = 0; r < 4; ++r)
                #pragma unroll
                for (int c = 0; c < 4; ++c)
                    acc[r][c] += ar[r] * bc[c];
        }
        __syncthreads();
    }

    float4 bv = make_float4(0,0,0,0);
    if (bias) bv = *(const float4*)&bias[n0 + j*4];
    #pragma unroll
    for (int r = 0; r < 4; ++r){
        int row = m0 + i*4 + r;
        if (row < M){
            float4 o;
            o.x = acc[r][0] + bv.x;
            o.y = acc[r][1] + bv.y;
            o.z = acc[r][2] + bv.z;
            o.w = acc[r][3] + bv.w;
            *(float4*)&C[(size_t)row * N + n0 + j*4] = o;
        }
    }
}

// ---------------------------------------------------------------------------
// GRU scan, gate-owner layout. One WG of 256 per (chunk,b,dir).
// tid = jp*4+quarter; thread owns gates (r,z,n) for j0=2jp, j1=2jp+1 over
// h-chunk [quarter*32, quarter*32+32). Butterfly xor(1,2) completes dots;
// all quarters compute the update redundantly (no divergence), one barrier
// per step via ping-pong h buffer. pre prefetched one step ahead.
__global__ __launch_bounds__(256, 1) void k_gru_scan(const float* __restrict__ pre,
                                                     const float* __restrict__ Whh,
                                                     const float* __restrict__ bhh,
                                                     float* __restrict__ out,
                                                     int T, int preChunk, int outChunk){
    int idx = blockIdx.x;
    int c = idx >> 4, bd = idx & 15, b = bd >> 1, d = bd & 1;
    pre += (size_t)c * preChunk;
    out += (size_t)c * outChunk;

    int tid = threadIdx.x;
    int jp = tid >> 2, quarter = tid & 3;
    int j0 = jp * 2;
    int cb = quarter * 32;

    // weights: wgt[G*2+jj][k], G in {r,z,n}, jj in {0,1}
    float wgt[6][32];
    const float* wb = Whh + (size_t)d * G3 * HH;
    #pragma unroll
    for (int G = 0; G < 3; ++G)
        #pragma unroll
        for (int jj = 0; jj < 2; ++jj){
            const float4* p4 = (const float4*)(wb + (size_t)(G*HH + j0 + jj) * HH + cb);
            #pragma unroll
            for (int kk = 0; kk < 8; ++kk){
                float4 u = p4[kk];
                wgt[G*2+jj][kk*4+0] = u.x; wgt[G*2+jj][kk*4+1] = u.y;
                wgt[G*2+jj][kk*4+2] = u.z; wgt[G*2+jj][kk*4+3] = u.w;
            }
        }
    const float* bb = bhh + d * G3;
    float bgr0 = bb[j0],        bgr1 = bb[j0+1];
    float bgz0 = bb[HH+j0],     bgz1 = bb[HH+j0+1];
    float bgn0 = bb[2*HH+j0],   bgn1 = bb[2*HH+j0+1];

    __shared__ __align__(16) float h_s[2][HH];
    if (tid < HH) h_s[0][tid] = 0.f;
    float hp0 = 0.f, hp1 = 0.f;   // local h[j0], h[j0+1] (redundant across quarters)

    const float* ptB = pre + ((size_t)d * BB + b) * (size_t)T * G3;
    float* ob = out + (size_t)b * T * 256 + d * HH;

    // prefetch step 0
    {
        int t0 = d ? (T-1) : 0;
        const float* pt = ptB + (size_t)t0 * G3;
        // fallthrough into loop-carried registers
        // (loaded below)
    }
    const float* pt0 = ptB + (size_t)(d ? (T-1) : 0) * G3;
    float2 pr = *(const float2*)(pt0 + j0);
    float2 pz = *(const float2*)(pt0 + HH + j0);
    float2 pn = *(const float2*)(pt0 + 2*HH + j0);
    __syncthreads();

    for (int step = 0; step < T; ++step){
        int t = d ? (T-1-step) : step;
        // prefetch next step's pre
        float2 nr = make_float2(0.f,0.f), nz = nr, nn = nr;
        if (step + 1 < T){
            int tn = d ? (T-2-step) : (step+1);
            const float* ptn = ptB + (size_t)tn * G3;
            nr = *(const float2*)(ptn + j0);
            nz = *(const float2*)(ptn + HH + j0);
            nn = *(const float2*)(ptn + 2*HH + j0);
        }
        int rb = step & 1;
        const float4* h4 = (const float4*)&h_s[rb][cb];
        float ar0=0.f, ar1=0.f, az0=0.f, az1=0.f, an0=0.f, an1=0.f;
        #pragma unroll
        for (int kk = 0; kk < 8; ++kk){
            float4 hv = h4[kk];
            ar0 = fmaf(wgt[0][kk*4+0], hv.x, ar0); ar0 = fmaf(wgt[0][kk*4+1], hv.y, ar0);
            ar0 = fmaf(wgt[0][kk*4+2], hv.z, ar0); ar0 = fmaf(wgt[0][kk*4+3], hv.w, ar0);
            ar1 = fmaf(wgt[1][kk*4+0], hv.x, ar1); ar1 = fmaf(wgt[1][kk*4+1], hv.y, ar1);
            ar1 = fmaf(wgt[1][kk*4+2], hv.z, ar1); ar1 = fmaf(wgt[1][kk*4+3], hv.w, ar1);
            az0 = fmaf(wgt[2][kk*4+0], hv.x, az0); az0 = fmaf(wgt[2][kk*4+1], hv.y, az0);
            az0 = fmaf(wgt[2][kk*4+2], hv.z, az0); az0 = fmaf(wgt[2][kk*4+3], hv.w, az0);
            az1 = fmaf(wgt[3][kk*4+0], hv.x, az1); az1 = fmaf(wgt[3][kk*4+1], hv.y, az1);
            az1 = fmaf(wgt[3][kk*4+2], hv.z, az1); az1 = fmaf(wgt[3][kk*4+3], hv.w, az1);
            an0 = fmaf(wgt[4][kk*4+0], hv.x, an0); an0 = fmaf(wgt[4][kk*4+1], hv.y, an0);
            an0 = fmaf(wgt[4][kk*4+2], hv.z, an0); an0 = fmaf(wgt[4][kk*4+3], hv.w, an0);
            an1 = fmaf(wgt[5][kk*4+0], hv.x, an1); an1 = fmaf(wgt[5][kk*4+1], hv.y, an1);
            an1 = fmaf(wgt[5][kk*4+2], hv.z, an1); an1 = fmaf(wgt[5][kk*4+3], hv.w, an1);
        }
        // butterfly over quarters
        ar0 += __shfl_xor(ar0, 1); ar0 += __shfl_xor(ar0, 2);
        ar1 += __shfl_xor(ar1, 1); ar1 += __shfl_xor(ar1, 2);
        az0 += __shfl_xor(az0, 1); az0 += __shfl_xor(az0, 2);
        az1 += __shfl_xor(az1, 1); az1 += __shfl_xor(az1, 2);
        an0 += __shfl_xor(an0, 1); an0 += __shfl_xor(an0, 2);
        an1 += __shfl_xor(an1, 1); an1 += __shfl_xor(an1, 2);

        float r0 = sig_fast(pr.x + ar0 + bgr0);
        float z0 = sig_fast(pz.x + az0 + bgz0);
        float n0 = tanh_fast(pn.x + r0 * (an0 + bgn0));
        float h0 = n0 + z0 * (hp0 - n0);
        float r1 = sig_fast(pr.y + ar1 + bgr1);
        float z1 = sig_fast(pz.y + az1 + bgz1);
        float n1 = tanh_fast(pn.y + r1 * (an1 + bgn1));
        float h1 = n1 + z1 * (hp1 - n1);
        hp0 = h0; hp1 = h1;

        if (quarter == 0) *(float2*)&h_s[1-rb][j0] = make_float2(h0, h1);
        if (quarter == 1) *(float2*)&ob[(size_t)t * 256 + j0] = make_float2(h0, h1);
        pr = nr; pz = nz; pn = nn;
        __syncthreads();
    }
}

// ---------------------------------------------------------------------------
__global__ __launch_bounds__(256) void k_cand_att(const float* __restrict__ h,
                                                  const float* __restrict__ a_att,
                                                  float* __restrict__ a_emb){
    int c = blockIdx.x / BB, b = blockIdx.x % BB, tid = threadIdx.x;
    __shared__ float att[256], sc[AL], sw[AL];
    att[tid] = a_att[tid];
    __syncthreads();
    const float* hb = h + (size_t)c * (BB*AL*256) + (size_t)b * (AL*256);
    if (tid < AL){
        float s = 0.f;
        for (int e = 0; e < 256; ++e) s += hb[tid*256 + e] * att[e];
        sc[tid] = s;
    }
    __syncthreads();
    if (tid == 0){
        float m = -1e30f;
        for (int t = 0; t < AL; ++t) m = fmaxf(m, sc[t]);
        float s = 0.f;
        for (int t = 0; t < AL; ++t){ sw[t] = __expf(sc[t] - m); s += sw[t]; }
        float inv = 1.f / s;
        for (int t = 0; t < AL; ++t) sw[t] *= inv;
    }
    __syncthreads();
    float o = 0.f;
    for (int t = 0; t < AL; ++t) o += sw[t] * hb[t*256 + tid];
    a_emb[((size_t)b*3 + c) * 256 + tid] = o;
}

// ---------------------------------------------------------------------------
// additive attention: score[p] = sum_e v[e]*tanh(Aq[b,p,e] + sign*Ap[b,q,e]);
// out = sum_p softmax(score)[p] * vals[b,p,:]  -> agg+outOff.
// Covers concat (sign=+1, vc) and factored minus (sign=-1, vm).
__global__ __launch_bounds__(256) void k_att_cm(const float* __restrict__ Aq,
                                                const float* __restrict__ Ap,
                                                const float* __restrict__ v,
                                                const float* __restrict__ vals,
                                                float sign, int outOff,
                                                float* __restrict__ agg){
    int b = blockIdx.x >> 7, q = blockIdx.x & 127, tid = threadIdx.x;
    __shared__ float apv[EE], vcv[EE], sc[256], red[256];
    if (tid < EE){
        apv[tid] = sign * Ap[((size_t)b*QL + q)*EE + tid];
        vcv[tid] = v[tid];
    }
    __syncthreads();
    const float* aqp = Aq + ((size_t)b*PL + tid)*EE;
    float s = 0.f;
    #pragma unroll 4
    for (int e = 0; e < EE; ++e) s += vcv[e] * tanh_fast(aqp[e] + apv[e]);
    sc[tid] = s;
    __syncthreads();
    softmax256(sc, red, tid);
    float o = 0.f;
    const float* vb = vals + (size_t)b*PL*256;
    for (int p = 0; p < PL; ++p) o += sc[p] * vb[(size_t)p*256 + tid];
    agg[((size_t)b*QL + q)*1536 + outOff + tid] = o;
}

// bilinear attention: score[p] = hp[b,q,:] . Bq[b,p,:]; qtb -> agg+1024
__global__ __launch_bounds__(256) void k_att_b(const float* __restrict__ Bq,
                                               const float* __restrict__ hp,
                                               const float* __restrict__ hq,
                                               float* __restrict__ agg){
    int b = blockIdx.x >> 7, q = blockIdx.x & 127, tid = threadIdx.x;
    __shared__ float xq[256], sc[256], red[256];
    xq[tid] = hp[((size_t)b*QL + q)*256 + tid];
    __syncthreads();
    const float* bq = Bq + ((size_t)b*PL + tid)*256;
    float s = 0.f;
    #pragma unroll 4
    for (int e = 0; e < 256; ++e) s += xq[e] * bq[e];
    sc[tid] = s;
    __syncthreads();
    softmax256(sc, red, tid);
    float o = 0.f;
    const float* hqb = hq + (size_t)b*PL*256;
    for (int p = 0; p < PL; ++p) o += sc[p] * hqb[(size_t)p*256 + tid];
    agg[((size_t)b*QL + q)*1536 + 1024 + tid] = o;
}

// ---------------------------------------------------------------------------
// dms scores (product mode): sc[b,q,p] = sum_e v[e]*tanh(sum_f W[e,f]*kv[p,f]*xq[f])
__global__ __launch_bounds__(256) void k_dms_score(const float* __restrict__ kv, int P,
                                                   const float* __restrict__ W,
                                                   const float* __restrict__ v,
                                                   const float* __restrict__ xsrc,
                                                   int mode,
                                                   float* __restrict__ sc){
    int pt = blockIdx.x, q = blockIdx.y, b = blockIdx.z;
    int tid = threadIdx.x;
    int i = tid & 15;
    int j = tid >> 4;

    __shared__ float xq[256];
    __shared__ float vv[128];
    __shared__ float As[32][68];
    __shared__ float Ws[32][132];
    __shared__ float sred[64][17];

    xq[tid] = xsrc[((size_t)b*QL + q)*256 + tid];
    if (tid < 128) vv[tid] = v[tid];

    const float* kvb = kv + ((size_t)b*P + pt*64) * 256;

    float acc[4][8];
    #pragma unroll
    for (int r = 0; r < 4; ++r)
        #pragma unroll
        for (int c = 0; c < 8; ++c) acc[r][c] = 0.f;

    int sm = tid & 63, sf = (tid >> 6) * 8;
    int se = tid & 127, sfw = (tid >> 7) * 16;

    __syncthreads();

    for (int f0 = 0; f0 < 256; f0 += 32){
        {
            const float* ap = kvb + (size_t)sm * 256 + f0 + sf;
            float4 a0 = *(const float4*)ap;
            float4 a1 = *(const float4*)(ap + 4);
            const float* xp = &xq[f0 + sf];
            if (mode == 0){
                a0.x *= xp[0]; a0.y *= xp[1]; a0.z *= xp[2]; a0.w *= xp[3];
                a1.x *= xp[4]; a1.y *= xp[5]; a1.z *= xp[6]; a1.w *= xp[7];
            } else {
                a0.x -= xp[0]; a0.y -= xp[1]; a0.z -= xp[2]; a0.w -= xp[3];
                a1.x -= xp[4]; a1.y -= xp[5]; a1.z -= xp[6]; a1.w -= xp[7];
            }
            As[sf+0][sm] = a0.x; As[sf+1][sm] = a0.y; As[sf+2][sm] = a0.z; As[sf+3][sm] = a0.w;
            As[sf+4][sm] = a1.x; As[sf+5][sm] = a1.y; As[sf+6][sm] = a1.z; As[sf+7][sm] = a1.w;
        }
        {
            const float* wp = W + (size_t)se * 256 + f0 + sfw;
            #pragma unroll
            for (int k4 = 0; k4 < 4; ++k4){
                float4 w4 = *(const float4*)(wp + k4*4);
                Ws[sfw+k4*4+0][se] = w4.x; Ws[sfw+k4*4+1][se] = w4.y;
                Ws[sfw+k4*4+2][se] = w4.z; Ws[sfw+k4*4+3][se] = w4.w;
            }
        }
        __syncthreads();
        #pragma unroll
        for (int f = 0; f < 32; ++f){
            float4 av = *(const float4*)&As[f][i*4];
            float4 b0 = *(const float4*)&Ws[f][j*8];
            float4 b1 = *(const float4*)&Ws[f][j*8+4];
            float ar[4] = {av.x, av.y, av.z, av.w};
            float bc[8] = {b0.x,b0.y,b0.z,b0.w,b1.x,b1.y,b1.z,b1.w};
            #pragma unroll
            for (int r = 0; r < 4; ++r)
                #pragma unroll
                for (int c = 0; c < 8; ++c)
                    acc[r][c] += ar[r] * bc[c];
        }
        __syncthreads();
    }

    #pragma unroll
    for (int r = 0; r < 4; ++r){
        float s = 0.f;
        #pragma unroll
        for (int c = 0; c < 8; ++c) s += vv[j*8 + c] * tanh_fast(acc[r][c]);
        sred[i*4 + r][j] = s;
    }
    __syncthreads();
    if (tid < 64){
        float s = 0.f;
        #pragma unroll
        for (int jj = 0; jj < 16; ++jj) s += sred[tid][jj];
        sc[((size_t)b*QL + q)*P + pt*64 + tid] = s;
    }
}

// softmax over scores + weighted sum
__global__ __launch_bounds__(256) void k_att_apply(const float* __restrict__ sc,
                                                   const float* __restrict__ kv, int P,
                                                   int outOff, float* __restrict__ agg){
    int b = blockIdx.x >> 7, q = blockIdx.x & 127, tid = threadIdx.x;
    __shared__ float w[256], red[256];
    w[tid] = (tid < P) ? sc[((size_t)b*QL + q)*P + tid] : -1e30f;
    __syncthreads();
    softmax256(w, red, tid);
    const float* kvb = kv + (size_t)b*P*256;
    float o = 0.f;
    #pragma unroll 4
    for (int p = 0; p < P; ++p) o += w[p] * kvb[(size_t)p*256 + tid];
    agg[((size_t)b*QL + q)*1536 + outOff + tid] = o;
}

__global__ __launch_bounds__(256) void k_copy_hp(const float* __restrict__ hp,
                                                 float* __restrict__ agg){
    int i = blockIdx.x, tid = threadIdx.x;
    agg[(size_t)i*1536 + tid] = hp[(size_t)i*256 + tid];
}

// ---------------------------------------------------------------------------
__global__ __launch_bounds__(256) void k_q_att(const float* __restrict__ Cq,
                                               const float* __restrict__ vq,
                                               const float* __restrict__ hq,
                                               float* __restrict__ rq){
    int b = blockIdx.x, tid = threadIdx.x;
    __shared__ float vv[EE], sc[256], red[256];
    if (tid < EE) vv[tid] = vq[tid];
    __syncthreads();
    const float* cb = Cq + ((size_t)b*PL + tid)*EE;
    float s = 0.f;
    #pragma unroll 4
    for (int e = 0; e < EE; ++e) s += vv[e] * tanh_fast(cb[e]);
    sc[tid] = s;
    __syncthreads();
    softmax256(sc, red, tid);
    float o = 0.f;
    const float* hqb = hq + (size_t)b*PL*256;
    for (int p = 0; p < PL; ++p) o += sc[p] * hqb[(size_t)p*256 + tid];
    rq[(size_t)b*256 + tid] = o;
}

__global__ __launch_bounds__(256) void k_p_att(const float* __restrict__ Gp,
                                               const float* __restrict__ vp,
                                               const float* __restrict__ rqW,
                                               const float* __restrict__ agg_rep,
                                               float* __restrict__ rp){
    int b = blockIdx.x, tid = threadIdx.x;
    __shared__ float vv[EE], rw[EE], sc[256], red[256];
    if (tid < EE){
        vv[tid] = vp[tid];
        rw[tid] = rqW[(size_t)b*EE + tid];
    }
    if (tid >= 128) sc[tid] = -1e30f;
    __syncthreads();
    if (tid < QL){
        const float* gp = Gp + ((size_t)b*QL + tid)*EE;
        float s = 0.f;
        for (int e = 0; e < EE; ++e) s += vv[e] * (gp[e] + rw[e]);
        sc[tid] = s;
    }
    __syncthreads();
    softmax256(sc, red, tid);
    float o = 0.f;
    const float* ab = agg_rep + (size_t)b*QL*256;
    for (int q = 0; q < QL; ++q) o += sc[q] * ab[(size_t)q*256 + tid];
    rp[(size_t)b*256 + tid] = o;
}

__global__ __launch_bounds__(256) void k_final(const float* __restrict__ rp,
                                               const float* __restrict__ Wpred,
                                               const float* __restrict__ a_emb,
                                               float* __restrict__ out){
    int b = blockIdx.x, tid = threadIdx.x;
    __shared__ float rpv[256], enc[256];
    rpv[tid] = rp[(size_t)b*256 + tid];
    __syncthreads();
    const float* wr = Wpred + (size_t)tid*256;
    float s = 0.f;
    #pragma unroll 4
    for (int e = 0; e < 256; ++e) s += wr[e] * rpv[e];
    enc[tid] = (s > 0.f) ? s : 0.01f * s;
    __syncthreads();
    if (tid < 3){
        const float* ae = a_emb + ((size_t)b*3 + tid)*256;
        float o = 0.f;
        for (int e = 0; e < 256; ++e) o += ae[e] * enc[e];
        out[b*3 + tid] = o;
    }
}

// ---------------------------------------------------------------------------
extern "C" void kernel_launch(void* const* d_in, const int* in_sizes, int n_in,
                              void* d_out, int out_size, void* d_ws, size_t ws_size,
                              hipStream_t stream){
    const float* emb   = (const float*)d_in[0];
    const float* a_att = (const float*)d_in[1];
    const float* Wc1   = (const float*)d_in[2];
    const float* Wc2   = (const float*)d_in[3];
    const float* vc    = (const float*)d_in[4];
    const float* Wb    = (const float*)d_in[5];
    const float* Wd    = (const float*)d_in[6];
    const float* vd    = (const float*)d_in[7];
    const float* Wm    = (const float*)d_in[8];
    const float* vm    = (const float*)d_in[9];
    const float* Ws    = (const float*)d_in[10];
    const float* vs    = (const float*)d_in[11];
    const float* Wq    = (const float*)d_in[12];
    const float* vq    = (const float*)d_in[13];
    const float* Wp1   = (const float*)d_in[14];
    const float* Wp2   = (const float*)d_in[15];
    const float* vp    = (const float*)d_in[16];
    const float* Wpred = (const float*)d_in[17];
    const float* q_Wih = (const float*)d_in[18];
    const float* q_Whh = (const float*)d_in[19];
    const float* q_bih = (const float*)d_in[20];
    const float* q_bhh = (const float*)d_in[21];
    const float* p_Wih = (const float*)d_in[22];
    const float* p_Whh = (const float*)d_in[23];
    const float* p_bih = (const float*)d_in[24];
    const float* p_bhh = (const float*)d_in[25];
    const float* a_Wih = (const float*)d_in[26];
    const float* a_Whh = (const float*)d_in[27];
    const float* a_bih = (const float*)d_in[28];
    const float* a_bhh = (const float*)d_in[29];
    const float* g_Wih = (const float*)d_in[30];
    const float* g_Whh = (const float*)d_in[31];
    const float* g_bih = (const float*)d_in[32];
    const float* g_bhh = (const float*)d_in[33];
    const int* query   = (const int*)d_in[34];
    const int* passage = (const int*)d_in[35];
    const int* cneg    = (const int*)d_in[36];
    const int* cpos    = (const int*)d_in[37];
    const int* cna     = (const int*)d_in[38];

    float* ws = (float*)d_ws;

    // 1. embedding gathers
    k_gather<<<BB*PL, 256, 0, stream>>>(passage, emb, ws + O_XPASS);
    k_gather<<<BB*QL, 256, 0, stream>>>(query,   emb, ws + O_XQUERY);
    k_gather<<<BB*AL, 256, 0, stream>>>(cneg, emb, ws + O_XCAND + 0*20480);
    k_gather<<<BB*AL, 256, 0, stream>>>(cpos, emb, ws + O_XCAND + 1*20480);
    k_gather<<<BB*AL, 256, 0, stream>>>(cna,  emb, ws + O_XCAND + 2*20480);

    // 2. input preactivations (x @ Wih^T + bih), z = direction
    k_gemm_v2<<<dim3(6,32,2), 256, 0, stream>>>(ws+O_XPASS, q_Wih, q_bih, ws+O_PREQ,
                                                2048, 384, 256, 98304LL, 786432LL, 384LL);
    k_gemm_v2<<<dim3(6,16,2), 256, 0, stream>>>(ws+O_XQUERY, p_Wih, p_bih, ws+O_PREP,
                                                1024, 384, 256, 98304LL, 393216LL, 384LL);
    for (int c = 0; c < 3; ++c)
        k_gemm_v2<<<dim3(6,2,2), 256, 0, stream>>>(ws+O_XCAND + c*20480, a_Wih, a_bih,
                                                   ws+O_PREA + c*61440,
                                                   80, 384, 256, 98304LL, 30720LL, 384LL);

    // 3. GRU scans (256 threads now)
    k_gru_scan<<<16, 256, 0, stream>>>(ws+O_PREQ, q_Whh, q_bhh, ws+O_HQ, 256, 0, 0);
    k_gru_scan<<<16, 256, 0, stream>>>(ws+O_PREP, p_Whh, p_bhh, ws+O_HP, 128, 0, 0);
    k_gru_scan<<<48, 256, 0, stream>>>(ws+O_PREA, a_Whh, a_bhh, ws+O_HCAND, 10, 61440, 20480);

    // 4. candidate pooling
    k_cand_att<<<24, 256, 0, stream>>>(ws+O_HCAND, a_att, ws+O_AEMB);

    // 5. projection GEMMs
    k_gemm_v2<<<dim3(2,32,1), 256, 0, stream>>>(ws+O_HQ, Wc1, nullptr, ws+O_AQ, 2048,128,256, 0,0,0);
    k_gemm_v2<<<dim3(2,16,1), 256, 0, stream>>>(ws+O_HP, Wc2, nullptr, ws+O_AP, 1024,128,256, 0,0,0);
    k_gemm_v2<<<dim3(4,32,1), 256, 0, stream>>>(ws+O_HQ, Wb,  nullptr, ws+O_BQ, 2048,256,256, 0,0,0);
    k_gemm_v2<<<dim3(2,32,1), 256, 0, stream>>>(ws+O_HQ, Wq,  nullptr, ws+O_CQ, 2048,128,256, 0,0,0);

    // 6. attention blocks -> agg slices
    // concat (qtc -> 512)
    k_att_cm<<<1024, 256, 0, stream>>>(ws+O_AQ, ws+O_AP, vc, ws+O_HQ, 1.f, 512, ws+O_AGG);
    // bilinear (qtb -> 1024)
    k_att_b<<<1024, 256, 0, stream>>>(ws+O_BQ, ws+O_HP, ws+O_HQ, ws+O_AGG);
    // dot (qtd -> 768)
    k_dms_score<<<dim3(4,128,8), 256, 0, stream>>>(ws+O_HQ, 256, Wd, vd, ws+O_HP, 0, ws+O_SCORE);
    k_att_apply<<<1024, 256, 0, stream>>>(ws+O_SCORE, ws+O_HQ, 256,  768, ws+O_AGG);
    // minus, factored: Mq = hq@Wm^T, Mp = hp@Wm^T, then additive att (qtm -> 1280)
    k_gemm_v2<<<dim3(2,32,1), 256, 0, stream>>>(ws+O_HQ, Wm, nullptr, ws+O_SCORE, 2048,128,256, 0,0,0);
    k_gemm_v2<<<dim3(2,16,1), 256, 0, stream>>>(ws+O_HP, Wm, nullptr, ws+O_MP,    1024,128,256, 0,0,0);
    k_att_cm<<<1024, 256, 0, stream>>>(ws+O_SCORE, ws+O_MP, vm, ws+O_HQ, -1.f, 1280, ws+O_AGG);
    // self (qts -> 256)
    k_dms_score<<<dim3(2,128,8), 256, 0, stream>>>(ws+O_HP, 128, Ws, vs, ws+O_HP, 0, ws+O_SCB);
    k_att_apply<<<1024, 256, 0, stream>>>(ws+O_SCB, ws+O_HP, 128,  256, ws+O_AGG);
    k_copy_hp<<<1024, 256, 0, stream>>>(ws+O_HP, ws+O_AGG);

    // 7. aggregation bigru
    k_gemm_v2<<<dim3(6,16,2), 256, 0, stream>>>(ws+O_AGG, g_Wih, g_bih, ws+O_PREG,
                                                1024, 384, 1536, 589824LL, 393216LL, 384LL);
    k_gru_scan<<<16, 256, 0, stream>>>(ws+O_PREG, g_Whh, g_bhh, ws+O_AGGREP, 128, 0, 0);

    // 8. pooling + prediction
    k_q_att<<<8, 256, 0, stream>>>(ws+O_CQ, vq, ws+O_HQ, ws+O_RQ);
    k_gemm_v2<<<dim3(2,16,1), 256, 0, stream>>>(ws+O_AGGREP, Wp1, nullptr, ws+O_GP, 1024,128,256, 0,0,0);
    k_gemm_v2<<<dim3(2,1,1),  256, 0, stream>>>(ws+O_RQ, Wp2, nullptr, ws+O_RQW, 8,128,256, 0,0,0);
    k_p_att<<<8, 256, 0, stream>>>(ws+O_GP, vp, ws+O_RQW, ws+O_AGGREP, ws+O_RP);
    k_final<<<8, 256, 0, stream>>>(ws+O_RP, Wpred, ws+O_AEMB, (float*)d_out);
}

// Round 6
// 1390.376 us; speedup vs baseline: 2.9912x; 1.1104x over previous
//
#include <hip/hip_runtime.h>
#include <hip/hip_bf16.h>

// ---------------------------------------------------------------------------
// MwAN forward, MI355X. B=8, QL=128, PL=256, AL=10, E=128, EMB=256.
// Inputs fp32; internal compute fp32 in d_ws; output fp32.
// R6: dms score GEMMs (dot/self) moved to bf16 MFMA (16x16x32). W fragments
// cached entirely in registers; A fragments (elementwise product) built
// in-register from a bf16 LDS tile in fragment-pattern layout.
// ---------------------------------------------------------------------------

#define BB 8
#define QL 128
#define PL 256
#define AL 10
#define EE 128
#define EMB 256
#define G3 384   // 3*H gates
#define HH 128   // hidden

// ---- ws layout (in floats) ----
#define O_XPASS   ((size_t)0)        // (8,256,256)  -- dead after pre-GEMMs; reused
#define O_XQUERY  ((size_t)524288)   // (8,128,256)  -- dead after pre-GEMMs; reused for Mp
#define O_XCAND   ((size_t)786432)   // 3 x (8,10,256), chunk 20480
#define O_PREQ    ((size_t)847872)   // (2,8,256,384)
#define O_PREP    ((size_t)2420736)  // (2,8,128,384)
#define O_PREA    ((size_t)3207168)  // 3 x (2,8,10,384), chunk 61440
#define O_PREG    ((size_t)3391488)  // (2,8,128,384)
#define O_HQ      ((size_t)4177920)  // (8,256,256)
#define O_HP      ((size_t)4702208)  // (8,128,256)
#define O_HCAND   ((size_t)4964352)  // 3 x (8,10,256), chunk 20480
#define O_AEMB    ((size_t)5025792)  // (8,3,256)
#define O_AQ      ((size_t)5031936)  // (8,256,128)
#define O_AP      ((size_t)5294080)  // (8,128,128)
#define O_BQ      ((size_t)5425152)  // (8,256,256)
#define O_AGG     ((size_t)5949440)  // (8,128,1536)
#define O_AGGREP  ((size_t)7522304)  // (8,128,256)
#define O_CQ      ((size_t)7784448)  // (8,256,128)
#define O_GP      ((size_t)8046592)  // (8,128,128)
#define O_RQ      ((size_t)8177664)  // (8,256)
#define O_RQW     ((size_t)8179712)  // (8,128)
#define O_RP      ((size_t)8180736)  // (8,256)
#define O_SCORE   O_XPASS                    // (8,128,256) dot scores / then Mq
#define O_SCB     (O_XPASS + (size_t)262144) // (8,128,128) self scores
#define O_MP      O_XQUERY                   // (8,128,128) Mp = hp@Wm^T

typedef __attribute__((ext_vector_type(8))) short bf16x8;
typedef __attribute__((ext_vector_type(4))) float f32x4;
union U4 { uint4 u; bf16x8 v; };

__device__ __forceinline__ float tanh_fast(float x){
    x = fminf(fmaxf(x, -20.f), 20.f);
    float e = __expf(2.f * x);
    return (e - 1.f) / (e + 1.f);
}
__device__ __forceinline__ float sig_fast(float x){
    return 1.f / (1.f + __expf(-x));
}
// pack two fp32 -> bf16 pair (round-half-up)
__device__ __forceinline__ unsigned pk2(float a, float b){
    unsigned ua = __float_as_uint(a), ub = __float_as_uint(b);
    return ((ua + 0x8000u) >> 16) | ((ub + 0x8000u) & 0xffff0000u);
}

// softmax over sc[0..255], 256 lanes
__device__ __forceinline__ void softmax256(float* sc, float* red, int tid){
    float v = sc[tid];
    red[tid] = v;
    __syncthreads();
    for (int s = 128; s > 0; s >>= 1){
        if (tid < s) red[tid] = fmaxf(red[tid], red[tid + s]);
        __syncthreads();
    }
    float m = red[0];
    __syncthreads();
    float e = __expf(v - m);
    red[tid] = e;
    __syncthreads();
    for (int s = 128; s > 0; s >>= 1){
        if (tid < s) red[tid] += red[tid + s];
        __syncthreads();
    }
    float inv = 1.f / red[0];
    __syncthreads();
    sc[tid] = e * inv;
    __syncthreads();
}

// ---------------------------------------------------------------------------
__global__ __launch_bounds__(256) void k_gather(const int* __restrict__ ids,
                                                const float* __restrict__ emb,
                                                float* __restrict__ out){
    int i = blockIdx.x, e = threadIdx.x;
    int id = ids[i];
    out[(size_t)i * EMB + e] = emb[(size_t)id * EMB + e];
}

// ---------------------------------------------------------------------------
// Register-tiled GEMM-NT: C[m,n] = sum_k A[m,k]*B[n,k] + bias[n].
// 64x64 tile, 256 threads, 4x4 fragment, K-chunk 32. K%32==0, N%64==0.
__global__ __launch_bounds__(256) void k_gemm_v2(const float* __restrict__ A,
                                                 const float* __restrict__ Bm,
                                                 const float* __restrict__ bias,
                                                 float* __restrict__ C,
                                                 int M, int N, int K,
                                                 long long strideB, long long strideC,
                                                 long long strideBias){
    int z = blockIdx.z;
    Bm += (size_t)z * strideB;
    C  += (size_t)z * strideC;
    if (bias) bias += (size_t)z * strideBias;

    __shared__ float As[32][68];
    __shared__ float Bs[32][68];

    int tid = threadIdx.x;
    int i = tid & 15;
    int j = tid >> 4;
    int m0 = blockIdx.y * 64;
    int n0 = blockIdx.x * 64;

    int sm = tid & 63;
    int sk = (tid >> 6) * 8;

    float acc[4][4];
    #pragma unroll
    for (int r = 0; r < 4; ++r)
        #pragma unroll
        for (int c = 0; c < 4; ++c) acc[r][c] = 0.f;

    for (int k0 = 0; k0 < K; k0 += 32){
        float4 a0 = make_float4(0,0,0,0), a1 = make_float4(0,0,0,0);
        if (m0 + sm < M){
            const float* ap = A + (size_t)(m0 + sm) * K + k0 + sk;
            a0 = *(const float4*)ap;
            a1 = *(const float4*)(ap + 4);
        }
        As[sk+0][sm] = a0.x; As[sk+1][sm] = a0.y; As[sk+2][sm] = a0.z; As[sk+3][sm] = a0.w;
        As[sk+4][sm] = a1.x; As[sk+5][sm] = a1.y; As[sk+6][sm] = a1.z; As[sk+7][sm] = a1.w;
        {
            const float* bp = Bm + (size_t)(n0 + sm) * K + k0 + sk;
            float4 b0 = *(const float4*)bp;
            float4 b1 = *(const float4*)(bp + 4);
            Bs[sk+0][sm] = b0.x; Bs[sk+1][sm] = b0.y; Bs[sk+2][sm] = b0.z; Bs[sk+3][sm] = b0.w;
            Bs[sk+4][sm] = b1.x; Bs[sk+5][sm] = b1.y; Bs[sk+6][sm] = b1.z; Bs[sk+7][sm] = b1.w;
        }
        __syncthreads();
        #pragma unroll
        for (int f = 0; f < 32; ++f){
            float4 av = *(const float4*)&As[f][i*4];
            float4 bv = *(const float4*)&Bs[f][j*4];
            float ar[4] = {av.x, av.y, av.z, av.w};
            float bc[4] = {bv.x, bv.y, bv.z, bv.w};
            #pragma unroll
            for (int r = 0; r < 4; ++r)
                #pragma unroll
                for (int c = 0; c < 4; ++c)
                    acc[r][c] += ar[r] * bc[c];
        }
        __syncthreads();
    }

    float4 bv = make_float4(0,0,0,0);
    if (bias) bv = *(const float4*)&bias[n0 + j*4];
    #pragma unroll
    for (int r = 0; r < 4; ++r){
        int row = m0 + i*4 + r;
        if (row < M){
            float4 o;
            o.x = acc[r][0] + bv.x;
            o.y = acc[r][1] + bv.y;
            o.z = acc[r][2] + bv.z;
            o.w = acc[r][3] + bv.w;
            *(float4*)&C[(size_t)row * N + n0 + j*4] = o;
        }
    }
}

// ---------------------------------------------------------------------------
// GRU scan, gate-owner layout (R5). One WG of 256 per (chunk,b,dir).
__global__ __launch_bounds__(256, 1) void k_gru_scan(const float* __restrict__ pre,
                                                     const float* __restrict__ Whh,
                                                     const float* __restrict__ bhh,
                                                     float* __restrict__ out,
                                                     int T, int preChunk, int outChunk){
    int idx = blockIdx.x;
    int c = idx >> 4, bd = idx & 15, b = bd >> 1, d = bd & 1;
    pre += (size_t)c * preChunk;
    out += (size_t)c * outChunk;

    int tid = threadIdx.x;
    int jp = tid >> 2, quarter = tid & 3;
    int j0 = jp * 2;
    int cb = quarter * 32;

    float wgt[6][32];
    const float* wb = Whh + (size_t)d * G3 * HH;
    #pragma unroll
    for (int G = 0; G < 3; ++G)
        #pragma unroll
        for (int jj = 0; jj < 2; ++jj){
            const float4* p4 = (const float4*)(wb + (size_t)(G*HH + j0 + jj) * HH + cb);
            #pragma unroll
            for (int kk = 0; kk < 8; ++kk){
                float4 u = p4[kk];
                wgt[G*2+jj][kk*4+0] = u.x; wgt[G*2+jj][kk*4+1] = u.y;
                wgt[G*2+jj][kk*4+2] = u.z; wgt[G*2+jj][kk*4+3] = u.w;
            }
        }
    const float* bb = bhh + d * G3;
    float bgr0 = bb[j0],        bgr1 = bb[j0+1];
    float bgz0 = bb[HH+j0],     bgz1 = bb[HH+j0+1];
    float bgn0 = bb[2*HH+j0],   bgn1 = bb[2*HH+j0+1];

    __shared__ __align__(16) float h_s[2][HH];
    if (tid < HH) h_s[0][tid] = 0.f;
    float hp0 = 0.f, hp1 = 0.f;

    const float* ptB = pre + ((size_t)d * BB + b) * (size_t)T * G3;
    float* ob = out + (size_t)b * T * 256 + d * HH;

    const float* pt0 = ptB + (size_t)(d ? (T-1) : 0) * G3;
    float2 pr = *(const float2*)(pt0 + j0);
    float2 pz = *(const float2*)(pt0 + HH + j0);
    float2 pn = *(const float2*)(pt0 + 2*HH + j0);
    __syncthreads();

    for (int step = 0; step < T; ++step){
        int t = d ? (T-1-step) : step;
        float2 nr = make_float2(0.f,0.f), nz = nr, nn = nr;
        if (step + 1 < T){
            int tn = d ? (T-2-step) : (step+1);
            const float* ptn = ptB + (size_t)tn * G3;
            nr = *(const float2*)(ptn + j0);
            nz = *(const float2*)(ptn + HH + j0);
            nn = *(const float2*)(ptn + 2*HH + j0);
        }
        int rb = step & 1;
        const float4* h4 = (const float4*)&h_s[rb][cb];
        float ar0=0.f, ar1=0.f, az0=0.f, az1=0.f, an0=0.f, an1=0.f;
        #pragma unroll
        for (int kk = 0; kk < 8; ++kk){
            float4 hv = h4[kk];
            ar0 = fmaf(wgt[0][kk*4+0], hv.x, ar0); ar0 = fmaf(wgt[0][kk*4+1], hv.y, ar0);
            ar0 = fmaf(wgt[0][kk*4+2], hv.z, ar0); ar0 = fmaf(wgt[0][kk*4+3], hv.w, ar0);
            ar1 = fmaf(wgt[1][kk*4+0], hv.x, ar1); ar1 = fmaf(wgt[1][kk*4+1], hv.y, ar1);
            ar1 = fmaf(wgt[1][kk*4+2], hv.z, ar1); ar1 = fmaf(wgt[1][kk*4+3], hv.w, ar1);
            az0 = fmaf(wgt[2][kk*4+0], hv.x, az0); az0 = fmaf(wgt[2][kk*4+1], hv.y, az0);
            az0 = fmaf(wgt[2][kk*4+2], hv.z, az0); az0 = fmaf(wgt[2][kk*4+3], hv.w, az0);
            az1 = fmaf(wgt[3][kk*4+0], hv.x, az1); az1 = fmaf(wgt[3][kk*4+1], hv.y, az1);
            az1 = fmaf(wgt[3][kk*4+2], hv.z, az1); az1 = fmaf(wgt[3][kk*4+3], hv.w, az1);
            an0 = fmaf(wgt[4][kk*4+0], hv.x, an0); an0 = fmaf(wgt[4][kk*4+1], hv.y, an0);
            an0 = fmaf(wgt[4][kk*4+2], hv.z, an0); an0 = fmaf(wgt[4][kk*4+3], hv.w, an0);
            an1 = fmaf(wgt[5][kk*4+0], hv.x, an1); an1 = fmaf(wgt[5][kk*4+1], hv.y, an1);
            an1 = fmaf(wgt[5][kk*4+2], hv.z, an1); an1 = fmaf(wgt[5][kk*4+3], hv.w, an1);
        }
        ar0 += __shfl_xor(ar0, 1); ar0 += __shfl_xor(ar0, 2);
        ar1 += __shfl_xor(ar1, 1); ar1 += __shfl_xor(ar1, 2);
        az0 += __shfl_xor(az0, 1); az0 += __shfl_xor(az0, 2);
        az1 += __shfl_xor(az1, 1); az1 += __shfl_xor(az1, 2);
        an0 += __shfl_xor(an0, 1); an0 += __shfl_xor(an0, 2);
        an1 += __shfl_xor(an1, 1); an1 += __shfl_xor(an1, 2);

        float r0 = sig_fast(pr.x + ar0 + bgr0);
        float z0 = sig_fast(pz.x + az0 + bgz0);
        float n0 = tanh_fast(pn.x + r0 * (an0 + bgn0));
        float h0 = n0 + z0 * (hp0 - n0);
        float r1 = sig_fast(pr.y + ar1 + bgr1);
        float z1 = sig_fast(pz.y + az1 + bgz1);
        float n1 = tanh_fast(pn.y + r1 * (an1 + bgn1));
        float h1 = n1 + z1 * (hp1 - n1);
        hp0 = h0; hp1 = h1;

        if (quarter == 0) *(float2*)&h_s[1-rb][j0] = make_float2(h0, h1);
        if (quarter == 1) *(float2*)&ob[(size_t)t * 256 + j0] = make_float2(h0, h1);
        pr = nr; pz = nz; pn = nn;
        __syncthreads();
    }
}

// ---------------------------------------------------------------------------
__global__ __launch_bounds__(256) void k_cand_att(const float* __restrict__ h,
                                                  const float* __restrict__ a_att,
                                                  float* __restrict__ a_emb){
    int c = blockIdx.x / BB, b = blockIdx.x % BB, tid = threadIdx.x;
    __shared__ float att[256], sc[AL], sw[AL];
    att[tid] = a_att[tid];
    __syncthreads();
    const float* hb = h + (size_t)c * (BB*AL*256) + (size_t)b * (AL*256);
    if (tid < AL){
        float s = 0.f;
        for (int e = 0; e < 256; ++e) s += hb[tid*256 + e] * att[e];
        sc[tid] = s;
    }
    __syncthreads();
    if (tid == 0){
        float m = -1e30f;
        for (int t = 0; t < AL; ++t) m = fmaxf(m, sc[t]);
        float s = 0.f;
        for (int t = 0; t < AL; ++t){ sw[t] = __expf(sc[t] - m); s += sw[t]; }
        float inv = 1.f / s;
        for (int t = 0; t < AL; ++t) sw[t] *= inv;
    }
    __syncthreads();
    float o = 0.f;
    for (int t = 0; t < AL; ++t) o += sw[t] * hb[t*256 + tid];
    a_emb[((size_t)b*3 + c) * 256 + tid] = o;
}

// ---------------------------------------------------------------------------
// additive attention: score[p] = sum_e v[e]*tanh(Aq[b,p,e] + sign*Ap[b,q,e]);
__global__ __launch_bounds__(256) void k_att_cm(const float* __restrict__ Aq,
                                                const float* __restrict__ Ap,
                                                const float* __restrict__ v,
                                                const float* __restrict__ vals,
                                                float sign, int outOff,
                                                float* __restrict__ agg){
    int b = blockIdx.x >> 7, q = blockIdx.x & 127, tid = threadIdx.x;
    __shared__ float apv[EE], vcv[EE], sc[256], red[256];
    if (tid < EE){
        apv[tid] = sign * Ap[((size_t)b*QL + q)*EE + tid];
        vcv[tid] = v[tid];
    }
    __syncthreads();
    const float* aqp = Aq + ((size_t)b*PL + tid)*EE;
    float s = 0.f;
    #pragma unroll 4
    for (int e = 0; e < EE; ++e) s += vcv[e] * tanh_fast(aqp[e] + apv[e]);
    sc[tid] = s;
    __syncthreads();
    softmax256(sc, red, tid);
    float o = 0.f;
    const float* vb = vals + (size_t)b*PL*256;
    for (int p = 0; p < PL; ++p) o += sc[p] * vb[(size_t)p*256 + tid];
    agg[((size_t)b*QL + q)*1536 + outOff + tid] = o;
}

// bilinear attention
__global__ __launch_bounds__(256) void k_att_b(const float* __restrict__ Bq,
                                               const float* __restrict__ hp,
                                               const float* __restrict__ hq,
                                               float* __restrict__ agg){
    int b = blockIdx.x >> 7, q = blockIdx.x & 127, tid = threadIdx.x;
    __shared__ float xq[256], sc[256], red[256];
    xq[tid] = hp[((size_t)b*QL + q)*256 + tid];
    __syncthreads();
    const float* bq = Bq + ((size_t)b*PL + tid)*256;
    float s = 0.f;
    #pragma unroll 4
    for (int e = 0; e < 256; ++e) s += xq[e] * bq[e];
    sc[tid] = s;
    __syncthreads();
    softmax256(sc, red, tid);
    float o = 0.f;
    const float* hqb = hq + (size_t)b*PL*256;
    for (int p = 0; p < PL; ++p) o += sc[p] * hqb[(size_t)p*256 + tid];
    agg[((size_t)b*QL + q)*1536 + 1024 + tid] = o;
}

// ---------------------------------------------------------------------------
// MFMA dms scores: sc[b,q,p] = sum_e v[e]*tanh( sum_f W[e,f]*kv[b,p,f]*xq[b,q,f] )
// Grid (P/64, QL/qPerBlock, BB), 256 threads (4 waves; wave owns 16 p-rows).
// W fragments (8 e-tiles x 8 k-steps) cached in registers; kv tile staged to
// LDS as bf16 in MFMA A-fragment order; A = kv ⊙ xq built in registers per q.
__global__ __launch_bounds__(256, 1) void k_dms_mfma(const float* __restrict__ kv, int P,
                                                     const float* __restrict__ Wmat,
                                                     const float* __restrict__ v,
                                                     const float* __restrict__ xsrc,
                                                     int qPerBlock,
                                                     float* __restrict__ sc){
    int pt = blockIdx.x, qc = blockIdx.y, b = blockIdx.z;
    int tid = threadIdx.x;
    int w = tid >> 6, lane = tid & 63, m = lane & 15, quad = lane >> 4;

    __shared__ unsigned Hlds[64 * 132];   // 64 rows x 256 bf16, stride 132 words
    __shared__ float hpq[256];

    // stage kv tile (64 p-rows) as bf16, fragment-pattern layout
    {
        const float* hr = kv + ((size_t)b * P + pt * 64 + w * 16 + m) * 256;
        unsigned* dst = &Hlds[(w * 16 + m) * 132];
        #pragma unroll
        for (int k0 = 0; k0 < 8; ++k0){
            const float* p0 = hr + k0 * 32 + quad * 8;
            float4 x0 = *(const float4*)p0;
            float4 x1 = *(const float4*)(p0 + 4);
            uint4 u;
            u.x = pk2(x0.x, x0.y); u.y = pk2(x0.z, x0.w);
            u.z = pk2(x1.x, x1.y); u.w = pk2(x1.z, x1.w);
            *(uint4*)&dst[k0 * 16 + quad * 4] = u;
        }
    }

    // W fragments -> registers, all 8 e-tiles x 8 k-steps
    bf16x8 bfr[8][8];
    #pragma unroll
    for (int et = 0; et < 8; ++et){
        const float* wr = Wmat + (size_t)(et * 16 + m) * 256;
        #pragma unroll
        for (int k0 = 0; k0 < 8; ++k0){
            const float* p0 = wr + k0 * 32 + quad * 8;
            float4 x0 = *(const float4*)p0;
            float4 x1 = *(const float4*)(p0 + 4);
            U4 uu;
            uu.u.x = pk2(x0.x, x0.y); uu.u.y = pk2(x0.z, x0.w);
            uu.u.z = pk2(x1.x, x1.y); uu.u.w = pk2(x1.z, x1.w);
            bfr[et][k0] = uu.v;
        }
    }
    float vreg[8];
    #pragma unroll
    for (int et = 0; et < 8; ++et) vreg[et] = v[et * 16 + m];

    __syncthreads();

    const unsigned* hrow = &Hlds[(w * 16 + m) * 132];

    for (int qi = 0; qi < qPerBlock; ++qi){
        int q = qc * qPerBlock + qi;
        __syncthreads();                       // prev iter's hpq readers done
        hpq[tid] = xsrc[((size_t)b * QL + q) * 256 + tid];
        __syncthreads();                       // hpq ready

        // A fragments: afr[k0] = bf16( kv_row ⊙ hpq ) k-strip
        bf16x8 afr[8];
        #pragma unroll
        for (int k0 = 0; k0 < 8; ++k0){
            uint4 hv = *(const uint4*)&hrow[k0 * 16 + quad * 4];
            const float* hf = &hpq[k0 * 32 + quad * 8];
            float f0 = __uint_as_float(hv.x << 16)         * hf[0];
            float f1 = __uint_as_float(hv.x & 0xffff0000u) * hf[1];
            float f2 = __uint_as_float(hv.y << 16)         * hf[2];
            float f3 = __uint_as_float(hv.y & 0xffff0000u) * hf[3];
            float f4 = __uint_as_float(hv.z << 16)         * hf[4];
            float f5 = __uint_as_float(hv.z & 0xffff0000u) * hf[5];
            float f6 = __uint_as_float(hv.w << 16)         * hf[6];
            float f7 = __uint_as_float(hv.w & 0xffff0000u) * hf[7];
            U4 uu;
            uu.u.x = pk2(f0, f1); uu.u.y = pk2(f2, f3);
            uu.u.z = pk2(f4, f5); uu.u.w = pk2(f6, f7);
            afr[k0] = uu.v;
        }

        f32x4 acc[8];
        #pragma unroll
        for (int et = 0; et < 8; ++et){
            acc[et][0] = 0.f; acc[et][1] = 0.f; acc[et][2] = 0.f; acc[et][3] = 0.f;
        }
        #pragma unroll
        for (int k0 = 0; k0 < 8; ++k0)
            #pragma unroll
            for (int et = 0; et < 8; ++et)
                acc[et] = __builtin_amdgcn_mfma_f32_16x16x32_bf16(afr[k0], bfr[et][k0], acc[et], 0, 0, 0);

        // epilogue: score over this lane's e-column, rows quad*4+r
        float p0 = 0.f, p1 = 0.f, p2 = 0.f, p3 = 0.f;
        #pragma unroll
        for (int et = 0; et < 8; ++et){
            p0 += vreg[et] * tanh_fast(acc[et][0]);
            p1 += vreg[et] * tanh_fast(acc[et][1]);
            p2 += vreg[et] * tanh_fast(acc[et][2]);
            p3 += vreg[et] * tanh_fast(acc[et][3]);
        }
        p0 += __shfl_xor(p0, 1); p0 += __shfl_xor(p0, 2); p0 += __shfl_xor(p0, 4); p0 += __shfl_xor(p0, 8);
        p1 += __shfl_xor(p1, 1); p1 += __shfl_xor(p1, 2); p1 += __shfl_xor(p1, 4); p1 += __shfl_xor(p1, 8);
        p2 += __shfl_xor(p2, 1); p2 += __shfl_xor(p2, 2); p2 += __shfl_xor(p2, 4); p2 += __shfl_xor(p2, 8);
        p3 += __shfl_xor(p3, 1); p3 += __shfl_xor(p3, 2); p3 += __shfl_xor(p3, 4); p3 += __shfl_xor(p3, 8);
        if (m == 0){
            float4 o = make_float4(p0, p1, p2, p3);
            *(float4*)&sc[((size_t)b * QL + q) * P + pt * 64 + w * 16 + quad * 4] = o;
        }
    }
}

// softmax over scores + weighted sum
__global__ __launch_bounds__(256) void k_att_apply(const float* __restrict__ sc,
                                                   const float* __restrict__ kv, int P,
                                                   int outOff, float* __restrict__ agg){
    int b = blockIdx.x >> 7, q = blockIdx.x & 127, tid = threadIdx.x;
    __shared__ float w[256], red[256];
    w[tid] = (tid < P) ? sc[((size_t)b*QL + q)*P + tid] : -1e30f;
    __syncthreads();
    softmax256(w, red, tid);
    const float* kvb = kv + (size_t)b*P*256;
    float o = 0.f;
    #pragma unroll 4
    for (int p = 0; p < P; ++p) o += w[p] * kvb[(size_t)p*256 + tid];
    agg[((size_t)b*QL + q)*1536 + outOff + tid] = o;
}

__global__ __launch_bounds__(256) void k_copy_hp(const float* __restrict__ hp,
                                                 float* __restrict__ agg){
    int i = blockIdx.x, tid = threadIdx.x;
    agg[(size_t)i*1536 + tid] = hp[(size_t)i*256 + tid];
}

// ---------------------------------------------------------------------------
__global__ __launch_bounds__(256) void k_q_att(const float* __restrict__ Cq,
                                               const float* __restrict__ vq,
                                               const float* __restrict__ hq,
                                               float* __restrict__ rq){
    int b = blockIdx.x, tid = threadIdx.x;
    __shared__ float vv[EE], sc[256], red[256];
    if (tid < EE) vv[tid] = vq[tid];
    __syncthreads();
    const float* cb = Cq + ((size_t)b*PL + tid)*EE;
    float s = 0.f;
    #pragma unroll 4
    for (int e = 0; e < EE; ++e) s += vv[e] * tanh_fast(cb[e]);
    sc[tid] = s;
    __syncthreads();
    softmax256(sc, red, tid);
    float o = 0.f;
    const float* hqb = hq + (size_t)b*PL*256;
    for (int p = 0; p < PL; ++p) o += sc[p] * hqb[(size_t)p*256 + tid];
    rq[(size_t)b*256 + tid] = o;
}

__global__ __launch_bounds__(256) void k_p_att(const float* __restrict__ Gp,
                                               const float* __restrict__ vp,
                                               const float* __restrict__ rqW,
                                               const float* __restrict__ agg_rep,
                                               float* __restrict__ rp){
    int b = blockIdx.x, tid = threadIdx.x;
    __shared__ float vv[EE], rw[EE], sc[256], red[256];
    if (tid < EE){
        vv[tid] = vp[tid];
        rw[tid] = rqW[(size_t)b*EE + tid];
    }
    if (tid >= 128) sc[tid] = -1e30f;
    __syncthreads();
    if (tid < QL){
        const float* gp = Gp + ((size_t)b*QL + tid)*EE;
        float s = 0.f;
        for (int e = 0; e < EE; ++e) s += vv[e] * (gp[e] + rw[e]);
        sc[tid] = s;
    }
    __syncthreads();
    softmax256(sc, red, tid);
    float o = 0.f;
    const float* ab = agg_rep + (size_t)b*QL*256;
    for (int q = 0; q < QL; ++q) o += sc[q] * ab[(size_t)q*256 + tid];
    rp[(size_t)b*256 + tid] = o;
}

__global__ __launch_bounds__(256) void k_final(const float* __restrict__ rp,
                                               const float* __restrict__ Wpred,
                                               const float* __restrict__ a_emb,
                                               float* __restrict__ out){
    int b = blockIdx.x, tid = threadIdx.x;
    __shared__ float rpv[256], enc[256];
    rpv[tid] = rp[(size_t)b*256 + tid];
    __syncthreads();
    const float* wr = Wpred + (size_t)tid*256;
    float s = 0.f;
    #pragma unroll 4
    for (int e = 0; e < 256; ++e) s += wr[e] * rpv[e];
    enc[tid] = (s > 0.f) ? s : 0.01f * s;
    __syncthreads();
    if (tid < 3){
        const float* ae = a_emb + ((size_t)b*3 + tid)*256;
        float o = 0.f;
        for (int e = 0; e < 256; ++e) o += ae[e] * enc[e];
        out[b*3 + tid] = o;
    }
}

// ---------------------------------------------------------------------------
extern "C" void kernel_launch(void* const* d_in, const int* in_sizes, int n_in,
                              void* d_out, int out_size, void* d_ws, size_t ws_size,
                              hipStream_t stream){
    const float* emb   = (const float*)d_in[0];
    const float* a_att = (const float*)d_in[1];
    const float* Wc1   = (const float*)d_in[2];
    const float* Wc2   = (const float*)d_in[3];
    const float* vc    = (const float*)d_in[4];
    const float* Wb    = (const float*)d_in[5];
    const float* Wd    = (const float*)d_in[6];
    const float* vd    = (const float*)d_in[7];
    const float* Wm    = (const float*)d_in[8];
    const float* vm    = (const float*)d_in[9];
    const float* Ws    = (const float*)d_in[10];
    const float* vs    = (const float*)d_in[11];
    const float* Wq    = (const float*)d_in[12];
    const float* vq    = (const float*)d_in[13];
    const float* Wp1   = (const float*)d_in[14];
    const float* Wp2   = (const float*)d_in[15];
    const float* vp    = (const float*)d_in[16];
    const float* Wpred = (const float*)d_in[17];
    const float* q_Wih = (const float*)d_in[18];
    const float* q_Whh = (const float*)d_in[19];
    const float* q_bih = (const float*)d_in[20];
    const float* q_bhh = (const float*)d_in[21];
    const float* p_Wih = (const float*)d_in[22];
    const float* p_Whh = (const float*)d_in[23];
    const float* p_bih = (const float*)d_in[24];
    const float* p_bhh = (const float*)d_in[25];
    const float* a_Wih = (const float*)d_in[26];
    const float* a_Whh = (const float*)d_in[27];
    const float* a_bih = (const float*)d_in[28];
    const float* a_bhh = (const float*)d_in[29];
    const float* g_Wih = (const float*)d_in[30];
    const float* g_Whh = (const float*)d_in[31];
    const float* g_bih = (const float*)d_in[32];
    const float* g_bhh = (const float*)d_in[33];
    const int* query   = (const int*)d_in[34];
    const int* passage = (const int*)d_in[35];
    const int* cneg    = (const int*)d_in[36];
    const int* cpos    = (const int*)d_in[37];
    const int* cna     = (const int*)d_in[38];

    float* ws = (float*)d_ws;

    // 1. embedding gathers
    k_gather<<<BB*PL, 256, 0, stream>>>(passage, emb, ws + O_XPASS);
    k_gather<<<BB*QL, 256, 0, stream>>>(query,   emb, ws + O_XQUERY);
    k_gather<<<BB*AL, 256, 0, stream>>>(cneg, emb, ws + O_XCAND + 0*20480);
    k_gather<<<BB*AL, 256, 0, stream>>>(cpos, emb, ws + O_XCAND + 1*20480);
    k_gather<<<BB*AL, 256, 0, stream>>>(cna,  emb, ws + O_XCAND + 2*20480);

    // 2. input preactivations (x @ Wih^T + bih), z = direction
    k_gemm_v2<<<dim3(6,32,2), 256, 0, stream>>>(ws+O_XPASS, q_Wih, q_bih, ws+O_PREQ,
                                                2048, 384, 256, 98304LL, 786432LL, 384LL);
    k_gemm_v2<<<dim3(6,16,2), 256, 0, stream>>>(ws+O_XQUERY, p_Wih, p_bih, ws+O_PREP,
                                                1024, 384, 256, 98304LL, 393216LL, 384LL);
    for (int c = 0; c < 3; ++c)
        k_gemm_v2<<<dim3(6,2,2), 256, 0, stream>>>(ws+O_XCAND + c*20480, a_Wih, a_bih,
                                                   ws+O_PREA + c*61440,
                                                   80, 384, 256, 98304LL, 30720LL, 384LL);

    // 3. GRU scans
    k_gru_scan<<<16, 256, 0, stream>>>(ws+O_PREQ, q_Whh, q_bhh, ws+O_HQ, 256, 0, 0);
    k_gru_scan<<<16, 256, 0, stream>>>(ws+O_PREP, p_Whh, p_bhh, ws+O_HP, 128, 0, 0);
    k_gru_scan<<<48, 256, 0, stream>>>(ws+O_PREA, a_Whh, a_bhh, ws+O_HCAND, 10, 61440, 20480);

    // 4. candidate pooling
    k_cand_att<<<24, 256, 0, stream>>>(ws+O_HCAND, a_att, ws+O_AEMB);

    // 5. projection GEMMs
    k_gemm_v2<<<dim3(2,32,1), 256, 0, stream>>>(ws+O_HQ, Wc1, nullptr, ws+O_AQ, 2048,128,256, 0,0,0);
    k_gemm_v2<<<dim3(2,16,1), 256, 0, stream>>>(ws+O_HP, Wc2, nullptr, ws+O_AP, 1024,128,256, 0,0,0);
    k_gemm_v2<<<dim3(4,32,1), 256, 0, stream>>>(ws+O_HQ, Wb,  nullptr, ws+O_BQ, 2048,256,256, 0,0,0);
    k_gemm_v2<<<dim3(2,32,1), 256, 0, stream>>>(ws+O_HQ, Wq,  nullptr, ws+O_CQ, 2048,128,256, 0,0,0);

    // 6. attention blocks -> agg slices
    // concat (qtc -> 512)
    k_att_cm<<<1024, 256, 0, stream>>>(ws+O_AQ, ws+O_AP, vc, ws+O_HQ, 1.f, 512, ws+O_AGG);
    // bilinear (qtb -> 1024)
    k_att_b<<<1024, 256, 0, stream>>>(ws+O_BQ, ws+O_HP, ws+O_HQ, ws+O_AGG);
    // dot (qtd -> 768): MFMA scores
    k_dms_mfma<<<dim3(4,8,8), 256, 0, stream>>>(ws+O_HQ, 256, Wd, vd, ws+O_HP, 16, ws+O_SCORE);
    k_att_apply<<<1024, 256, 0, stream>>>(ws+O_SCORE, ws+O_HQ, 256,  768, ws+O_AGG);
    // minus, factored: Mq = hq@Wm^T, Mp = hp@Wm^T, then additive att (qtm -> 1280)
    k_gemm_v2<<<dim3(2,32,1), 256, 0, stream>>>(ws+O_HQ, Wm, nullptr, ws+O_SCORE, 2048,128,256, 0,0,0);
    k_gemm_v2<<<dim3(2,16,1), 256, 0, stream>>>(ws+O_HP, Wm, nullptr, ws+O_MP,    1024,128,256, 0,0,0);
    k_att_cm<<<1024, 256, 0, stream>>>(ws+O_SCORE, ws+O_MP, vm, ws+O_HQ, -1.f, 1280, ws+O_AGG);
    // self (qts -> 256): MFMA scores
    k_dms_mfma<<<dim3(2,16,8), 256, 0, stream>>>(ws+O_HP, 128, Ws, vs, ws+O_HP, 8, ws+O_SCB);
    k_att_apply<<<1024, 256, 0, stream>>>(ws+O_SCB, ws+O_HP, 128,  256, ws+O_AGG);
    k_copy_hp<<<1024, 256, 0, stream>>>(ws+O_HP, ws+O_AGG);

    // 7. aggregation bigru
    k_gemm_v2<<<dim3(6,16,2), 256, 0, stream>>>(ws+O_AGG, g_Wih, g_bih, ws+O_PREG,
                                                1024, 384, 1536, 589824LL, 393216LL, 384LL);
    k_gru_scan<<<16, 256, 0, stream>>>(ws+O_PREG, g_Whh, g_bhh, ws+O_AGGREP, 128, 0, 0);

    // 8. pooling + prediction
    k_q_att<<<8, 256, 0, stream>>>(ws+O_CQ, vq, ws+O_HQ, ws+O_RQ);
    k_gemm_v2<<<dim3(2,16,1), 256, 0, stream>>>(ws+O_AGGREP, Wp1, nullptr, ws+O_GP, 1024,128,256, 0,0,0);
    k_gemm_v2<<<dim3(2,1,1),  256, 0, stream>>>(ws+O_RQ, Wp2, nullptr, ws+O_RQW, 8,128,256, 0,0,0);
    k_p_att<<<8, 256, 0, stream>>>(ws+O_GP, vp, ws+O_RQW, ws+O_AGGREP, ws+O_RP);
    k_final<<<8, 256, 0, stream>>>(ws+O_RP, Wpred, ws+O_AEMB, (float*)d_out);
}

// Round 7
// 1272.307 us; speedup vs baseline: 3.2687x; 1.0928x over previous
//
#include <hip/hip_runtime.h>
#include <hip/hip_bf16.h>

// ---------------------------------------------------------------------------
// MwAN forward, MI355X. B=8, QL=128, PL=256, AL=10, E=128, EMB=256.
// Inputs fp32; internal compute fp32 in d_ws; output fp32.
// R7: GRU scan thread=(j,quarter): 96-float weight cache (was 192 -> AGPR
// spill, VGPR_Count=124 vs needed 192). 512 threads, no spill. Fused gathers.
// ---------------------------------------------------------------------------

#define BB 8
#define QL 128
#define PL 256
#define AL 10
#define EE 128
#define EMB 256
#define G3 384   // 3*H gates
#define HH 128   // hidden

// ---- ws layout (in floats) ----
#define O_XPASS   ((size_t)0)        // (8,256,256)  -- dead after pre-GEMMs; reused
#define O_XQUERY  ((size_t)524288)   // (8,128,256)  -- dead after pre-GEMMs; reused for Mp
#define O_XCAND   ((size_t)786432)   // 3 x (8,10,256), chunk 20480
#define O_PREQ    ((size_t)847872)   // (2,8,256,384)
#define O_PREP    ((size_t)2420736)  // (2,8,128,384)
#define O_PREA    ((size_t)3207168)  // 3 x (2,8,10,384), chunk 61440
#define O_PREG    ((size_t)3391488)  // (2,8,128,384)
#define O_HQ      ((size_t)4177920)  // (8,256,256)
#define O_HP      ((size_t)4702208)  // (8,128,256)
#define O_HCAND   ((size_t)4964352)  // 3 x (8,10,256), chunk 20480
#define O_AEMB    ((size_t)5025792)  // (8,3,256)
#define O_AQ      ((size_t)5031936)  // (8,256,128)
#define O_AP      ((size_t)5294080)  // (8,128,128)
#define O_BQ      ((size_t)5425152)  // (8,256,256)
#define O_AGG     ((size_t)5949440)  // (8,128,1536)
#define O_AGGREP  ((size_t)7522304)  // (8,128,256)
#define O_CQ      ((size_t)7784448)  // (8,256,128)
#define O_GP      ((size_t)8046592)  // (8,128,128)
#define O_RQ      ((size_t)8177664)  // (8,256)
#define O_RQW     ((size_t)8179712)  // (8,128)
#define O_RP      ((size_t)8180736)  // (8,256)
#define O_SCORE   O_XPASS                    // (8,128,256) dot scores / then Mq
#define O_SCB     (O_XPASS + (size_t)262144) // (8,128,128) self scores
#define O_MP      O_XQUERY                   // (8,128,128) Mp = hp@Wm^T

typedef __attribute__((ext_vector_type(8))) short bf16x8;
typedef __attribute__((ext_vector_type(4))) float f32x4;
union U4 { uint4 u; bf16x8 v; };

__device__ __forceinline__ float tanh_fast(float x){
    x = fminf(fmaxf(x, -20.f), 20.f);
    float e = __expf(2.f * x);
    return (e - 1.f) / (e + 1.f);
}
__device__ __forceinline__ float sig_fast(float x){
    return 1.f / (1.f + __expf(-x));
}
// pack two fp32 -> bf16 pair (round-half-up)
__device__ __forceinline__ unsigned pk2(float a, float b){
    unsigned ua = __float_as_uint(a), ub = __float_as_uint(b);
    return ((ua + 0x8000u) >> 16) | ((ub + 0x8000u) & 0xffff0000u);
}

// softmax over sc[0..255], 256 lanes
__device__ __forceinline__ void softmax256(float* sc, float* red, int tid){
    float v = sc[tid];
    red[tid] = v;
    __syncthreads();
    for (int s = 128; s > 0; s >>= 1){
        if (tid < s) red[tid] = fmaxf(red[tid], red[tid + s]);
        __syncthreads();
    }
    float m = red[0];
    __syncthreads();
    float e = __expf(v - m);
    red[tid] = e;
    __syncthreads();
    for (int s = 128; s > 0; s >>= 1){
        if (tid < s) red[tid] += red[tid + s];
        __syncthreads();
    }
    float inv = 1.f / red[0];
    __syncthreads();
    sc[tid] = e * inv;
    __syncthreads();
}

// ---------------------------------------------------------------------------
// fused embedding gathers: passage | query | cneg | cpos | cna
__global__ __launch_bounds__(256) void k_gather_all(const int* __restrict__ passage,
                                                    const int* __restrict__ query,
                                                    const int* __restrict__ cneg,
                                                    const int* __restrict__ cpos,
                                                    const int* __restrict__ cna,
                                                    const float* __restrict__ emb,
                                                    float* __restrict__ ws){
    int blk = blockIdx.x, e = threadIdx.x;
    const int* ids; size_t dst; int i;
    if (blk < 2048){            ids = passage; dst = O_XPASS;            i = blk; }
    else if (blk < 3072){       ids = query;   dst = O_XQUERY;           i = blk - 2048; }
    else if (blk < 3152){       ids = cneg;    dst = O_XCAND + 0*20480;  i = blk - 3072; }
    else if (blk < 3232){       ids = cpos;    dst = O_XCAND + 1*20480;  i = blk - 3152; }
    else {                      ids = cna;     dst = O_XCAND + 2*20480;  i = blk - 3232; }
    int id = ids[i];
    ws[dst + (size_t)i * EMB + e] = emb[(size_t)id * EMB + e];
}

// ---------------------------------------------------------------------------
// Register-tiled GEMM-NT: C[m,n] = sum_k A[m,k]*B[n,k] + bias[n].
// 64x64 tile, 256 threads, 4x4 fragment, K-chunk 32. K%32==0, N%64==0.
__global__ __launch_bounds__(256) void k_gemm_v2(const float* __restrict__ A,
                                                 const float* __restrict__ Bm,
                                                 const float* __restrict__ bias,
                                                 float* __restrict__ C,
                                                 int M, int N, int K,
                                                 long long strideB, long long strideC,
                                                 long long strideBias){
    int z = blockIdx.z;
    Bm += (size_t)z * strideB;
    C  += (size_t)z * strideC;
    if (bias) bias += (size_t)z * strideBias;

    __shared__ float As[32][68];
    __shared__ float Bs[32][68];

    int tid = threadIdx.x;
    int i = tid & 15;
    int j = tid >> 4;
    int m0 = blockIdx.y * 64;
    int n0 = blockIdx.x * 64;

    int sm = tid & 63;
    int sk = (tid >> 6) * 8;

    float acc[4][4];
    #pragma unroll
    for (int r = 0; r < 4; ++r)
        #pragma unroll
        for (int c = 0; c < 4; ++c) acc[r][c] = 0.f;

    for (int k0 = 0; k0 < K; k0 += 32){
        float4 a0 = make_float4(0,0,0,0), a1 = make_float4(0,0,0,0);
        if (m0 + sm < M){
            const float* ap = A + (size_t)(m0 + sm) * K + k0 + sk;
            a0 = *(const float4*)ap;
            a1 = *(const float4*)(ap + 4);
        }
        As[sk+0][sm] = a0.x; As[sk+1][sm] = a0.y; As[sk+2][sm] = a0.z; As[sk+3][sm] = a0.w;
        As[sk+4][sm] = a1.x; As[sk+5][sm] = a1.y; As[sk+6][sm] = a1.z; As[sk+7][sm] = a1.w;
        {
            const float* bp = Bm + (size_t)(n0 + sm) * K + k0 + sk;
            float4 b0 = *(const float4*)bp;
            float4 b1 = *(const float4*)(bp + 4);
            Bs[sk+0][sm] = b0.x; Bs[sk+1][sm] = b0.y; Bs[sk+2][sm] = b0.z; Bs[sk+3][sm] = b0.w;
            Bs[sk+4][sm] = b1.x; Bs[sk+5][sm] = b1.y; Bs[sk+6][sm] = b1.z; Bs[sk+7][sm] = b1.w;
        }
        __syncthreads();
        #pragma unroll
        for (int f = 0; f < 32; ++f){
            float4 av = *(const float4*)&As[f][i*4];
            float4 bv = *(const float4*)&Bs[f][j*4];
            float ar[4] = {av.x, av.y, av.z, av.w};
            float bc[4] = {bv.x, bv.y, bv.z, bv.w};
            #pragma unroll
            for (int r = 0; r < 4; ++r)
                #pragma unroll
                for (int c = 0; c < 4; ++c)
                    acc[r][c] += ar[r] * bc[c];
        }
        __syncthreads();
    }

    float4 bv = make_float4(0,0,0,0);
    if (bias) bv = *(const float4*)&bias[n0 + j*4];
    #pragma unroll
    for (int r = 0; r < 4; ++r){
        int row = m0 + i*4 + r;
        if (row < M){
            float4 o;
            o.x = acc[r][0] + bv.x;
            o.y = acc[r][1] + bv.y;
            o.z = acc[r][2] + bv.z;
            o.w = acc[r][3] + bv.w;
            *(float4*)&C[(size_t)row * N + n0 + j*4] = o;
        }
    }
}

// ---------------------------------------------------------------------------
// GRU scan, R7: 512 threads, thread = (j, quarter). Each thread owns gates
// r/z/n for ONE hidden unit j over h-chunk [q*32, q*32+32): 96 weight floats
// (fits VGPRs, no spill). Butterfly xor(1,2) completes dots; all quarters
// update h redundantly; 1 barrier/step via ping-pong h; pre prefetched.
__global__ __launch_bounds__(512, 1) void k_gru_scan(const float* __restrict__ pre,
                                                     const float* __restrict__ Whh,
                                                     const float* __restrict__ bhh,
                                                     float* __restrict__ out,
                                                     int T, int preChunk, int outChunk){
    int idx = blockIdx.x;
    int c = idx >> 4, bd = idx & 15, b = bd >> 1, d = bd & 1;
    pre += (size_t)c * preChunk;
    out += (size_t)c * outChunk;

    int tid = threadIdx.x;
    int j = tid >> 2, q = tid & 3;
    int cb = q * 32;

    float wr_[32], wz_[32], wn_[32];
    const float* wb = Whh + (size_t)d * G3 * HH;
    {
        const float4* pr4 = (const float4*)(wb + (size_t)j * HH + cb);
        const float4* pz4 = (const float4*)(wb + (size_t)(HH + j) * HH + cb);
        const float4* pn4 = (const float4*)(wb + (size_t)(2*HH + j) * HH + cb);
        #pragma unroll
        for (int kk = 0; kk < 8; ++kk){
            float4 ur = pr4[kk], uz = pz4[kk], un = pn4[kk];
            wr_[kk*4+0]=ur.x; wr_[kk*4+1]=ur.y; wr_[kk*4+2]=ur.z; wr_[kk*4+3]=ur.w;
            wz_[kk*4+0]=uz.x; wz_[kk*4+1]=uz.y; wz_[kk*4+2]=uz.z; wz_[kk*4+3]=uz.w;
            wn_[kk*4+0]=un.x; wn_[kk*4+1]=un.y; wn_[kk*4+2]=un.z; wn_[kk*4+3]=un.w;
        }
    }
    const float* bb = bhh + d * G3;
    float br = bb[j], bz = bb[HH + j], bn = bb[2*HH + j];

    __shared__ __align__(16) float h_s[2][HH];
    if (tid < HH) h_s[0][tid] = 0.f;
    float hprev = 0.f;

    const float* ptB = pre + ((size_t)d * BB + b) * (size_t)T * G3;
    float* ob = out + (size_t)b * T * 256 + d * HH;

    const float* pt0 = ptB + (size_t)(d ? (T-1) : 0) * G3;
    float pr = pt0[j], pz = pt0[HH + j], pn = pt0[2*HH + j];
    __syncthreads();

    for (int step = 0; step < T; ++step){
        int t = d ? (T-1-step) : step;
        float nr = 0.f, nz = 0.f, nn = 0.f;
        if (step + 1 < T){
            const float* ptn = ptB + (size_t)(d ? (T-2-step) : (step+1)) * G3;
            nr = ptn[j]; nz = ptn[HH + j]; nn = ptn[2*HH + j];
        }
        int rb = step & 1;
        const float4* h4 = (const float4*)&h_s[rb][cb];
        float ar = 0.f, az = 0.f, an = 0.f;
        #pragma unroll
        for (int kk = 0; kk < 8; ++kk){
            float4 hv = h4[kk];
            ar = fmaf(wr_[kk*4+0], hv.x, ar); ar = fmaf(wr_[kk*4+1], hv.y, ar);
            ar = fmaf(wr_[kk*4+2], hv.z, ar); ar = fmaf(wr_[kk*4+3], hv.w, ar);
            az = fmaf(wz_[kk*4+0], hv.x, az); az = fmaf(wz_[kk*4+1], hv.y, az);
            az = fmaf(wz_[kk*4+2], hv.z, az); az = fmaf(wz_[kk*4+3], hv.w, az);
            an = fmaf(wn_[kk*4+0], hv.x, an); an = fmaf(wn_[kk*4+1], hv.y, an);
            an = fmaf(wn_[kk*4+2], hv.z, an); an = fmaf(wn_[kk*4+3], hv.w, an);
        }
        ar += __shfl_xor(ar, 1); ar += __shfl_xor(ar, 2);
        az += __shfl_xor(az, 1); az += __shfl_xor(az, 2);
        an += __shfl_xor(an, 1); an += __shfl_xor(an, 2);

        float r = sig_fast(pr + ar + br);
        float z = sig_fast(pz + az + bz);
        float n = tanh_fast(pn + r * (an + bn));
        float h = n + z * (hprev - n);
        hprev = h;

        if (q == 0) h_s[1-rb][j] = h;
        if (q == 1) ob[(size_t)t * 256 + j] = h;
        pr = nr; pz = nz; pn = nn;
        __syncthreads();
    }
}

// ---------------------------------------------------------------------------
__global__ __launch_bounds__(256) void k_cand_att(const float* __restrict__ h,
                                                  const float* __restrict__ a_att,
                                                  float* __restrict__ a_emb){
    int c = blockIdx.x / BB, b = blockIdx.x % BB, tid = threadIdx.x;
    __shared__ float att[256], sc[AL], sw[AL];
    att[tid] = a_att[tid];
    __syncthreads();
    const float* hb = h + (size_t)c * (BB*AL*256) + (size_t)b * (AL*256);
    if (tid < AL){
        float s = 0.f;
        for (int e = 0; e < 256; ++e) s += hb[tid*256 + e] * att[e];
        sc[tid] = s;
    }
    __syncthreads();
    if (tid == 0){
        float m = -1e30f;
        for (int t = 0; t < AL; ++t) m = fmaxf(m, sc[t]);
        float s = 0.f;
        for (int t = 0; t < AL; ++t){ sw[t] = __expf(sc[t] - m); s += sw[t]; }
        float inv = 1.f / s;
        for (int t = 0; t < AL; ++t) sw[t] *= inv;
    }
    __syncthreads();
    float o = 0.f;
    for (int t = 0; t < AL; ++t) o += sw[t] * hb[t*256 + tid];
    a_emb[((size_t)b*3 + c) * 256 + tid] = o;
}

// ---------------------------------------------------------------------------
// additive attention: score[p] = sum_e v[e]*tanh(Aq[b,p,e] + sign*Ap[b,q,e]);
__global__ __launch_bounds__(256) void k_att_cm(const float* __restrict__ Aq,
                                                const float* __restrict__ Ap,
                                                const float* __restrict__ v,
                                                const float* __restrict__ vals,
                                                float sign, int outOff,
                                                float* __restrict__ agg){
    int b = blockIdx.x >> 7, q = blockIdx.x & 127, tid = threadIdx.x;
    __shared__ float apv[EE], vcv[EE], sc[256], red[256];
    if (tid < EE){
        apv[tid] = sign * Ap[((size_t)b*QL + q)*EE + tid];
        vcv[tid] = v[tid];
    }
    __syncthreads();
    const float* aqp = Aq + ((size_t)b*PL + tid)*EE;
    float s = 0.f;
    #pragma unroll 4
    for (int e = 0; e < EE; ++e) s += vcv[e] * tanh_fast(aqp[e] + apv[e]);
    sc[tid] = s;
    __syncthreads();
    softmax256(sc, red, tid);
    float o = 0.f;
    const float* vb = vals + (size_t)b*PL*256;
    for (int p = 0; p < PL; ++p) o += sc[p] * vb[(size_t)p*256 + tid];
    agg[((size_t)b*QL + q)*1536 + outOff + tid] = o;
}

// bilinear attention
__global__ __launch_bounds__(256) void k_att_b(const float* __restrict__ Bq,
                                               const float* __restrict__ hp,
                                               const float* __restrict__ hq,
                                               float* __restrict__ agg){
    int b = blockIdx.x >> 7, q = blockIdx.x & 127, tid = threadIdx.x;
    __shared__ float xq[256], sc[256], red[256];
    xq[tid] = hp[((size_t)b*QL + q)*256 + tid];
    __syncthreads();
    const float* bq = Bq + ((size_t)b*PL + tid)*256;
    float s = 0.f;
    #pragma unroll 4
    for (int e = 0; e < 256; ++e) s += xq[e] * bq[e];
    sc[tid] = s;
    __syncthreads();
    softmax256(sc, red, tid);
    float o = 0.f;
    const float* hqb = hq + (size_t)b*PL*256;
    for (int p = 0; p < PL; ++p) o += sc[p] * hqb[(size_t)p*256 + tid];
    agg[((size_t)b*QL + q)*1536 + 1024 + tid] = o;
}

// ---------------------------------------------------------------------------
// MFMA dms scores: sc[b,q,p] = sum_e v[e]*tanh( sum_f W[e,f]*kv[b,p,f]*xq[b,q,f] )
__global__ __launch_bounds__(256, 1) void k_dms_mfma(const float* __restrict__ kv, int P,
                                                     const float* __restrict__ Wmat,
                                                     const float* __restrict__ v,
                                                     const float* __restrict__ xsrc,
                                                     int qPerBlock,
                                                     float* __restrict__ sc){
    int pt = blockIdx.x, qc = blockIdx.y, b = blockIdx.z;
    int tid = threadIdx.x;
    int w = tid >> 6, lane = tid & 63, m = lane & 15, quad = lane >> 4;

    __shared__ unsigned Hlds[64 * 132];
    __shared__ float hpq[256];

    {
        const float* hr = kv + ((size_t)b * P + pt * 64 + w * 16 + m) * 256;
        unsigned* dst = &Hlds[(w * 16 + m) * 132];
        #pragma unroll
        for (int k0 = 0; k0 < 8; ++k0){
            const float* p0 = hr + k0 * 32 + quad * 8;
            float4 x0 = *(const float4*)p0;
            float4 x1 = *(const float4*)(p0 + 4);
            uint4 u;
            u.x = pk2(x0.x, x0.y); u.y = pk2(x0.z, x0.w);
            u.z = pk2(x1.x, x1.y); u.w = pk2(x1.z, x1.w);
            *(uint4*)&dst[k0 * 16 + quad * 4] = u;
        }
    }

    bf16x8 bfr[8][8];
    #pragma unroll
    for (int et = 0; et < 8; ++et){
        const float* wr = Wmat + (size_t)(et * 16 + m) * 256;
        #pragma unroll
        for (int k0 = 0; k0 < 8; ++k0){
            const float* p0 = wr + k0 * 32 + quad * 8;
            float4 x0 = *(const float4*)p0;
            float4 x1 = *(const float4*)(p0 + 4);
            U4 uu;
            uu.u.x = pk2(x0.x, x0.y); uu.u.y = pk2(x0.z, x0.w);
            uu.u.z = pk2(x1.x, x1.y); uu.u.w = pk2(x1.z, x1.w);
            bfr[et][k0] = uu.v;
        }
    }
    float vreg[8];
    #pragma unroll
    for (int et = 0; et < 8; ++et) vreg[et] = v[et * 16 + m];

    __syncthreads();

    const unsigned* hrow = &Hlds[(w * 16 + m) * 132];

    for (int qi = 0; qi < qPerBlock; ++qi){
        int q = qc * qPerBlock + qi;
        __syncthreads();
        hpq[tid] = xsrc[((size_t)b * QL + q) * 256 + tid];
        __syncthreads();

        bf16x8 afr[8];
        #pragma unroll
        for (int k0 = 0; k0 < 8; ++k0){
            uint4 hv = *(const uint4*)&hrow[k0 * 16 + quad * 4];
            const float* hf = &hpq[k0 * 32 + quad * 8];
            float f0 = __uint_as_float(hv.x << 16)         * hf[0];
            float f1 = __uint_as_float(hv.x & 0xffff0000u) * hf[1];
            float f2 = __uint_as_float(hv.y << 16)         * hf[2];
            float f3 = __uint_as_float(hv.y & 0xffff0000u) * hf[3];
            float f4 = __uint_as_float(hv.z << 16)         * hf[4];
            float f5 = __uint_as_float(hv.z & 0xffff0000u) * hf[5];
            float f6 = __uint_as_float(hv.w << 16)         * hf[6];
            float f7 = __uint_as_float(hv.w & 0xffff0000u) * hf[7];
            U4 uu;
            uu.u.x = pk2(f0, f1); uu.u.y = pk2(f2, f3);
            uu.u.z = pk2(f4, f5); uu.u.w = pk2(f6, f7);
            afr[k0] = uu.v;
        }

        f32x4 acc[8];
        #pragma unroll
        for (int et = 0; et < 8; ++et){
            acc[et][0] = 0.f; acc[et][1] = 0.f; acc[et][2] = 0.f; acc[et][3] = 0.f;
        }
        #pragma unroll
        for (int k0 = 0; k0 < 8; ++k0)
            #pragma unroll
            for (int et = 0; et < 8; ++et)
                acc[et] = __builtin_amdgcn_mfma_f32_16x16x32_bf16(afr[k0], bfr[et][k0], acc[et], 0, 0, 0);

        float p0 = 0.f, p1 = 0.f, p2 = 0.f, p3 = 0.f;
        #pragma unroll
        for (int et = 0; et < 8; ++et){
            p0 += vreg[et] * tanh_fast(acc[et][0]);
            p1 += vreg[et] * tanh_fast(acc[et][1]);
            p2 += vreg[et] * tanh_fast(acc[et][2]);
            p3 += vreg[et] * tanh_fast(acc[et][3]);
        }
        p0 += __shfl_xor(p0, 1); p0 += __shfl_xor(p0, 2); p0 += __shfl_xor(p0, 4); p0 += __shfl_xor(p0, 8);
        p1 += __shfl_xor(p1, 1); p1 += __shfl_xor(p1, 2); p1 += __shfl_xor(p1, 4); p1 += __shfl_xor(p1, 8);
        p2 += __shfl_xor(p2, 1); p2 += __shfl_xor(p2, 2); p2 += __shfl_xor(p2, 4); p2 += __shfl_xor(p2, 8);
        p3 += __shfl_xor(p3, 1); p3 += __shfl_xor(p3, 2); p3 += __shfl_xor(p3, 4); p3 += __shfl_xor(p3, 8);
        if (m == 0){
            float4 o = make_float4(p0, p1, p2, p3);
            *(float4*)&sc[((size_t)b * QL + q) * P + pt * 64 + w * 16 + quad * 4] = o;
        }
    }
}

// softmax over scores + weighted sum
__global__ __launch_bounds__(256) void k_att_apply(const float* __restrict__ sc,
                                                   const float* __restrict__ kv, int P,
                                                   int outOff, float* __restrict__ agg){
    int b = blockIdx.x >> 7, q = blockIdx.x & 127, tid = threadIdx.x;
    __shared__ float w[256], red[256];
    w[tid] = (tid < P) ? sc[((size_t)b*QL + q)*P + tid] : -1e30f;
    __syncthreads();
    softmax256(w, red, tid);
    const float* kvb = kv + (size_t)b*P*256;
    float o = 0.f;
    #pragma unroll 4
    for (int p = 0; p < P; ++p) o += w[p] * kvb[(size_t)p*256 + tid];
    agg[((size_t)b*QL + q)*1536 + outOff + tid] = o;
}

__global__ __launch_bounds__(256) void k_copy_hp(const float* __restrict__ hp,
                                                 float* __restrict__ agg){
    int i = blockIdx.x, tid = threadIdx.x;
    agg[(size_t)i*1536 + tid] = hp[(size_t)i*256 + tid];
}

// ---------------------------------------------------------------------------
__global__ __launch_bounds__(256) void k_q_att(const float* __restrict__ Cq,
                                               const float* __restrict__ vq,
                                               const float* __restrict__ hq,
                                               float* __restrict__ rq){
    int b = blockIdx.x, tid = threadIdx.x;
    __shared__ float vv[EE], sc[256], red[256];
    if (tid < EE) vv[tid] = vq[tid];
    __syncthreads();
    const float* cb = Cq + ((size_t)b*PL + tid)*EE;
    float s = 0.f;
    #pragma unroll 4
    for (int e = 0; e < EE; ++e) s += vv[e] * tanh_fast(cb[e]);
    sc[tid] = s;
    __syncthreads();
    softmax256(sc, red, tid);
    float o = 0.f;
    const float* hqb = hq + (size_t)b*PL*256;
    for (int p = 0; p < PL; ++p) o += sc[p] * hqb[(size_t)p*256 + tid];
    rq[(size_t)b*256 + tid] = o;
}

__global__ __launch_bounds__(256) void k_p_att(const float* __restrict__ Gp,
                                               const float* __restrict__ vp,
                                               const float* __restrict__ rqW,
                                               const float* __restrict__ agg_rep,
                                               float* __restrict__ rp){
    int b = blockIdx.x, tid = threadIdx.x;
    __shared__ float vv[EE], rw[EE], sc[256], red[256];
    if (tid < EE){
        vv[tid] = vp[tid];
        rw[tid] = rqW[(size_t)b*EE + tid];
    }
    if (tid >= 128) sc[tid] = -1e30f;
    __syncthreads();
    if (tid < QL){
        const float* gp = Gp + ((size_t)b*QL + tid)*EE;
        float s = 0.f;
        for (int e = 0; e < EE; ++e) s += vv[e] * (gp[e] + rw[e]);
        sc[tid] = s;
    }
    __syncthreads();
    softmax256(sc, red, tid);
    float o = 0.f;
    const float* ab = agg_rep + (size_t)b*QL*256;
    for (int q = 0; q < QL; ++q) o += sc[q] * ab[(size_t)q*256 + tid];
    rp[(size_t)b*256 + tid] = o;
}

__global__ __launch_bounds__(256) void k_final(const float* __restrict__ rp,
                                               const float* __restrict__ Wpred,
                                               const float* __restrict__ a_emb,
                                               float* __restrict__ out){
    int b = blockIdx.x, tid = threadIdx.x;
    __shared__ float rpv[256], enc[256];
    rpv[tid] = rp[(size_t)b*256 + tid];
    __syncthreads();
    const float* wr = Wpred + (size_t)tid*256;
    float s = 0.f;
    #pragma unroll 4
    for (int e = 0; e < 256; ++e) s += wr[e] * rpv[e];
    enc[tid] = (s > 0.f) ? s : 0.01f * s;
    __syncthreads();
    if (tid < 3){
        const float* ae = a_emb + ((size_t)b*3 + tid)*256;
        float o = 0.f;
        for (int e = 0; e < 256; ++e) o += ae[e] * enc[e];
        out[b*3 + tid] = o;
    }
}

// ---------------------------------------------------------------------------
extern "C" void kernel_launch(void* const* d_in, const int* in_sizes, int n_in,
                              void* d_out, int out_size, void* d_ws, size_t ws_size,
                              hipStream_t stream){
    const float* emb   = (const float*)d_in[0];
    const float* a_att = (const float*)d_in[1];
    const float* Wc1   = (const float*)d_in[2];
    const float* Wc2   = (const float*)d_in[3];
    const float* vc    = (const float*)d_in[4];
    const float* Wb    = (const float*)d_in[5];
    const float* Wd    = (const float*)d_in[6];
    const float* vd    = (const float*)d_in[7];
    const float* Wm    = (const float*)d_in[8];
    const float* vm    = (const float*)d_in[9];
    const float* Ws    = (const float*)d_in[10];
    const float* vs    = (const float*)d_in[11];
    const float* Wq    = (const float*)d_in[12];
    const float* vq    = (const float*)d_in[13];
    const float* Wp1   = (const float*)d_in[14];
    const float* Wp2   = (const float*)d_in[15];
    const float* vp    = (const float*)d_in[16];
    const float* Wpred = (const float*)d_in[17];
    const float* q_Wih = (const float*)d_in[18];
    const float* q_Whh = (const float*)d_in[19];
    const float* q_bih = (const float*)d_in[20];
    const float* q_bhh = (const float*)d_in[21];
    const float* p_Wih = (const float*)d_in[22];
    const float* p_Whh = (const float*)d_in[23];
    const float* p_bih = (const float*)d_in[24];
    const float* p_bhh = (const float*)d_in[25];
    const float* a_Wih = (const float*)d_in[26];
    const float* a_Whh = (const float*)d_in[27];
    const float* a_bih = (const float*)d_in[28];
    const float* a_bhh = (const float*)d_in[29];
    const float* g_Wih = (const float*)d_in[30];
    const float* g_Whh = (const float*)d_in[31];
    const float* g_bih = (const float*)d_in[32];
    const float* g_bhh = (const float*)d_in[33];
    const int* query   = (const int*)d_in[34];
    const int* passage = (const int*)d_in[35];
    const int* cneg    = (const int*)d_in[36];
    const int* cpos    = (const int*)d_in[37];
    const int* cna     = (const int*)d_in[38];

    float* ws = (float*)d_ws;

    // 1. embedding gathers (fused)
    k_gather_all<<<3312, 256, 0, stream>>>(passage, query, cneg, cpos, cna, emb, ws);

    // 2. input preactivations (x @ Wih^T + bih), z = direction
    k_gemm_v2<<<dim3(6,32,2), 256, 0, stream>>>(ws+O_XPASS, q_Wih, q_bih, ws+O_PREQ,
                                                2048, 384, 256, 98304LL, 786432LL, 384LL);
    k_gemm_v2<<<dim3(6,16,2), 256, 0, stream>>>(ws+O_XQUERY, p_Wih, p_bih, ws+O_PREP,
                                                1024, 384, 256, 98304LL, 393216LL, 384LL);
    for (int c = 0; c < 3; ++c)
        k_gemm_v2<<<dim3(6,2,2), 256, 0, stream>>>(ws+O_XCAND + c*20480, a_Wih, a_bih,
                                                   ws+O_PREA + c*61440,
                                                   80, 384, 256, 98304LL, 30720LL, 384LL);

    // 3. GRU scans (512 threads)
    k_gru_scan<<<16, 512, 0, stream>>>(ws+O_PREQ, q_Whh, q_bhh, ws+O_HQ, 256, 0, 0);
    k_gru_scan<<<16, 512, 0, stream>>>(ws+O_PREP, p_Whh, p_bhh, ws+O_HP, 128, 0, 0);
    k_gru_scan<<<48, 512, 0, stream>>>(ws+O_PREA, a_Whh, a_bhh, ws+O_HCAND, 10, 61440, 20480);

    // 4. candidate pooling
    k_cand_att<<<24, 256, 0, stream>>>(ws+O_HCAND, a_att, ws+O_AEMB);

    // 5. projection GEMMs
    k_gemm_v2<<<dim3(2,32,1), 256, 0, stream>>>(ws+O_HQ, Wc1, nullptr, ws+O_AQ, 2048,128,256, 0,0,0);
    k_gemm_v2<<<dim3(2,16,1), 256, 0, stream>>>(ws+O_HP, Wc2, nullptr, ws+O_AP, 1024,128,256, 0,0,0);
    k_gemm_v2<<<dim3(4,32,1), 256, 0, stream>>>(ws+O_HQ, Wb,  nullptr, ws+O_BQ, 2048,256,256, 0,0,0);
    k_gemm_v2<<<dim3(2,32,1), 256, 0, stream>>>(ws+O_HQ, Wq,  nullptr, ws+O_CQ, 2048,128,256, 0,0,0);

    // 6. attention blocks -> agg slices
    k_att_cm<<<1024, 256, 0, stream>>>(ws+O_AQ, ws+O_AP, vc, ws+O_HQ, 1.f, 512, ws+O_AGG);
    k_att_b<<<1024, 256, 0, stream>>>(ws+O_BQ, ws+O_HP, ws+O_HQ, ws+O_AGG);
    k_dms_mfma<<<dim3(4,8,8), 256, 0, stream>>>(ws+O_HQ, 256, Wd, vd, ws+O_HP, 16, ws+O_SCORE);
    k_att_apply<<<1024, 256, 0, stream>>>(ws+O_SCORE, ws+O_HQ, 256,  768, ws+O_AGG);
    k_gemm_v2<<<dim3(2,32,1), 256, 0, stream>>>(ws+O_HQ, Wm, nullptr, ws+O_SCORE, 2048,128,256, 0,0,0);
    k_gemm_v2<<<dim3(2,16,1), 256, 0, stream>>>(ws+O_HP, Wm, nullptr, ws+O_MP,    1024,128,256, 0,0,0);
    k_att_cm<<<1024, 256, 0, stream>>>(ws+O_SCORE, ws+O_MP, vm, ws+O_HQ, -1.f, 1280, ws+O_AGG);
    k_dms_mfma<<<dim3(2,16,8), 256, 0, stream>>>(ws+O_HP, 128, Ws, vs, ws+O_HP, 8, ws+O_SCB);
    k_att_apply<<<1024, 256, 0, stream>>>(ws+O_SCB, ws+O_HP, 128,  256, ws+O_AGG);
    k_copy_hp<<<1024, 256, 0, stream>>>(ws+O_HP, ws+O_AGG);

    // 7. aggregation bigru
    k_gemm_v2<<<dim3(6,16,2), 256, 0, stream>>>(ws+O_AGG, g_Wih, g_bih, ws+O_PREG,
                                                1024, 384, 1536, 589824LL, 393216LL, 384LL);
    k_gru_scan<<<16, 512, 0, stream>>>(ws+O_PREG, g_Whh, g_bhh, ws+O_AGGREP, 128, 0, 0);

    // 8. pooling + prediction
    k_q_att<<<8, 256, 0, stream>>>(ws+O_CQ, vq, ws+O_HQ, ws+O_RQ);
    k_gemm_v2<<<dim3(2,16,1), 256, 0, stream>>>(ws+O_AGGREP, Wp1, nullptr, ws+O_GP, 1024,128,256, 0,0,0);
    k_gemm_v2<<<dim3(2,1,1),  256, 0, stream>>>(ws+O_RQ, Wp2, nullptr, ws+O_RQW, 8,128,256, 0,0,0);
    k_p_att<<<8, 256, 0, stream>>>(ws+O_GP, vp, ws+O_RQW, ws+O_AGGREP, ws+O_RP);
    k_final<<<8, 256, 0, stream>>>(ws+O_RP, Wpred, ws+O_AEMB, (float*)d_out);
}

// Round 8
// 1266.444 us; speedup vs baseline: 3.2839x; 1.0046x over previous
//
#include <hip/hip_runtime.h>
#include <hip/hip_bf16.h>

// ---------------------------------------------------------------------------
// MwAN forward, MI355X. B=8, QL=128, PL=256, AL=10, E=128, EMB=256.
// Inputs fp32; internal compute fp32 in d_ws; output fp32.
// R8: GRU step barrier = lgkmcnt(0)-only s_barrier (skip the vmcnt(0) drain
// of output stores + prefetch loads that __syncthreads forces each step).
// k_copy_hp fused into k_att_b.
// ---------------------------------------------------------------------------

#define BB 8
#define QL 128
#define PL 256
#define AL 10
#define EE 128
#define EMB 256
#define G3 384   // 3*H gates
#define HH 128   // hidden

// ---- ws layout (in floats) ----
#define O_XPASS   ((size_t)0)        // (8,256,256)  -- dead after pre-GEMMs; reused
#define O_XQUERY  ((size_t)524288)   // (8,128,256)  -- dead after pre-GEMMs; reused for Mp
#define O_XCAND   ((size_t)786432)   // 3 x (8,10,256), chunk 20480
#define O_PREQ    ((size_t)847872)   // (2,8,256,384)
#define O_PREP    ((size_t)2420736)  // (2,8,128,384)
#define O_PREA    ((size_t)3207168)  // 3 x (2,8,10,384), chunk 61440
#define O_PREG    ((size_t)3391488)  // (2,8,128,384)
#define O_HQ      ((size_t)4177920)  // (8,256,256)
#define O_HP      ((size_t)4702208)  // (8,128,256)
#define O_HCAND   ((size_t)4964352)  // 3 x (8,10,256), chunk 20480
#define O_AEMB    ((size_t)5025792)  // (8,3,256)
#define O_AQ      ((size_t)5031936)  // (8,256,128)
#define O_AP      ((size_t)5294080)  // (8,128,128)
#define O_BQ      ((size_t)5425152)  // (8,256,256)
#define O_AGG     ((size_t)5949440)  // (8,128,1536)
#define O_AGGREP  ((size_t)7522304)  // (8,128,256)
#define O_CQ      ((size_t)7784448)  // (8,256,128)
#define O_GP      ((size_t)8046592)  // (8,128,128)
#define O_RQ      ((size_t)8177664)  // (8,256)
#define O_RQW     ((size_t)8179712)  // (8,128)
#define O_RP      ((size_t)8180736)  // (8,256)
#define O_SCORE   O_XPASS                    // (8,128,256) dot scores / then Mq
#define O_SCB     (O_XPASS + (size_t)262144) // (8,128,128) self scores
#define O_MP      O_XQUERY                   // (8,128,128) Mp = hp@Wm^T

typedef __attribute__((ext_vector_type(8))) short bf16x8;
typedef __attribute__((ext_vector_type(4))) float f32x4;
union U4 { uint4 u; bf16x8 v; };

// barrier with LDS-visibility only: do NOT drain vmcnt (global stores /
// prefetch loads); per-thread uses get compiler-inserted vmcnt waits.
#define BAR_LDS() asm volatile("s_waitcnt lgkmcnt(0)\n\ts_barrier" ::: "memory")

__device__ __forceinline__ float tanh_fast(float x){
    x = fminf(fmaxf(x, -20.f), 20.f);
    float e = __expf(2.f * x);
    return (e - 1.f) / (e + 1.f);
}
__device__ __forceinline__ float sig_fast(float x){
    return 1.f / (1.f + __expf(-x));
}
// pack two fp32 -> bf16 pair (round-half-up)
__device__ __forceinline__ unsigned pk2(float a, float b){
    unsigned ua = __float_as_uint(a), ub = __float_as_uint(b);
    return ((ua + 0x8000u) >> 16) | ((ub + 0x8000u) & 0xffff0000u);
}

// softmax over sc[0..255], 256 lanes
__device__ __forceinline__ void softmax256(float* sc, float* red, int tid){
    float v = sc[tid];
    red[tid] = v;
    __syncthreads();
    for (int s = 128; s > 0; s >>= 1){
        if (tid < s) red[tid] = fmaxf(red[tid], red[tid + s]);
        __syncthreads();
    }
    float m = red[0];
    __syncthreads();
    float e = __expf(v - m);
    red[tid] = e;
    __syncthreads();
    for (int s = 128; s > 0; s >>= 1){
        if (tid < s) red[tid] += red[tid + s];
        __syncthreads();
    }
    float inv = 1.f / red[0];
    __syncthreads();
    sc[tid] = e * inv;
    __syncthreads();
}

// ---------------------------------------------------------------------------
// fused embedding gathers: passage | query | cneg | cpos | cna
__global__ __launch_bounds__(256) void k_gather_all(const int* __restrict__ passage,
                                                    const int* __restrict__ query,
                                                    const int* __restrict__ cneg,
                                                    const int* __restrict__ cpos,
                                                    const int* __restrict__ cna,
                                                    const float* __restrict__ emb,
                                                    float* __restrict__ ws){
    int blk = blockIdx.x, e = threadIdx.x;
    const int* ids; size_t dst; int i;
    if (blk < 2048){            ids = passage; dst = O_XPASS;            i = blk; }
    else if (blk < 3072){       ids = query;   dst = O_XQUERY;           i = blk - 2048; }
    else if (blk < 3152){       ids = cneg;    dst = O_XCAND + 0*20480;  i = blk - 3072; }
    else if (blk < 3232){       ids = cpos;    dst = O_XCAND + 1*20480;  i = blk - 3152; }
    else {                      ids = cna;     dst = O_XCAND + 2*20480;  i = blk - 3232; }
    int id = ids[i];
    ws[dst + (size_t)i * EMB + e] = emb[(size_t)id * EMB + e];
}

// ---------------------------------------------------------------------------
// Register-tiled GEMM-NT: C[m,n] = sum_k A[m,k]*B[n,k] + bias[n].
// 64x64 tile, 256 threads, 4x4 fragment, K-chunk 32. K%32==0, N%64==0.
__global__ __launch_bounds__(256) void k_gemm_v2(const float* __restrict__ A,
                                                 const float* __restrict__ Bm,
                                                 const float* __restrict__ bias,
                                                 float* __restrict__ C,
                                                 int M, int N, int K,
                                                 long long strideB, long long strideC,
                                                 long long strideBias){
    int z = blockIdx.z;
    Bm += (size_t)z * strideB;
    C  += (size_t)z * strideC;
    if (bias) bias += (size_t)z * strideBias;

    __shared__ float As[32][68];
    __shared__ float Bs[32][68];

    int tid = threadIdx.x;
    int i = tid & 15;
    int j = tid >> 4;
    int m0 = blockIdx.y * 64;
    int n0 = blockIdx.x * 64;

    int sm = tid & 63;
    int sk = (tid >> 6) * 8;

    float acc[4][4];
    #pragma unroll
    for (int r = 0; r < 4; ++r)
        #pragma unroll
        for (int c = 0; c < 4; ++c) acc[r][c] = 0.f;

    for (int k0 = 0; k0 < K; k0 += 32){
        float4 a0 = make_float4(0,0,0,0), a1 = make_float4(0,0,0,0);
        if (m0 + sm < M){
            const float* ap = A + (size_t)(m0 + sm) * K + k0 + sk;
            a0 = *(const float4*)ap;
            a1 = *(const float4*)(ap + 4);
        }
        As[sk+0][sm] = a0.x; As[sk+1][sm] = a0.y; As[sk+2][sm] = a0.z; As[sk+3][sm] = a0.w;
        As[sk+4][sm] = a1.x; As[sk+5][sm] = a1.y; As[sk+6][sm] = a1.z; As[sk+7][sm] = a1.w;
        {
            const float* bp = Bm + (size_t)(n0 + sm) * K + k0 + sk;
            float4 b0 = *(const float4*)bp;
            float4 b1 = *(const float4*)(bp + 4);
            Bs[sk+0][sm] = b0.x; Bs[sk+1][sm] = b0.y; Bs[sk+2][sm] = b0.z; Bs[sk+3][sm] = b0.w;
            Bs[sk+4][sm] = b1.x; Bs[sk+5][sm] = b1.y; Bs[sk+6][sm] = b1.z; Bs[sk+7][sm] = b1.w;
        }
        __syncthreads();
        #pragma unroll
        for (int f = 0; f < 32; ++f){
            float4 av = *(const float4*)&As[f][i*4];
            float4 bv = *(const float4*)&Bs[f][j*4];
            float ar[4] = {av.x, av.y, av.z, av.w};
            float bc[4] = {bv.x, bv.y, bv.z, bv.w};
            #pragma unroll
            for (int r = 0; r < 4; ++r)
                #pragma unroll
                for (int c = 0; c < 4; ++c)
                    acc[r][c] += ar[r] * bc[c];
        }
        __syncthreads();
    }

    float4 bv = make_float4(0,0,0,0);
    if (bias) bv = *(const float4*)&bias[n0 + j*4];
    #pragma unroll
    for (int r = 0; r < 4; ++r){
        int row = m0 + i*4 + r;
        if (row < M){
            float4 o;
            o.x = acc[r][0] + bv.x;
            o.y = acc[r][1] + bv.y;
            o.z = acc[r][2] + bv.z;
            o.w = acc[r][3] + bv.w;
            *(float4*)&C[(size_t)row * N + n0 + j*4] = o;
        }
    }
}

// ---------------------------------------------------------------------------
// GRU scan, R8: same layout as R7 (512 thr, thread=(j,quarter), 96-float
// weight cache, 1 barrier/step) but the step barrier is lgkmcnt-only:
// global output stores and pre-prefetch loads stay in flight across steps.
__global__ __launch_bounds__(512, 1) void k_gru_scan(const float* __restrict__ pre,
                                                     const float* __restrict__ Whh,
                                                     const float* __restrict__ bhh,
                                                     float* __restrict__ out,
                                                     int T, int preChunk, int outChunk){
    int idx = blockIdx.x;
    int c = idx >> 4, bd = idx & 15, b = bd >> 1, d = bd & 1;
    pre += (size_t)c * preChunk;
    out += (size_t)c * outChunk;

    int tid = threadIdx.x;
    int j = tid >> 2, q = tid & 3;
    int cb = q * 32;

    float wr_[32], wz_[32], wn_[32];
    const float* wb = Whh + (size_t)d * G3 * HH;
    {
        const float4* pr4 = (const float4*)(wb + (size_t)j * HH + cb);
        const float4* pz4 = (const float4*)(wb + (size_t)(HH + j) * HH + cb);
        const float4* pn4 = (const float4*)(wb + (size_t)(2*HH + j) * HH + cb);
        #pragma unroll
        for (int kk = 0; kk < 8; ++kk){
            float4 ur = pr4[kk], uz = pz4[kk], un = pn4[kk];
            wr_[kk*4+0]=ur.x; wr_[kk*4+1]=ur.y; wr_[kk*4+2]=ur.z; wr_[kk*4+3]=ur.w;
            wz_[kk*4+0]=uz.x; wz_[kk*4+1]=uz.y; wz_[kk*4+2]=uz.z; wz_[kk*4+3]=uz.w;
            wn_[kk*4+0]=un.x; wn_[kk*4+1]=un.y; wn_[kk*4+2]=un.z; wn_[kk*4+3]=un.w;
        }
    }
    const float* bb = bhh + d * G3;
    float br = bb[j], bz = bb[HH + j], bn = bb[2*HH + j];

    __shared__ __align__(16) float h_s[2][HH];
    if (tid < HH) h_s[0][tid] = 0.f;
    float hprev = 0.f;

    const float* ptB = pre + ((size_t)d * BB + b) * (size_t)T * G3;
    float* ob = out + (size_t)b * T * 256 + d * HH;

    const float* pt0 = ptB + (size_t)(d ? (T-1) : 0) * G3;
    float pr = pt0[j], pz = pt0[HH + j], pn = pt0[2*HH + j];
    BAR_LDS();

    for (int step = 0; step < T; ++step){
        int t = d ? (T-1-step) : step;
        float nr = 0.f, nz = 0.f, nn = 0.f;
        if (step + 1 < T){
            const float* ptn = ptB + (size_t)(d ? (T-2-step) : (step+1)) * G3;
            nr = ptn[j]; nz = ptn[HH + j]; nn = ptn[2*HH + j];
        }
        int rb = step & 1;
        const float4* h4 = (const float4*)&h_s[rb][cb];
        float ar = 0.f, az = 0.f, an = 0.f;
        #pragma unroll
        for (int kk = 0; kk < 8; ++kk){
            float4 hv = h4[kk];
            ar = fmaf(wr_[kk*4+0], hv.x, ar); ar = fmaf(wr_[kk*4+1], hv.y, ar);
            ar = fmaf(wr_[kk*4+2], hv.z, ar); ar = fmaf(wr_[kk*4+3], hv.w, ar);
            az = fmaf(wz_[kk*4+0], hv.x, az); az = fmaf(wz_[kk*4+1], hv.y, az);
            az = fmaf(wz_[kk*4+2], hv.z, az); az = fmaf(wz_[kk*4+3], hv.w, az);
            an = fmaf(wn_[kk*4+0], hv.x, an); an = fmaf(wn_[kk*4+1], hv.y, an);
            an = fmaf(wn_[kk*4+2], hv.z, an); an = fmaf(wn_[kk*4+3], hv.w, an);
        }
        ar += __shfl_xor(ar, 1); ar += __shfl_xor(ar, 2);
        az += __shfl_xor(az, 1); az += __shfl_xor(az, 2);
        an += __shfl_xor(an, 1); an += __shfl_xor(an, 2);

        float r = sig_fast(pr + ar + br);
        float z = sig_fast(pz + az + bz);
        float n = tanh_fast(pn + r * (an + bn));
        float h = n + z * (hprev - n);
        hprev = h;

        if (q == 0) h_s[1-rb][j] = h;
        if (q == 1) ob[(size_t)t * 256 + j] = h;
        pr = nr; pz = nz; pn = nn;
        BAR_LDS();
    }
}

// ---------------------------------------------------------------------------
__global__ __launch_bounds__(256) void k_cand_att(const float* __restrict__ h,
                                                  const float* __restrict__ a_att,
                                                  float* __restrict__ a_emb){
    int c = blockIdx.x / BB, b = blockIdx.x % BB, tid = threadIdx.x;
    __shared__ float att[256], sc[AL], sw[AL];
    att[tid] = a_att[tid];
    __syncthreads();
    const float* hb = h + (size_t)c * (BB*AL*256) + (size_t)b * (AL*256);
    if (tid < AL){
        float s = 0.f;
        for (int e = 0; e < 256; ++e) s += hb[tid*256 + e] * att[e];
        sc[tid] = s;
    }
    __syncthreads();
    if (tid == 0){
        float m = -1e30f;
        for (int t = 0; t < AL; ++t) m = fmaxf(m, sc[t]);
        float s = 0.f;
        for (int t = 0; t < AL; ++t){ sw[t] = __expf(sc[t] - m); s += sw[t]; }
        float inv = 1.f / s;
        for (int t = 0; t < AL; ++t) sw[t] *= inv;
    }
    __syncthreads();
    float o = 0.f;
    for (int t = 0; t < AL; ++t) o += sw[t] * hb[t*256 + tid];
    a_emb[((size_t)b*3 + c) * 256 + tid] = o;
}

// ---------------------------------------------------------------------------
// additive attention: score[p] = sum_e v[e]*tanh(Aq[b,p,e] + sign*Ap[b,q,e]);
__global__ __launch_bounds__(256) void k_att_cm(const float* __restrict__ Aq,
                                                const float* __restrict__ Ap,
                                                const float* __restrict__ v,
                                                const float* __restrict__ vals,
                                                float sign, int outOff,
                                                float* __restrict__ agg){
    int b = blockIdx.x >> 7, q = blockIdx.x & 127, tid = threadIdx.x;
    __shared__ float apv[EE], vcv[EE], sc[256], red[256];
    if (tid < EE){
        apv[tid] = sign * Ap[((size_t)b*QL + q)*EE + tid];
        vcv[tid] = v[tid];
    }
    __syncthreads();
    const float* aqp = Aq + ((size_t)b*PL + tid)*EE;
    float s = 0.f;
    #pragma unroll 4
    for (int e = 0; e < EE; ++e) s += vcv[e] * tanh_fast(aqp[e] + apv[e]);
    sc[tid] = s;
    __syncthreads();
    softmax256(sc, red, tid);
    float o = 0.f;
    const float* vb = vals + (size_t)b*PL*256;
    for (int p = 0; p < PL; ++p) o += sc[p] * vb[(size_t)p*256 + tid];
    agg[((size_t)b*QL + q)*1536 + outOff + tid] = o;
}

// bilinear attention + fused hp copy into agg[...,0:256]
__global__ __launch_bounds__(256) void k_att_b(const float* __restrict__ Bq,
                                               const float* __restrict__ hp,
                                               const float* __restrict__ hq,
                                               float* __restrict__ agg){
    int b = blockIdx.x >> 7, q = blockIdx.x & 127, tid = threadIdx.x;
    __shared__ float xq[256], sc[256], red[256];
    float xv = hp[((size_t)b*QL + q)*256 + tid];
    xq[tid] = xv;
    agg[((size_t)b*QL + q)*1536 + tid] = xv;   // fused copy_hp
    __syncthreads();
    const float* bq = Bq + ((size_t)b*PL + tid)*256;
    float s = 0.f;
    #pragma unroll 4
    for (int e = 0; e < 256; ++e) s += xq[e] * bq[e];
    sc[tid] = s;
    __syncthreads();
    softmax256(sc, red, tid);
    float o = 0.f;
    const float* hqb = hq + (size_t)b*PL*256;
    for (int p = 0; p < PL; ++p) o += sc[p] * hqb[(size_t)p*256 + tid];
    agg[((size_t)b*QL + q)*1536 + 1024 + tid] = o;
}

// ---------------------------------------------------------------------------
// MFMA dms scores: sc[b,q,p] = sum_e v[e]*tanh( sum_f W[e,f]*kv[b,p,f]*xq[b,q,f] )
__global__ __launch_bounds__(256, 1) void k_dms_mfma(const float* __restrict__ kv, int P,
                                                     const float* __restrict__ Wmat,
                                                     const float* __restrict__ v,
                                                     const float* __restrict__ xsrc,
                                                     int qPerBlock,
                                                     float* __restrict__ sc){
    int pt = blockIdx.x, qc = blockIdx.y, b = blockIdx.z;
    int tid = threadIdx.x;
    int w = tid >> 6, lane = tid & 63, m = lane & 15, quad = lane >> 4;

    __shared__ unsigned Hlds[64 * 132];
    __shared__ float hpq[256];

    {
        const float* hr = kv + ((size_t)b * P + pt * 64 + w * 16 + m) * 256;
        unsigned* dst = &Hlds[(w * 16 + m) * 132];
        #pragma unroll
        for (int k0 = 0; k0 < 8; ++k0){
            const float* p0 = hr + k0 * 32 + quad * 8;
            float4 x0 = *(const float4*)p0;
            float4 x1 = *(const float4*)(p0 + 4);
            uint4 u;
            u.x = pk2(x0.x, x0.y); u.y = pk2(x0.z, x0.w);
            u.z = pk2(x1.x, x1.y); u.w = pk2(x1.z, x1.w);
            *(uint4*)&dst[k0 * 16 + quad * 4] = u;
        }
    }

    bf16x8 bfr[8][8];
    #pragma unroll
    for (int et = 0; et < 8; ++et){
        const float* wr = Wmat + (size_t)(et * 16 + m) * 256;
        #pragma unroll
        for (int k0 = 0; k0 < 8; ++k0){
            const float* p0 = wr + k0 * 32 + quad * 8;
            float4 x0 = *(const float4*)p0;
            float4 x1 = *(const float4*)(p0 + 4);
            U4 uu;
            uu.u.x = pk2(x0.x, x0.y); uu.u.y = pk2(x0.z, x0.w);
            uu.u.z = pk2(x1.x, x1.y); uu.u.w = pk2(x1.z, x1.w);
            bfr[et][k0] = uu.v;
        }
    }
    float vreg[8];
    #pragma unroll
    for (int et = 0; et < 8; ++et) vreg[et] = v[et * 16 + m];

    __syncthreads();

    const unsigned* hrow = &Hlds[(w * 16 + m) * 132];

    for (int qi = 0; qi < qPerBlock; ++qi){
        int q = qc * qPerBlock + qi;
        __syncthreads();
        hpq[tid] = xsrc[((size_t)b * QL + q) * 256 + tid];
        __syncthreads();

        bf16x8 afr[8];
        #pragma unroll
        for (int k0 = 0; k0 < 8; ++k0){
            uint4 hv = *(const uint4*)&hrow[k0 * 16 + quad * 4];
            const float* hf = &hpq[k0 * 32 + quad * 8];
            float f0 = __uint_as_float(hv.x << 16)         * hf[0];
            float f1 = __uint_as_float(hv.x & 0xffff0000u) * hf[1];
            float f2 = __uint_as_float(hv.y << 16)         * hf[2];
            float f3 = __uint_as_float(hv.y & 0xffff0000u) * hf[3];
            float f4 = __uint_as_float(hv.z << 16)         * hf[4];
            float f5 = __uint_as_float(hv.z & 0xffff0000u) * hf[5];
            float f6 = __uint_as_float(hv.w << 16)         * hf[6];
            float f7 = __uint_as_float(hv.w & 0xffff0000u) * hf[7];
            U4 uu;
            uu.u.x = pk2(f0, f1); uu.u.y = pk2(f2, f3);
            uu.u.z = pk2(f4, f5); uu.u.w = pk2(f6, f7);
            afr[k0] = uu.v;
        }

        f32x4 acc[8];
        #pragma unroll
        for (int et = 0; et < 8; ++et){
            acc[et][0] = 0.f; acc[et][1] = 0.f; acc[et][2] = 0.f; acc[et][3] = 0.f;
        }
        #pragma unroll
        for (int k0 = 0; k0 < 8; ++k0)
            #pragma unroll
            for (int et = 0; et < 8; ++et)
                acc[et] = __builtin_amdgcn_mfma_f32_16x16x32_bf16(afr[k0], bfr[et][k0], acc[et], 0, 0, 0);

        float p0 = 0.f, p1 = 0.f, p2 = 0.f, p3 = 0.f;
        #pragma unroll
        for (int et = 0; et < 8; ++et){
            p0 += vreg[et] * tanh_fast(acc[et][0]);
            p1 += vreg[et] * tanh_fast(acc[et][1]);
            p2 += vreg[et] * tanh_fast(acc[et][2]);
            p3 += vreg[et] * tanh_fast(acc[et][3]);
        }
        p0 += __shfl_xor(p0, 1); p0 += __shfl_xor(p0, 2); p0 += __shfl_xor(p0, 4); p0 += __shfl_xor(p0, 8);
        p1 += __shfl_xor(p1, 1); p1 += __shfl_xor(p1, 2); p1 += __shfl_xor(p1, 4); p1 += __shfl_xor(p1, 8);
        p2 += __shfl_xor(p2, 1); p2 += __shfl_xor(p2, 2); p2 += __shfl_xor(p2, 4); p2 += __shfl_xor(p2, 8);
        p3 += __shfl_xor(p3, 1); p3 += __shfl_xor(p3, 2); p3 += __shfl_xor(p3, 4); p3 += __shfl_xor(p3, 8);
        if (m == 0){
            float4 o = make_float4(p0, p1, p2, p3);
            *(float4*)&sc[((size_t)b * QL + q) * P + pt * 64 + w * 16 + quad * 4] = o;
        }
    }
}

// softmax over scores + weighted sum
__global__ __launch_bounds__(256) void k_att_apply(const float* __restrict__ sc,
                                                   const float* __restrict__ kv, int P,
                                                   int outOff, float* __restrict__ agg){
    int b = blockIdx.x >> 7, q = blockIdx.x & 127, tid = threadIdx.x;
    __shared__ float w[256], red[256];
    w[tid] = (tid < P) ? sc[((size_t)b*QL + q)*P + tid] : -1e30f;
    __syncthreads();
    softmax256(w, red, tid);
    const float* kvb = kv + (size_t)b*P*256;
    float o = 0.f;
    #pragma unroll 4
    for (int p = 0; p < P; ++p) o += w[p] * kvb[(size_t)p*256 + tid];
    agg[((size_t)b*QL + q)*1536 + outOff + tid] = o;
}

// ---------------------------------------------------------------------------
__global__ __launch_bounds__(256) void k_q_att(const float* __restrict__ Cq,
                                               const float* __restrict__ vq,
                                               const float* __restrict__ hq,
                                               float* __restrict__ rq){
    int b = blockIdx.x, tid = threadIdx.x;
    __shared__ float vv[EE], sc[256], red[256];
    if (tid < EE) vv[tid] = vq[tid];
    __syncthreads();
    const float* cb = Cq + ((size_t)b*PL + tid)*EE;
    float s = 0.f;
    #pragma unroll 4
    for (int e = 0; e < EE; ++e) s += vv[e] * tanh_fast(cb[e]);
    sc[tid] = s;
    __syncthreads();
    softmax256(sc, red, tid);
    float o = 0.f;
    const float* hqb = hq + (size_t)b*PL*256;
    for (int p = 0; p < PL; ++p) o += sc[p] * hqb[(size_t)p*256 + tid];
    rq[(size_t)b*256 + tid] = o;
}

__global__ __launch_bounds__(256) void k_p_att(const float* __restrict__ Gp,
                                               const float* __restrict__ vp,
                                               const float* __restrict__ rqW,
                                               const float* __restrict__ agg_rep,
                                               float* __restrict__ rp){
    int b = blockIdx.x, tid = threadIdx.x;
    __shared__ float vv[EE], rw[EE], sc[256], red[256];
    if (tid < EE){
        vv[tid] = vp[tid];
        rw[tid] = rqW[(size_t)b*EE + tid];
    }
    if (tid >= 128) sc[tid] = -1e30f;
    __syncthreads();
    if (tid < QL){
        const float* gp = Gp + ((size_t)b*QL + tid)*EE;
        float s = 0.f;
        for (int e = 0; e < EE; ++e) s += vv[e] * (gp[e] + rw[e]);
        sc[tid] = s;
    }
    __syncthreads();
    softmax256(sc, red, tid);
    float o = 0.f;
    const float* ab = agg_rep + (size_t)b*QL*256;
    for (int q = 0; q < QL; ++q) o += sc[q] * ab[(size_t)q*256 + tid];
    rp[(size_t)b*256 + tid] = o;
}

__global__ __launch_bounds__(256) void k_final(const float* __restrict__ rp,
                                               const float* __restrict__ Wpred,
                                               const float* __restrict__ a_emb,
                                               float* __restrict__ out){
    int b = blockIdx.x, tid = threadIdx.x;
    __shared__ float rpv[256], enc[256];
    rpv[tid] = rp[(size_t)b*256 + tid];
    __syncthreads();
    const float* wr = Wpred + (size_t)tid*256;
    float s = 0.f;
    #pragma unroll 4
    for (int e = 0; e < 256; ++e) s += wr[e] * rpv[e];
    enc[tid] = (s > 0.f) ? s : 0.01f * s;
    __syncthreads();
    if (tid < 3){
        const float* ae = a_emb + ((size_t)b*3 + tid)*256;
        float o = 0.f;
        for (int e = 0; e < 256; ++e) o += ae[e] * enc[e];
        out[b*3 + tid] = o;
    }
}

// ---------------------------------------------------------------------------
extern "C" void kernel_launch(void* const* d_in, const int* in_sizes, int n_in,
                              void* d_out, int out_size, void* d_ws, size_t ws_size,
                              hipStream_t stream){
    const float* emb   = (const float*)d_in[0];
    const float* a_att = (const float*)d_in[1];
    const float* Wc1   = (const float*)d_in[2];
    const float* Wc2   = (const float*)d_in[3];
    const float* vc    = (const float*)d_in[4];
    const float* Wb    = (const float*)d_in[5];
    const float* Wd    = (const float*)d_in[6];
    const float* vd    = (const float*)d_in[7];
    const float* Wm    = (const float*)d_in[8];
    const float* vm    = (const float*)d_in[9];
    const float* Ws    = (const float*)d_in[10];
    const float* vs    = (const float*)d_in[11];
    const float* Wq    = (const float*)d_in[12];
    const float* vq    = (const float*)d_in[13];
    const float* Wp1   = (const float*)d_in[14];
    const float* Wp2   = (const float*)d_in[15];
    const float* vp    = (const float*)d_in[16];
    const float* Wpred = (const float*)d_in[17];
    const float* q_Wih = (const float*)d_in[18];
    const float* q_Whh = (const float*)d_in[19];
    const float* q_bih = (const float*)d_in[20];
    const float* q_bhh = (const float*)d_in[21];
    const float* p_Wih = (const float*)d_in[22];
    const float* p_Whh = (const float*)d_in[23];
    const float* p_bih = (const float*)d_in[24];
    const float* p_bhh = (const float*)d_in[25];
    const float* a_Wih = (const float*)d_in[26];
    const float* a_Whh = (const float*)d_in[27];
    const float* a_bih = (const float*)d_in[28];
    const float* a_bhh = (const float*)d_in[29];
    const float* g_Wih = (const float*)d_in[30];
    const float* g_Whh = (const float*)d_in[31];
    const float* g_bih = (const float*)d_in[32];
    const float* g_bhh = (const float*)d_in[33];
    const int* query   = (const int*)d_in[34];
    const int* passage = (const int*)d_in[35];
    const int* cneg    = (const int*)d_in[36];
    const int* cpos    = (const int*)d_in[37];
    const int* cna     = (const int*)d_in[38];

    float* ws = (float*)d_ws;

    // 1. embedding gathers (fused)
    k_gather_all<<<3312, 256, 0, stream>>>(passage, query, cneg, cpos, cna, emb, ws);

    // 2. input preactivations (x @ Wih^T + bih), z = direction
    k_gemm_v2<<<dim3(6,32,2), 256, 0, stream>>>(ws+O_XPASS, q_Wih, q_bih, ws+O_PREQ,
                                                2048, 384, 256, 98304LL, 786432LL, 384LL);
    k_gemm_v2<<<dim3(6,16,2), 256, 0, stream>>>(ws+O_XQUERY, p_Wih, p_bih, ws+O_PREP,
                                                1024, 384, 256, 98304LL, 393216LL, 384LL);
    for (int c = 0; c < 3; ++c)
        k_gemm_v2<<<dim3(6,2,2), 256, 0, stream>>>(ws+O_XCAND + c*20480, a_Wih, a_bih,
                                                   ws+O_PREA + c*61440,
                                                   80, 384, 256, 98304LL, 30720LL, 384LL);

    // 3. GRU scans
    k_gru_scan<<<16, 512, 0, stream>>>(ws+O_PREQ, q_Whh, q_bhh, ws+O_HQ, 256, 0, 0);
    k_gru_scan<<<16, 512, 0, stream>>>(ws+O_PREP, p_Whh, p_bhh, ws+O_HP, 128, 0, 0);
    k_gru_scan<<<48, 512, 0, stream>>>(ws+O_PREA, a_Whh, a_bhh, ws+O_HCAND, 10, 61440, 20480);

    // 4. candidate pooling
    k_cand_att<<<24, 256, 0, stream>>>(ws+O_HCAND, a_att, ws+O_AEMB);

    // 5. projection GEMMs
    k_gemm_v2<<<dim3(2,32,1), 256, 0, stream>>>(ws+O_HQ, Wc1, nullptr, ws+O_AQ, 2048,128,256, 0,0,0);
    k_gemm_v2<<<dim3(2,16,1), 256, 0, stream>>>(ws+O_HP, Wc2, nullptr, ws+O_AP, 1024,128,256, 0,0,0);
    k_gemm_v2<<<dim3(4,32,1), 256, 0, stream>>>(ws+O_HQ, Wb,  nullptr, ws+O_BQ, 2048,256,256, 0,0,0);
    k_gemm_v2<<<dim3(2,32,1), 256, 0, stream>>>(ws+O_HQ, Wq,  nullptr, ws+O_CQ, 2048,128,256, 0,0,0);

    // 6. attention blocks -> agg slices
    k_att_cm<<<1024, 256, 0, stream>>>(ws+O_AQ, ws+O_AP, vc, ws+O_HQ, 1.f, 512, ws+O_AGG);
    k_att_b<<<1024, 256, 0, stream>>>(ws+O_BQ, ws+O_HP, ws+O_HQ, ws+O_AGG);
    k_dms_mfma<<<dim3(4,8,8), 256, 0, stream>>>(ws+O_HQ, 256, Wd, vd, ws+O_HP, 16, ws+O_SCORE);
    k_att_apply<<<1024, 256, 0, stream>>>(ws+O_SCORE, ws+O_HQ, 256,  768, ws+O_AGG);
    k_gemm_v2<<<dim3(2,32,1), 256, 0, stream>>>(ws+O_HQ, Wm, nullptr, ws+O_SCORE, 2048,128,256, 0,0,0);
    k_gemm_v2<<<dim3(2,16,1), 256, 0, stream>>>(ws+O_HP, Wm, nullptr, ws+O_MP,    1024,128,256, 0,0,0);
    k_att_cm<<<1024, 256, 0, stream>>>(ws+O_SCORE, ws+O_MP, vm, ws+O_HQ, -1.f, 1280, ws+O_AGG);
    k_dms_mfma<<<dim3(2,16,8), 256, 0, stream>>>(ws+O_HP, 128, Ws, vs, ws+O_HP, 8, ws+O_SCB);
    k_att_apply<<<1024, 256, 0, stream>>>(ws+O_SCB, ws+O_HP, 128,  256, ws+O_AGG);

    // 7. aggregation bigru
    k_gemm_v2<<<dim3(6,16,2), 256, 0, stream>>>(ws+O_AGG, g_Wih, g_bih, ws+O_PREG,
                                                1024, 384, 1536, 589824LL, 393216LL, 384LL);
    k_gru_scan<<<16, 512, 0, stream>>>(ws+O_PREG, g_Whh, g_bhh, ws+O_AGGREP, 128, 0, 0);

    // 8. pooling + prediction
    k_q_att<<<8, 256, 0, stream>>>(ws+O_CQ, vq, ws+O_HQ, ws+O_RQ);
    k_gemm_v2<<<dim3(2,16,1), 256, 0, stream>>>(ws+O_AGGREP, Wp1, nullptr, ws+O_GP, 1024,128,256, 0,0,0);
    k_gemm_v2<<<dim3(2,1,1),  256, 0, stream>>>(ws+O_RQ, Wp2, nullptr, ws+O_RQW, 8,128,256, 0,0,0);
    k_p_att<<<8, 256, 0, stream>>>(ws+O_GP, vp, ws+O_RQW, ws+O_AGGREP, ws+O_RP);
    k_final<<<8, 256, 0, stream>>>(ws+O_RP, Wpred, ws+O_AEMB, (float*)d_out);
}

// Round 9
// 1229.096 us; speedup vs baseline: 3.3837x; 1.0304x over previous
//
#include <hip/hip_runtime.h>
#include <hip/hip_bf16.h>

// ---------------------------------------------------------------------------
// MwAN forward, MI355X. B=8, QL=128, PL=256, AL=10, E=128, EMB=256.
// Inputs fp32; internal compute fp32 in d_ws; output fp32.
// R9: GRU h_s chunks padded to stride 40 (banks {4k,4k+8,4k+16,4k+24} per
// wave-read -> conflict-free; was 4-way aliased on one 4-bank group), packed
// fp32 FMA (v_pk_fma_f32) halves dot-product issue. Candidate pre-GEMMs
// batched into one dispatch (zmode=1).
// ---------------------------------------------------------------------------

#define BB 8
#define QL 128
#define PL 256
#define AL 10
#define EE 128
#define EMB 256
#define G3 384   // 3*H gates
#define HH 128   // hidden

// ---- ws layout (in floats) ----
#define O_XPASS   ((size_t)0)        // (8,256,256)  -- dead after pre-GEMMs; reused
#define O_XQUERY  ((size_t)524288)   // (8,128,256)  -- dead after pre-GEMMs; reused for Mp
#define O_XCAND   ((size_t)786432)   // 3 x (8,10,256), chunk 20480
#define O_PREQ    ((size_t)847872)   // (2,8,256,384)
#define O_PREP    ((size_t)2420736)  // (2,8,128,384)
#define O_PREA    ((size_t)3207168)  // 3 x (2,8,10,384), chunk 61440
#define O_PREG    ((size_t)3391488)  // (2,8,128,384)
#define O_HQ      ((size_t)4177920)  // (8,256,256)
#define O_HP      ((size_t)4702208)  // (8,128,256)
#define O_HCAND   ((size_t)4964352)  // 3 x (8,10,256), chunk 20480
#define O_AEMB    ((size_t)5025792)  // (8,3,256)
#define O_AQ      ((size_t)5031936)  // (8,256,128)
#define O_AP      ((size_t)5294080)  // (8,128,128)
#define O_BQ      ((size_t)5425152)  // (8,256,256)
#define O_AGG     ((size_t)5949440)  // (8,128,1536)
#define O_AGGREP  ((size_t)7522304)  // (8,128,256)
#define O_CQ      ((size_t)7784448)  // (8,256,128)
#define O_GP      ((size_t)8046592)  // (8,128,128)
#define O_RQ      ((size_t)8177664)  // (8,256)
#define O_RQW     ((size_t)8179712)  // (8,128)
#define O_RP      ((size_t)8180736)  // (8,256)
#define O_SCORE   O_XPASS                    // (8,128,256) dot scores / then Mq
#define O_SCB     (O_XPASS + (size_t)262144) // (8,128,128) self scores
#define O_MP      O_XQUERY                   // (8,128,128) Mp = hp@Wm^T

typedef __attribute__((ext_vector_type(8))) short bf16x8;
typedef __attribute__((ext_vector_type(4))) float f32x4;
typedef __attribute__((ext_vector_type(2))) float v2f;
union U4 { uint4 u; bf16x8 v; };

// barrier with LDS-visibility only
#define BAR_LDS() asm volatile("s_waitcnt lgkmcnt(0)\n\ts_barrier" ::: "memory")

__device__ __forceinline__ float tanh_fast(float x){
    x = fminf(fmaxf(x, -20.f), 20.f);
    float e = __expf(2.f * x);
    return (e - 1.f) / (e + 1.f);
}
__device__ __forceinline__ float sig_fast(float x){
    return 1.f / (1.f + __expf(-x));
}
// pack two fp32 -> bf16 pair (round-half-up)
__device__ __forceinline__ unsigned pk2(float a, float b){
    unsigned ua = __float_as_uint(a), ub = __float_as_uint(b);
    return ((ua + 0x8000u) >> 16) | ((ub + 0x8000u) & 0xffff0000u);
}

// softmax over sc[0..255], 256 lanes
__device__ __forceinline__ void softmax256(float* sc, float* red, int tid){
    float v = sc[tid];
    red[tid] = v;
    __syncthreads();
    for (int s = 128; s > 0; s >>= 1){
        if (tid < s) red[tid] = fmaxf(red[tid], red[tid + s]);
        __syncthreads();
    }
    float m = red[0];
    __syncthreads();
    float e = __expf(v - m);
    red[tid] = e;
    __syncthreads();
    for (int s = 128; s > 0; s >>= 1){
        if (tid < s) red[tid] += red[tid + s];
        __syncthreads();
    }
    float inv = 1.f / red[0];
    __syncthreads();
    sc[tid] = e * inv;
    __syncthreads();
}

// ---------------------------------------------------------------------------
// fused embedding gathers: passage | query | cneg | cpos | cna
__global__ __launch_bounds__(256) void k_gather_all(const int* __restrict__ passage,
                                                    const int* __restrict__ query,
                                                    const int* __restrict__ cneg,
                                                    const int* __restrict__ cpos,
                                                    const int* __restrict__ cna,
                                                    const float* __restrict__ emb,
                                                    float* __restrict__ ws){
    int blk = blockIdx.x, e = threadIdx.x;
    const int* ids; size_t dst; int i;
    if (blk < 2048){            ids = passage; dst = O_XPASS;            i = blk; }
    else if (blk < 3072){       ids = query;   dst = O_XQUERY;           i = blk - 2048; }
    else if (blk < 3152){       ids = cneg;    dst = O_XCAND + 0*20480;  i = blk - 3072; }
    else if (blk < 3232){       ids = cpos;    dst = O_XCAND + 1*20480;  i = blk - 3152; }
    else {                      ids = cna;     dst = O_XCAND + 2*20480;  i = blk - 3232; }
    int id = ids[i];
    ws[dst + (size_t)i * EMB + e] = emb[(size_t)id * EMB + e];
}

// ---------------------------------------------------------------------------
// Register-tiled GEMM-NT: C[m,n] = sum_k A[m,k]*B[n,k] + bias[n].
// 64x64 tile, 256 threads, 4x4 fragment, K-chunk 32. K%32==0, N%64==0.
// zmode 0: z indexes direction on B/C/bias. zmode 1 (candidate batch):
// z = c*2+d: A += c*20480, C += c*61440 + d*30720, B/bias indexed by d.
__global__ __launch_bounds__(256) void k_gemm_v2(const float* __restrict__ A,
                                                 const float* __restrict__ Bm,
                                                 const float* __restrict__ bias,
                                                 float* __restrict__ C,
                                                 int M, int N, int K,
                                                 long long strideB, long long strideC,
                                                 long long strideBias, int zmode){
    int z = blockIdx.z;
    if (zmode == 0){
        Bm += (size_t)z * strideB;
        C  += (size_t)z * strideC;
        if (bias) bias += (size_t)z * strideBias;
    } else {
        int cc = z >> 1, d = z & 1;
        A  += (size_t)cc * 20480;
        C  += (size_t)cc * 61440 + (size_t)d * strideC;
        Bm += (size_t)d * strideB;
        if (bias) bias += (size_t)d * strideBias;
    }

    __shared__ float As[32][68];
    __shared__ float Bs[32][68];

    int tid = threadIdx.x;
    int i = tid & 15;
    int j = tid >> 4;
    int m0 = blockIdx.y * 64;
    int n0 = blockIdx.x * 64;

    int sm = tid & 63;
    int sk = (tid >> 6) * 8;

    float acc[4][4];
    #pragma unroll
    for (int r = 0; r < 4; ++r)
        #pragma unroll
        for (int c = 0; c < 4; ++c) acc[r][c] = 0.f;

    for (int k0 = 0; k0 < K; k0 += 32){
        float4 a0 = make_float4(0,0,0,0), a1 = make_float4(0,0,0,0);
        if (m0 + sm < M){
            const float* ap = A + (size_t)(m0 + sm) * K + k0 + sk;
            a0 = *(const float4*)ap;
            a1 = *(const float4*)(ap + 4);
        }
        As[sk+0][sm] = a0.x; As[sk+1][sm] = a0.y; As[sk+2][sm] = a0.z; As[sk+3][sm] = a0.w;
        As[sk+4][sm] = a1.x; As[sk+5][sm] = a1.y; As[sk+6][sm] = a1.z; As[sk+7][sm] = a1.w;
        {
            const float* bp = Bm + (size_t)(n0 + sm) * K + k0 + sk;
            float4 b0 = *(const float4*)bp;
            float4 b1 = *(const float4*)(bp + 4);
            Bs[sk+0][sm] = b0.x; Bs[sk+1][sm] = b0.y; Bs[sk+2][sm] = b0.z; Bs[sk+3][sm] = b0.w;
            Bs[sk+4][sm] = b1.x; Bs[sk+5][sm] = b1.y; Bs[sk+6][sm] = b1.z; Bs[sk+7][sm] = b1.w;
        }
        __syncthreads();
        #pragma unroll
        for (int f = 0; f < 32; ++f){
            float4 av = *(const float4*)&As[f][i*4];
            float4 bv = *(const float4*)&Bs[f][j*4];
            float ar[4] = {av.x, av.y, av.z, av.w};
            float bc[4] = {bv.x, bv.y, bv.z, bv.w};
            #pragma unroll
            for (int r = 0; r < 4; ++r)
                #pragma unroll
                for (int c = 0; c < 4; ++c)
                    acc[r][c] += ar[r] * bc[c];
        }
        __syncthreads();
    }

    float4 bv = make_float4(0,0,0,0);
    if (bias) bv = *(const float4*)&bias[n0 + j*4];
    #pragma unroll
    for (int r = 0; r < 4; ++r){
        int row = m0 + i*4 + r;
        if (row < M){
            float4 o;
            o.x = acc[r][0] + bv.x;
            o.y = acc[r][1] + bv.y;
            o.z = acc[r][2] + bv.z;
            o.w = acc[r][3] + bv.w;
            *(float4*)&C[(size_t)row * N + n0 + j*4] = o;
        }
    }
}

// ---------------------------------------------------------------------------
// GRU scan, R9: 512 thr, thread=(j,quarter). h_s chunk stride 40 (padded) so
// the 4 distinct wave addresses hit disjoint bank groups; packed fp32 FMA.
#define HSTRIDE 40
__global__ __launch_bounds__(512, 1) void k_gru_scan(const float* __restrict__ pre,
                                                     const float* __restrict__ Whh,
                                                     const float* __restrict__ bhh,
                                                     float* __restrict__ out,
                                                     int T, int preChunk, int outChunk){
    int idx = blockIdx.x;
    int c = idx >> 4, bd = idx & 15, b = bd >> 1, d = bd & 1;
    pre += (size_t)c * preChunk;
    out += (size_t)c * outChunk;

    int tid = threadIdx.x;
    int j = tid >> 2, q = tid & 3;
    int cb = q * 32;

    v2f wr2[16], wz2[16], wn2[16];
    const float* wb = Whh + (size_t)d * G3 * HH;
    {
        const float4* pr4 = (const float4*)(wb + (size_t)j * HH + cb);
        const float4* pz4 = (const float4*)(wb + (size_t)(HH + j) * HH + cb);
        const float4* pn4 = (const float4*)(wb + (size_t)(2*HH + j) * HH + cb);
        #pragma unroll
        for (int kk = 0; kk < 8; ++kk){
            float4 ur = pr4[kk], uz = pz4[kk], un = pn4[kk];
            wr2[2*kk]   = (v2f){ur.x, ur.y}; wr2[2*kk+1] = (v2f){ur.z, ur.w};
            wz2[2*kk]   = (v2f){uz.x, uz.y}; wz2[2*kk+1] = (v2f){uz.z, uz.w};
            wn2[2*kk]   = (v2f){un.x, un.y}; wn2[2*kk+1] = (v2f){un.z, un.w};
        }
    }
    const float* bb = bhh + d * G3;
    float br = bb[j], bz = bb[HH + j], bn = bb[2*HH + j];

    __shared__ __align__(16) float h_s[2][4*HSTRIDE];
    if (tid < 4*HSTRIDE) h_s[0][tid] = 0.f;
    float hprev = 0.f;

    const float* ptB = pre + ((size_t)d * BB + b) * (size_t)T * G3;
    float* ob = out + (size_t)b * T * 256 + d * HH;

    int hw = (j >> 5) * HSTRIDE + (j & 31);   // owner write slot

    const float* pt0 = ptB + (size_t)(d ? (T-1) : 0) * G3;
    float pr = pt0[j], pz = pt0[HH + j], pn = pt0[2*HH + j];
    BAR_LDS();

    for (int step = 0; step < T; ++step){
        int t = d ? (T-1-step) : step;
        float nr = 0.f, nz = 0.f, nn = 0.f;
        if (step + 1 < T){
            const float* ptn = ptB + (size_t)(d ? (T-2-step) : (step+1)) * G3;
            nr = ptn[j]; nz = ptn[HH + j]; nn = ptn[2*HH + j];
        }
        int rb = step & 1;
        const float4* h4 = (const float4*)&h_s[rb][q * HSTRIDE];
        v2f ar2 = {0.f,0.f}, az2 = {0.f,0.f}, an2 = {0.f,0.f};
        #pragma unroll
        for (int kk = 0; kk < 8; ++kk){
            float4 hv = h4[kk];
            v2f h0 = {hv.x, hv.y}, h1 = {hv.z, hv.w};
            ar2 += wr2[2*kk] * h0; ar2 += wr2[2*kk+1] * h1;
            az2 += wz2[2*kk] * h0; az2 += wz2[2*kk+1] * h1;
            an2 += wn2[2*kk] * h0; an2 += wn2[2*kk+1] * h1;
        }
        float ar = ar2.x + ar2.y, az = az2.x + az2.y, an = an2.x + an2.y;
        ar += __shfl_xor(ar, 1); ar += __shfl_xor(ar, 2);
        az += __shfl_xor(az, 1); az += __shfl_xor(az, 2);
        an += __shfl_xor(an, 1); an += __shfl_xor(an, 2);

        float r = sig_fast(pr + ar + br);
        float z = sig_fast(pz + az + bz);
        float n = tanh_fast(pn + r * (an + bn));
        float h = n + z * (hprev - n);
        hprev = h;

        if (q == 0) h_s[1-rb][hw] = h;
        if (q == 1) ob[(size_t)t * 256 + j] = h;
        pr = nr; pz = nz; pn = nn;
        BAR_LDS();
    }
}

// ---------------------------------------------------------------------------
__global__ __launch_bounds__(256) void k_cand_att(const float* __restrict__ h,
                                                  const float* __restrict__ a_att,
                                                  float* __restrict__ a_emb){
    int c = blockIdx.x / BB, b = blockIdx.x % BB, tid = threadIdx.x;
    __shared__ float att[256], sc[AL], sw[AL];
    att[tid] = a_att[tid];
    __syncthreads();
    const float* hb = h + (size_t)c * (BB*AL*256) + (size_t)b * (AL*256);
    if (tid < AL){
        float s = 0.f;
        for (int e = 0; e < 256; ++e) s += hb[tid*256 + e] * att[e];
        sc[tid] = s;
    }
    __syncthreads();
    if (tid == 0){
        float m = -1e30f;
        for (int t = 0; t < AL; ++t) m = fmaxf(m, sc[t]);
        float s = 0.f;
        for (int t = 0; t < AL; ++t){ sw[t] = __expf(sc[t] - m); s += sw[t]; }
        float inv = 1.f / s;
        for (int t = 0; t < AL; ++t) sw[t] *= inv;
    }
    __syncthreads();
    float o = 0.f;
    for (int t = 0; t < AL; ++t) o += sw[t] * hb[t*256 + tid];
    a_emb[((size_t)b*3 + c) * 256 + tid] = o;
}

// ---------------------------------------------------------------------------
// additive attention: score[p] = sum_e v[e]*tanh(Aq[b,p,e] + sign*Ap[b,q,e]);
__global__ __launch_bounds__(256) void k_att_cm(const float* __restrict__ Aq,
                                                const float* __restrict__ Ap,
                                                const float* __restrict__ v,
                                                const float* __restrict__ vals,
                                                float sign, int outOff,
                                                float* __restrict__ agg){
    int b = blockIdx.x >> 7, q = blockIdx.x & 127, tid = threadIdx.x;
    __shared__ float apv[EE], vcv[EE], sc[256], red[256];
    if (tid < EE){
        apv[tid] = sign * Ap[((size_t)b*QL + q)*EE + tid];
        vcv[tid] = v[tid];
    }
    __syncthreads();
    const float* aqp = Aq + ((size_t)b*PL + tid)*EE;
    float s = 0.f;
    #pragma unroll 4
    for (int e = 0; e < EE; ++e) s += vcv[e] * tanh_fast(aqp[e] + apv[e]);
    sc[tid] = s;
    __syncthreads();
    softmax256(sc, red, tid);
    float o = 0.f;
    const float* vb = vals + (size_t)b*PL*256;
    for (int p = 0; p < PL; ++p) o += sc[p] * vb[(size_t)p*256 + tid];
    agg[((size_t)b*QL + q)*1536 + outOff + tid] = o;
}

// bilinear attention + fused hp copy into agg[...,0:256]
__global__ __launch_bounds__(256) void k_att_b(const float* __restrict__ Bq,
                                               const float* __restrict__ hp,
                                               const float* __restrict__ hq,
                                               float* __restrict__ agg){
    int b = blockIdx.x >> 7, q = blockIdx.x & 127, tid = threadIdx.x;
    __shared__ float xq[256], sc[256], red[256];
    float xv = hp[((size_t)b*QL + q)*256 + tid];
    xq[tid] = xv;
    agg[((size_t)b*QL + q)*1536 + tid] = xv;   // fused copy_hp
    __syncthreads();
    const float* bq = Bq + ((size_t)b*PL + tid)*256;
    float s = 0.f;
    #pragma unroll 4
    for (int e = 0; e < 256; ++e) s += xq[e] * bq[e];
    sc[tid] = s;
    __syncthreads();
    softmax256(sc, red, tid);
    float o = 0.f;
    const float* hqb = hq + (size_t)b*PL*256;
    for (int p = 0; p < PL; ++p) o += sc[p] * hqb[(size_t)p*256 + tid];
    agg[((size_t)b*QL + q)*1536 + 1024 + tid] = o;
}

// ---------------------------------------------------------------------------
// MFMA dms scores: sc[b,q,p] = sum_e v[e]*tanh( sum_f W[e,f]*kv[b,p,f]*xq[b,q,f] )
__global__ __launch_bounds__(256, 1) void k_dms_mfma(const float* __restrict__ kv, int P,
                                                     const float* __restrict__ Wmat,
                                                     const float* __restrict__ v,
                                                     const float* __restrict__ xsrc,
                                                     int qPerBlock,
                                                     float* __restrict__ sc){
    int pt = blockIdx.x, qc = blockIdx.y, b = blockIdx.z;
    int tid = threadIdx.x;
    int w = tid >> 6, lane = tid & 63, m = lane & 15, quad = lane >> 4;

    __shared__ unsigned Hlds[64 * 132];
    __shared__ float hpq[256];

    {
        const float* hr = kv + ((size_t)b * P + pt * 64 + w * 16 + m) * 256;
        unsigned* dst = &Hlds[(w * 16 + m) * 132];
        #pragma unroll
        for (int k0 = 0; k0 < 8; ++k0){
            const float* p0 = hr + k0 * 32 + quad * 8;
            float4 x0 = *(const float4*)p0;
            float4 x1 = *(const float4*)(p0 + 4);
            uint4 u;
            u.x = pk2(x0.x, x0.y); u.y = pk2(x0.z, x0.w);
            u.z = pk2(x1.x, x1.y); u.w = pk2(x1.z, x1.w);
            *(uint4*)&dst[k0 * 16 + quad * 4] = u;
        }
    }

    bf16x8 bfr[8][8];
    #pragma unroll
    for (int et = 0; et < 8; ++et){
        const float* wr = Wmat + (size_t)(et * 16 + m) * 256;
        #pragma unroll
        for (int k0 = 0; k0 < 8; ++k0){
            const float* p0 = wr + k0 * 32 + quad * 8;
            float4 x0 = *(const float4*)p0;
            float4 x1 = *(const float4*)(p0 + 4);
            U4 uu;
            uu.u.x = pk2(x0.x, x0.y); uu.u.y = pk2(x0.z, x0.w);
            uu.u.z = pk2(x1.x, x1.y); uu.u.w = pk2(x1.z, x1.w);
            bfr[et][k0] = uu.v;
        }
    }
    float vreg[8];
    #pragma unroll
    for (int et = 0; et < 8; ++et) vreg[et] = v[et * 16 + m];

    __syncthreads();

    const unsigned* hrow = &Hlds[(w * 16 + m) * 132];

    for (int qi = 0; qi < qPerBlock; ++qi){
        int q = qc * qPerBlock + qi;
        __syncthreads();
        hpq[tid] = xsrc[((size_t)b * QL + q) * 256 + tid];
        __syncthreads();

        bf16x8 afr[8];
        #pragma unroll
        for (int k0 = 0; k0 < 8; ++k0){
            uint4 hv = *(const uint4*)&hrow[k0 * 16 + quad * 4];
            const float* hf = &hpq[k0 * 32 + quad * 8];
            float f0 = __uint_as_float(hv.x << 16)         * hf[0];
            float f1 = __uint_as_float(hv.x & 0xffff0000u) * hf[1];
            float f2 = __uint_as_float(hv.y << 16)         * hf[2];
            float f3 = __uint_as_float(hv.y & 0xffff0000u) * hf[3];
            float f4 = __uint_as_float(hv.z << 16)         * hf[4];
            float f5 = __uint_as_float(hv.z & 0xffff0000u) * hf[5];
            float f6 = __uint_as_float(hv.w << 16)         * hf[6];
            float f7 = __uint_as_float(hv.w & 0xffff0000u) * hf[7];
            U4 uu;
            uu.u.x = pk2(f0, f1); uu.u.y = pk2(f2, f3);
            uu.u.z = pk2(f4, f5); uu.u.w = pk2(f6, f7);
            afr[k0] = uu.v;
        }

        f32x4 acc[8];
        #pragma unroll
        for (int et = 0; et < 8; ++et){
            acc[et][0] = 0.f; acc[et][1] = 0.f; acc[et][2] = 0.f; acc[et][3] = 0.f;
        }
        #pragma unroll
        for (int k0 = 0; k0 < 8; ++k0)
            #pragma unroll
            for (int et = 0; et < 8; ++et)
                acc[et] = __builtin_amdgcn_mfma_f32_16x16x32_bf16(afr[k0], bfr[et][k0], acc[et], 0, 0, 0);

        float p0 = 0.f, p1 = 0.f, p2 = 0.f, p3 = 0.f;
        #pragma unroll
        for (int et = 0; et < 8; ++et){
            p0 += vreg[et] * tanh_fast(acc[et][0]);
            p1 += vreg[et] * tanh_fast(acc[et][1]);
            p2 += vreg[et] * tanh_fast(acc[et][2]);
            p3 += vreg[et] * tanh_fast(acc[et][3]);
        }
        p0 += __shfl_xor(p0, 1); p0 += __shfl_xor(p0, 2); p0 += __shfl_xor(p0, 4); p0 += __shfl_xor(p0, 8);
        p1 += __shfl_xor(p1, 1); p1 += __shfl_xor(p1, 2); p1 += __shfl_xor(p1, 4); p1 += __shfl_xor(p1, 8);
        p2 += __shfl_xor(p2, 1); p2 += __shfl_xor(p2, 2); p2 += __shfl_xor(p2, 4); p2 += __shfl_xor(p2, 8);
        p3 += __shfl_xor(p3, 1); p3 += __shfl_xor(p3, 2); p3 += __shfl_xor(p3, 4); p3 += __shfl_xor(p3, 8);
        if (m == 0){
            float4 o = make_float4(p0, p1, p2, p3);
            *(float4*)&sc[((size_t)b * QL + q) * P + pt * 64 + w * 16 + quad * 4] = o;
        }
    }
}

// softmax over scores + weighted sum
__global__ __launch_bounds__(256) void k_att_apply(const float* __restrict__ sc,
                                                   const float* __restrict__ kv, int P,
                                                   int outOff, float* __restrict__ agg){
    int b = blockIdx.x >> 7, q = blockIdx.x & 127, tid = threadIdx.x;
    __shared__ float w[256], red[256];
    w[tid] = (tid < P) ? sc[((size_t)b*QL + q)*P + tid] : -1e30f;
    __syncthreads();
    softmax256(w, red, tid);
    const float* kvb = kv + (size_t)b*P*256;
    float o = 0.f;
    #pragma unroll 4
    for (int p = 0; p < P; ++p) o += w[p] * kvb[(size_t)p*256 + tid];
    agg[((size_t)b*QL + q)*1536 + outOff + tid] = o;
}

// ---------------------------------------------------------------------------
__global__ __launch_bounds__(256) void k_q_att(const float* __restrict__ Cq,
                                               const float* __restrict__ vq,
                                               const float* __restrict__ hq,
                                               float* __restrict__ rq){
    int b = blockIdx.x, tid = threadIdx.x;
    __shared__ float vv[EE], sc[256], red[256];
    if (tid < EE) vv[tid] = vq[tid];
    __syncthreads();
    const float* cb = Cq + ((size_t)b*PL + tid)*EE;
    float s = 0.f;
    #pragma unroll 4
    for (int e = 0; e < EE; ++e) s += vv[e] * tanh_fast(cb[e]);
    sc[tid] = s;
    __syncthreads();
    softmax256(sc, red, tid);
    float o = 0.f;
    const float* hqb = hq + (size_t)b*PL*256;
    for (int p = 0; p < PL; ++p) o += sc[p] * hqb[(size_t)p*256 + tid];
    rq[(size_t)b*256 + tid] = o;
}

__global__ __launch_bounds__(256) void k_p_att(const float* __restrict__ Gp,
                                               const float* __restrict__ vp,
                                               const float* __restrict__ rqW,
                                               const float* __restrict__ agg_rep,
                                               float* __restrict__ rp){
    int b = blockIdx.x, tid = threadIdx.x;
    __shared__ float vv[EE], rw[EE], sc[256], red[256];
    if (tid < EE){
        vv[tid] = vp[tid];
        rw[tid] = rqW[(size_t)b*EE + tid];
    }
    if (tid >= 128) sc[tid] = -1e30f;
    __syncthreads();
    if (tid < QL){
        const float* gp = Gp + ((size_t)b*QL + tid)*EE;
        float s = 0.f;
        for (int e = 0; e < EE; ++e) s += vv[e] * (gp[e] + rw[e]);
        sc[tid] = s;
    }
    __syncthreads();
    softmax256(sc, red, tid);
    float o = 0.f;
    const float* ab = agg_rep + (size_t)b*QL*256;
    for (int q = 0; q < QL; ++q) o += sc[q] * ab[(size_t)q*256 + tid];
    rp[(size_t)b*256 + tid] = o;
}

__global__ __launch_bounds__(256) void k_final(const float* __restrict__ rp,
                                               const float* __restrict__ Wpred,
                                               const float* __restrict__ a_emb,
                                               float* __restrict__ out){
    int b = blockIdx.x, tid = threadIdx.x;
    __shared__ float rpv[256], enc[256];
    rpv[tid] = rp[(size_t)b*256 + tid];
    __syncthreads();
    const float* wr = Wpred + (size_t)tid*256;
    float s = 0.f;
    #pragma unroll 4
    for (int e = 0; e < 256; ++e) s += wr[e] * rpv[e];
    enc[tid] = (s > 0.f) ? s : 0.01f * s;
    __syncthreads();
    if (tid < 3){
        const float* ae = a_emb + ((size_t)b*3 + tid)*256;
        float o = 0.f;
        for (int e = 0; e < 256; ++e) o += ae[e] * enc[e];
        out[b*3 + tid] = o;
    }
}

// ---------------------------------------------------------------------------
extern "C" void kernel_launch(void* const* d_in, const int* in_sizes, int n_in,
                              void* d_out, int out_size, void* d_ws, size_t ws_size,
                              hipStream_t stream){
    const float* emb   = (const float*)d_in[0];
    const float* a_att = (const float*)d_in[1];
    const float* Wc1   = (const float*)d_in[2];
    const float* Wc2   = (const float*)d_in[3];
    const float* vc    = (const float*)d_in[4];
    const float* Wb    = (const float*)d_in[5];
    const float* Wd    = (const float*)d_in[6];
    const float* vd    = (const float*)d_in[7];
    const float* Wm    = (const float*)d_in[8];
    const float* vm    = (const float*)d_in[9];
    const float* Ws    = (const float*)d_in[10];
    const float* vs    = (const float*)d_in[11];
    const float* Wq    = (const float*)d_in[12];
    const float* vq    = (const float*)d_in[13];
    const float* Wp1   = (const float*)d_in[14];
    const float* Wp2   = (const float*)d_in[15];
    const float* vp    = (const float*)d_in[16];
    const float* Wpred = (const float*)d_in[17];
    const float* q_Wih = (const float*)d_in[18];
    const float* q_Whh = (const float*)d_in[19];
    const float* q_bih = (const float*)d_in[20];
    const float* q_bhh = (const float*)d_in[21];
    const float* p_Wih = (const float*)d_in[22];
    const float* p_Whh = (const float*)d_in[23];
    const float* p_bih = (const float*)d_in[24];
    const float* p_bhh = (const float*)d_in[25];
    const float* a_Wih = (const float*)d_in[26];
    const float* a_Whh = (const float*)d_in[27];
    const float* a_bih = (const float*)d_in[28];
    const float* a_bhh = (const float*)d_in[29];
    const float* g_Wih = (const float*)d_in[30];
    const float* g_Whh = (const float*)d_in[31];
    const float* g_bih = (const float*)d_in[32];
    const float* g_bhh = (const float*)d_in[33];
    const int* query   = (const int*)d_in[34];
    const int* passage = (const int*)d_in[35];
    const int* cneg    = (const int*)d_in[36];
    const int* cpos    = (const int*)d_in[37];
    const int* cna     = (const int*)d_in[38];

    float* ws = (float*)d_ws;

    // 1. embedding gathers (fused)
    k_gather_all<<<3312, 256, 0, stream>>>(passage, query, cneg, cpos, cna, emb, ws);

    // 2. input preactivations (x @ Wih^T + bih)
    k_gemm_v2<<<dim3(6,32,2), 256, 0, stream>>>(ws+O_XPASS, q_Wih, q_bih, ws+O_PREQ,
                                                2048, 384, 256, 98304LL, 786432LL, 384LL, 0);
    k_gemm_v2<<<dim3(6,16,2), 256, 0, stream>>>(ws+O_XQUERY, p_Wih, p_bih, ws+O_PREP,
                                                1024, 384, 256, 98304LL, 393216LL, 384LL, 0);
    // candidate batch: z = c*2+d (6 z-slices in one dispatch)
    k_gemm_v2<<<dim3(6,2,6), 256, 0, stream>>>(ws+O_XCAND, a_Wih, a_bih, ws+O_PREA,
                                               80, 384, 256, 98304LL, 30720LL, 384LL, 1);

    // 3. GRU scans
    k_gru_scan<<<16, 512, 0, stream>>>(ws+O_PREQ, q_Whh, q_bhh, ws+O_HQ, 256, 0, 0);
    k_gru_scan<<<16, 512, 0, stream>>>(ws+O_PREP, p_Whh, p_bhh, ws+O_HP, 128, 0, 0);
    k_gru_scan<<<48, 512, 0, stream>>>(ws+O_PREA, a_Whh, a_bhh, ws+O_HCAND, 10, 61440, 20480);

    // 4. candidate pooling
    k_cand_att<<<24, 256, 0, stream>>>(ws+O_HCAND, a_att, ws+O_AEMB);

    // 5. projection GEMMs
    k_gemm_v2<<<dim3(2,32,1), 256, 0, stream>>>(ws+O_HQ, Wc1, nullptr, ws+O_AQ, 2048,128,256, 0,0,0, 0);
    k_gemm_v2<<<dim3(2,16,1), 256, 0, stream>>>(ws+O_HP, Wc2, nullptr, ws+O_AP, 1024,128,256, 0,0,0, 0);
    k_gemm_v2<<<dim3(4,32,1), 256, 0, stream>>>(ws+O_HQ, Wb,  nullptr, ws+O_BQ, 2048,256,256, 0,0,0, 0);
    k_gemm_v2<<<dim3(2,32,1), 256, 0, stream>>>(ws+O_HQ, Wq,  nullptr, ws+O_CQ, 2048,128,256, 0,0,0, 0);

    // 6. attention blocks -> agg slices
    k_att_cm<<<1024, 256, 0, stream>>>(ws+O_AQ, ws+O_AP, vc, ws+O_HQ, 1.f, 512, ws+O_AGG);
    k_att_b<<<1024, 256, 0, stream>>>(ws+O_BQ, ws+O_HP, ws+O_HQ, ws+O_AGG);
    k_dms_mfma<<<dim3(4,8,8), 256, 0, stream>>>(ws+O_HQ, 256, Wd, vd, ws+O_HP, 16, ws+O_SCORE);
    k_att_apply<<<1024, 256, 0, stream>>>(ws+O_SCORE, ws+O_HQ, 256,  768, ws+O_AGG);
    k_gemm_v2<<<dim3(2,32,1), 256, 0, stream>>>(ws+O_HQ, Wm, nullptr, ws+O_SCORE, 2048,128,256, 0,0,0, 0);
    k_gemm_v2<<<dim3(2,16,1), 256, 0, stream>>>(ws+O_HP, Wm, nullptr, ws+O_MP,    1024,128,256, 0,0,0, 0);
    k_att_cm<<<1024, 256, 0, stream>>>(ws+O_SCORE, ws+O_MP, vm, ws+O_HQ, -1.f, 1280, ws+O_AGG);
    k_dms_mfma<<<dim3(2,16,8), 256, 0, stream>>>(ws+O_HP, 128, Ws, vs, ws+O_HP, 8, ws+O_SCB);
    k_att_apply<<<1024, 256, 0, stream>>>(ws+O_SCB, ws+O_HP, 128,  256, ws+O_AGG);

    // 7. aggregation bigru
    k_gemm_v2<<<dim3(6,16,2), 256, 0, stream>>>(ws+O_AGG, g_Wih, g_bih, ws+O_PREG,
                                                1024, 384, 1536, 589824LL, 393216LL, 384LL, 0);
    k_gru_scan<<<16, 512, 0, stream>>>(ws+O_PREG, g_Whh, g_bhh, ws+O_AGGREP, 128, 0, 0);

    // 8. pooling + prediction
    k_q_att<<<8, 256, 0, stream>>>(ws+O_CQ, vq, ws+O_HQ, ws+O_RQ);
    k_gemm_v2<<<dim3(2,16,1), 256, 0, stream>>>(ws+O_AGGREP, Wp1, nullptr, ws+O_GP, 1024,128,256, 0,0,0, 0);
    k_gemm_v2<<<dim3(2,1,1),  256, 0, stream>>>(ws+O_RQ, Wp2, nullptr, ws+O_RQW, 8,128,256, 0,0,0, 0);
    k_p_att<<<8, 256, 0, stream>>>(ws+O_GP, vp, ws+O_RQW, ws+O_AGGREP, ws+O_RP);
    k_final<<<8, 256, 0, stream>>>(ws+O_RP, Wpred, ws+O_AEMB, (float*)d_out);
}

// Round 10
// 1056.672 us; speedup vs baseline: 3.9358x; 1.1632x over previous
//
#include <hip/hip_runtime.h>
#include <hip/hip_bf16.h>

// ---------------------------------------------------------------------------
// MwAN forward, MI355X. B=8, QL=128, PL=256, AL=10, E=128, EMB=256.
// Inputs fp32; internal compute fp32 in d_ws; output fp32.
// R10: (1) dms MFMA split into two e-half dispatches: bfr[4][8]=128 VGPRs,
//      kills the scratch spill (was VGPR=256 + 28MB scratch WRITE).
//      (2) xor1/xor2 lane reductions via DPP quad_perm (VALU) instead of
//      ds_swizzle (DS pipe) in GRU + dms epilogue.
//      (3) q/p/cand GRU scans fused into one dispatch (independent chains).
// ---------------------------------------------------------------------------

#define BB 8
#define QL 128
#define PL 256
#define AL 10
#define EE 128
#define EMB 256
#define G3 384   // 3*H gates
#define HH 128   // hidden

// ---- ws layout (in floats) ----
#define O_XPASS   ((size_t)0)        // (8,256,256)  -- dead after pre-GEMMs; reused
#define O_XQUERY  ((size_t)524288)   // (8,128,256)  -- dead after pre-GEMMs; reused
#define O_XCAND   ((size_t)786432)   // 3 x (8,10,256), chunk 20480
#define O_PREQ    ((size_t)847872)   // (2,8,256,384)
#define O_PREP    ((size_t)2420736)  // (2,8,128,384)
#define O_PREA    ((size_t)3207168)  // 3 x (2,8,10,384), chunk 61440
#define O_PREG    ((size_t)3391488)  // (2,8,128,384)
#define O_HQ      ((size_t)4177920)  // (8,256,256)
#define O_HP      ((size_t)4702208)  // (8,128,256)
#define O_HCAND   ((size_t)4964352)  // 3 x (8,10,256), chunk 20480
#define O_AEMB    ((size_t)5025792)  // (8,3,256)
#define O_AQ      ((size_t)5031936)  // (8,256,128)
#define O_AP      ((size_t)5294080)  // (8,128,128)
#define O_BQ      ((size_t)5425152)  // (8,256,256)
#define O_AGG     ((size_t)5949440)  // (8,128,1536)
#define O_AGGREP  ((size_t)7522304)  // (8,128,256)
#define O_CQ      ((size_t)7784448)  // (8,256,128)
#define O_GP      ((size_t)8046592)  // (8,128,128)
#define O_RQ      ((size_t)8177664)  // (8,256)
#define O_RQW     ((size_t)8179712)  // (8,128)
#define O_RP      ((size_t)8180736)  // (8,256)
// score staging (reuses dead gather regions, stream-ordered):
#define O_SCD0    O_XPASS                     // dot scores, e-half 0 (8,128,256)
#define O_SCD1    (O_XPASS + (size_t)262144)  // dot scores, e-half 1
#define O_MQ      O_XPASS                     // Mq = hq@Wm^T (after dot apply)
#define O_SCS0    (O_XPASS + (size_t)262144)  // self scores half 0 (8,128,128)
#define O_SCS1    (O_XPASS + (size_t)393216)  // self scores half 1
#define O_MP      O_XQUERY                    // Mp = hp@Wm^T

typedef __attribute__((ext_vector_type(8))) short bf16x8;
typedef __attribute__((ext_vector_type(4))) float f32x4;
typedef __attribute__((ext_vector_type(2))) float v2f;
union U4 { uint4 u; bf16x8 v; };

// barrier with LDS-visibility only
#define BAR_LDS() asm volatile("s_waitcnt lgkmcnt(0)\n\ts_barrier" ::: "memory")

// x += xor1(x); x += xor2(x) via DPP quad_perm (VALU, not DS pipe)
__device__ __forceinline__ float dpp_xadd12(float x){
    int a = __builtin_amdgcn_update_dpp(0, __float_as_int(x), 0xB1, 0xF, 0xF, true); // [1,0,3,2]
    x += __int_as_float(a);
    int b = __builtin_amdgcn_update_dpp(0, __float_as_int(x), 0x4E, 0xF, 0xF, true); // [2,3,0,1]
    x += __int_as_float(b);
    return x;
}

__device__ __forceinline__ float tanh_fast(float x){
    x = fminf(fmaxf(x, -20.f), 20.f);
    float e = __expf(2.f * x);
    return (e - 1.f) / (e + 1.f);
}
__device__ __forceinline__ float sig_fast(float x){
    return 1.f / (1.f + __expf(-x));
}
// pack two fp32 -> bf16 pair (round-half-up)
__device__ __forceinline__ unsigned pk2(float a, float b){
    unsigned ua = __float_as_uint(a), ub = __float_as_uint(b);
    return ((ua + 0x8000u) >> 16) | ((ub + 0x8000u) & 0xffff0000u);
}

// softmax over sc[0..255], 256 lanes
__device__ __forceinline__ void softmax256(float* sc, float* red, int tid){
    float v = sc[tid];
    red[tid] = v;
    __syncthreads();
    for (int s = 128; s > 0; s >>= 1){
        if (tid < s) red[tid] = fmaxf(red[tid], red[tid + s]);
        __syncthreads();
    }
    float m = red[0];
    __syncthreads();
    float e = __expf(v - m);
    red[tid] = e;
    __syncthreads();
    for (int s = 128; s > 0; s >>= 1){
        if (tid < s) red[tid] += red[tid + s];
        __syncthreads();
    }
    float inv = 1.f / red[0];
    __syncthreads();
    sc[tid] = e * inv;
    __syncthreads();
}

// ---------------------------------------------------------------------------
// fused embedding gathers
__global__ __launch_bounds__(256) void k_gather_all(const int* __restrict__ passage,
                                                    const int* __restrict__ query,
                                                    const int* __restrict__ cneg,
                                                    const int* __restrict__ cpos,
                                                    const int* __restrict__ cna,
                                                    const float* __restrict__ emb,
                                                    float* __restrict__ ws){
    int blk = blockIdx.x, e = threadIdx.x;
    const int* ids; size_t dst; int i;
    if (blk < 2048){            ids = passage; dst = O_XPASS;            i = blk; }
    else if (blk < 3072){       ids = query;   dst = O_XQUERY;           i = blk - 2048; }
    else if (blk < 3152){       ids = cneg;    dst = O_XCAND + 0*20480;  i = blk - 3072; }
    else if (blk < 3232){       ids = cpos;    dst = O_XCAND + 1*20480;  i = blk - 3152; }
    else {                      ids = cna;     dst = O_XCAND + 2*20480;  i = blk - 3232; }
    int id = ids[i];
    ws[dst + (size_t)i * EMB + e] = emb[(size_t)id * EMB + e];
}

// ---------------------------------------------------------------------------
// Register-tiled GEMM-NT (R9, unchanged)
__global__ __launch_bounds__(256) void k_gemm_v2(const float* __restrict__ A,
                                                 const float* __restrict__ Bm,
                                                 const float* __restrict__ bias,
                                                 float* __restrict__ C,
                                                 int M, int N, int K,
                                                 long long strideB, long long strideC,
                                                 long long strideBias, int zmode){
    int z = blockIdx.z;
    if (zmode == 0){
        Bm += (size_t)z * strideB;
        C  += (size_t)z * strideC;
        if (bias) bias += (size_t)z * strideBias;
    } else {
        int cc = z >> 1, d = z & 1;
        A  += (size_t)cc * 20480;
        C  += (size_t)cc * 61440 + (size_t)d * strideC;
        Bm += (size_t)d * strideB;
        if (bias) bias += (size_t)d * strideBias;
    }

    __shared__ float As[32][68];
    __shared__ float Bs[32][68];

    int tid = threadIdx.x;
    int i = tid & 15;
    int j = tid >> 4;
    int m0 = blockIdx.y * 64;
    int n0 = blockIdx.x * 64;

    int sm = tid & 63;
    int sk = (tid >> 6) * 8;

    float acc[4][4];
    #pragma unroll
    for (int r = 0; r < 4; ++r)
        #pragma unroll
        for (int c = 0; c < 4; ++c) acc[r][c] = 0.f;

    for (int k0 = 0; k0 < K; k0 += 32){
        float4 a0 = make_float4(0,0,0,0), a1 = make_float4(0,0,0,0);
        if (m0 + sm < M){
            const float* ap = A + (size_t)(m0 + sm) * K + k0 + sk;
            a0 = *(const float4*)ap;
            a1 = *(const float4*)(ap + 4);
        }
        As[sk+0][sm] = a0.x; As[sk+1][sm] = a0.y; As[sk+2][sm] = a0.z; As[sk+3][sm] = a0.w;
        As[sk+4][sm] = a1.x; As[sk+5][sm] = a1.y; As[sk+6][sm] = a1.z; As[sk+7][sm] = a1.w;
        {
            const float* bp = Bm + (size_t)(n0 + sm) * K + k0 + sk;
            float4 b0 = *(const float4*)bp;
            float4 b1 = *(const float4*)(bp + 4);
            Bs[sk+0][sm] = b0.x; Bs[sk+1][sm] = b0.y; Bs[sk+2][sm] = b0.z; Bs[sk+3][sm] = b0.w;
            Bs[sk+4][sm] = b1.x; Bs[sk+5][sm] = b1.y; Bs[sk+6][sm] = b1.z; Bs[sk+7][sm] = b1.w;
        }
        __syncthreads();
        #pragma unroll
        for (int f = 0; f < 32; ++f){
            float4 av = *(const float4*)&As[f][i*4];
            float4 bv = *(const float4*)&Bs[f][j*4];
            float ar[4] = {av.x, av.y, av.z, av.w};
            float bc[4] = {bv.x, bv.y, bv.z, bv.w};
            #pragma unroll
            for (int r = 0; r < 4; ++r)
                #pragma unroll
                for (int c = 0; c < 4; ++c)
                    acc[r][c] += ar[r] * bc[c];
        }
        __syncthreads();
    }

    float4 bv = make_float4(0,0,0,0);
    if (bias) bv = *(const float4*)&bias[n0 + j*4];
    #pragma unroll
    for (int r = 0; r < 4; ++r){
        int row = m0 + i*4 + r;
        if (row < M){
            float4 o;
            o.x = acc[r][0] + bv.x;
            o.y = acc[r][1] + bv.y;
            o.z = acc[r][2] + bv.z;
            o.w = acc[r][3] + bv.w;
            *(float4*)&C[(size_t)row * N + n0 + j*4] = o;
        }
    }
}

// ---------------------------------------------------------------------------
// GRU scan body (R9 layout, DPP reductions). 512 thr, thread=(j,quarter),
// h_s stride 40 (conflict-free), 96-float weight cache, 1 barrier/step.
#define HSTRIDE 40
__device__ __forceinline__ void gru_body(const float* __restrict__ pre,
                                         const float* __restrict__ Whh,
                                         const float* __restrict__ bhh,
                                         float* __restrict__ out,
                                         int T, int b, int d){
    int tid = threadIdx.x;
    int j = tid >> 2, q = tid & 3;
    int cb = q * 32;

    v2f wr2[16], wz2[16], wn2[16];
    const float* wb = Whh + (size_t)d * G3 * HH;
    {
        const float4* pr4 = (const float4*)(wb + (size_t)j * HH + cb);
        const float4* pz4 = (const float4*)(wb + (size_t)(HH + j) * HH + cb);
        const float4* pn4 = (const float4*)(wb + (size_t)(2*HH + j) * HH + cb);
        #pragma unroll
        for (int kk = 0; kk < 8; ++kk){
            float4 ur = pr4[kk], uz = pz4[kk], un = pn4[kk];
            wr2[2*kk]   = (v2f){ur.x, ur.y}; wr2[2*kk+1] = (v2f){ur.z, ur.w};
            wz2[2*kk]   = (v2f){uz.x, uz.y}; wz2[2*kk+1] = (v2f){uz.z, uz.w};
            wn2[2*kk]   = (v2f){un.x, un.y}; wn2[2*kk+1] = (v2f){un.z, un.w};
        }
    }
    const float* bb = bhh + d * G3;
    float br = bb[j], bz = bb[HH + j], bn = bb[2*HH + j];

    __shared__ __align__(16) float h_s[2][4*HSTRIDE];
    if (tid < 4*HSTRIDE) h_s[0][tid] = 0.f;
    float hprev = 0.f;

    const float* ptB = pre + ((size_t)d * BB + b) * (size_t)T * G3;
    float* ob = out + (size_t)b * T * 256 + d * HH;

    int hw = (j >> 5) * HSTRIDE + (j & 31);   // owner write slot

    const float* pt0 = ptB + (size_t)(d ? (T-1) : 0) * G3;
    float pr = pt0[j], pz = pt0[HH + j], pn = pt0[2*HH + j];
    BAR_LDS();

    for (int step = 0; step < T; ++step){
        int t = d ? (T-1-step) : step;
        float nr = 0.f, nz = 0.f, nn = 0.f;
        if (step + 1 < T){
            const float* ptn = ptB + (size_t)(d ? (T-2-step) : (step+1)) * G3;
            nr = ptn[j]; nz = ptn[HH + j]; nn = ptn[2*HH + j];
        }
        int rb = step & 1;
        const float4* h4 = (const float4*)&h_s[rb][q * HSTRIDE];
        v2f ar2 = {0.f,0.f}, az2 = {0.f,0.f}, an2 = {0.f,0.f};
        #pragma unroll
        for (int kk = 0; kk < 8; ++kk){
            float4 hv = h4[kk];
            v2f h0 = {hv.x, hv.y}, h1 = {hv.z, hv.w};
            ar2 += wr2[2*kk] * h0; ar2 += wr2[2*kk+1] * h1;
            az2 += wz2[2*kk] * h0; az2 += wz2[2*kk+1] * h1;
            an2 += wn2[2*kk] * h0; an2 += wn2[2*kk+1] * h1;
        }
        float ar = dpp_xadd12(ar2.x + ar2.y);
        float az = dpp_xadd12(az2.x + az2.y);
        float an = dpp_xadd12(an2.x + an2.y);

        float r = sig_fast(pr + ar + br);
        float z = sig_fast(pz + az + bz);
        float n = tanh_fast(pn + r * (an + bn));
        float h = n + z * (hprev - n);
        hprev = h;

        if (q == 0) h_s[1-rb][hw] = h;
        if (q == 1) ob[(size_t)t * 256 + j] = h;
        pr = nr; pz = nz; pn = nn;
        BAR_LDS();
    }
}

// fused forward scans: blocks 0-15 q (T=256), 16-31 p (T=128), 32-79 cand (T=10)
__global__ __launch_bounds__(512, 1) void k_gru_fwd(float* __restrict__ ws,
                                                    const float* __restrict__ qW, const float* __restrict__ qB,
                                                    const float* __restrict__ pW, const float* __restrict__ pB,
                                                    const float* __restrict__ aW, const float* __restrict__ aB){
    int blk = blockIdx.x;
    const float *pre, *W, *bb; float* out; int T, bd;
    if (blk < 16){
        pre = ws + O_PREQ; out = ws + O_HQ; W = qW; bb = qB; T = 256; bd = blk;
    } else if (blk < 32){
        pre = ws + O_PREP; out = ws + O_HP; W = pW; bb = pB; T = 128; bd = blk - 16;
    } else {
        int local = blk - 32; int c = local >> 4;
        pre = ws + O_PREA + (size_t)c * 61440; out = ws + O_HCAND + (size_t)c * 20480;
        W = aW; bb = aB; T = 10; bd = local & 15;
    }
    gru_body(pre, W, bb, out, T, bd >> 1, bd & 1);
}

// single scan (aggregation GRU)
__global__ __launch_bounds__(512, 1) void k_gru_scan(const float* __restrict__ pre,
                                                     const float* __restrict__ Whh,
                                                     const float* __restrict__ bhh,
                                                     float* __restrict__ out, int T){
    int bd = blockIdx.x & 15;
    gru_body(pre, Whh, bhh, out, T, bd >> 1, bd & 1);
}

// ---------------------------------------------------------------------------
__global__ __launch_bounds__(256) void k_cand_att(const float* __restrict__ h,
                                                  const float* __restrict__ a_att,
                                                  float* __restrict__ a_emb){
    int c = blockIdx.x / BB, b = blockIdx.x % BB, tid = threadIdx.x;
    __shared__ float att[256], sc[AL], sw[AL];
    att[tid] = a_att[tid];
    __syncthreads();
    const float* hb = h + (size_t)c * (BB*AL*256) + (size_t)b * (AL*256);
    if (tid < AL){
        float s = 0.f;
        for (int e = 0; e < 256; ++e) s += hb[tid*256 + e] * att[e];
        sc[tid] = s;
    }
    __syncthreads();
    if (tid == 0){
        float m = -1e30f;
        for (int t = 0; t < AL; ++t) m = fmaxf(m, sc[t]);
        float s = 0.f;
        for (int t = 0; t < AL; ++t){ sw[t] = __expf(sc[t] - m); s += sw[t]; }
        float inv = 1.f / s;
        for (int t = 0; t < AL; ++t) sw[t] *= inv;
    }
    __syncthreads();
    float o = 0.f;
    for (int t = 0; t < AL; ++t) o += sw[t] * hb[t*256 + tid];
    a_emb[((size_t)b*3 + c) * 256 + tid] = o;
}

// ---------------------------------------------------------------------------
// additive attention: score[p] = sum_e v[e]*tanh(Aq[b,p,e] + sign*Ap[b,q,e]);
__global__ __launch_bounds__(256) void k_att_cm(const float* __restrict__ Aq,
                                                const float* __restrict__ Ap,
                                                const float* __restrict__ v,
                                                const float* __restrict__ vals,
                                                float sign, int outOff,
                                                float* __restrict__ agg){
    int b = blockIdx.x >> 7, q = blockIdx.x & 127, tid = threadIdx.x;
    __shared__ float apv[EE], vcv[EE], sc[256], red[256];
    if (tid < EE){
        apv[tid] = sign * Ap[((size_t)b*QL + q)*EE + tid];
        vcv[tid] = v[tid];
    }
    __syncthreads();
    const float* aqp = Aq + ((size_t)b*PL + tid)*EE;
    float s = 0.f;
    #pragma unroll 4
    for (int e = 0; e < EE; ++e) s += vcv[e] * tanh_fast(aqp[e] + apv[e]);
    sc[tid] = s;
    __syncthreads();
    softmax256(sc, red, tid);
    float o = 0.f;
    const float* vb = vals + (size_t)b*PL*256;
    for (int p = 0; p < PL; ++p) o += sc[p] * vb[(size_t)p*256 + tid];
    agg[((size_t)b*QL + q)*1536 + outOff + tid] = o;
}

// bilinear attention + fused hp copy into agg[...,0:256]
__global__ __launch_bounds__(256) void k_att_b(const float* __restrict__ Bq,
                                               const float* __restrict__ hp,
                                               const float* __restrict__ hq,
                                               float* __restrict__ agg){
    int b = blockIdx.x >> 7, q = blockIdx.x & 127, tid = threadIdx.x;
    __shared__ float xq[256], sc[256], red[256];
    float xv = hp[((size_t)b*QL + q)*256 + tid];
    xq[tid] = xv;
    agg[((size_t)b*QL + q)*1536 + tid] = xv;   // fused copy_hp
    __syncthreads();
    const float* bq = Bq + ((size_t)b*PL + tid)*256;
    float s = 0.f;
    #pragma unroll 4
    for (int e = 0; e < 256; ++e) s += xq[e] * bq[e];
    sc[tid] = s;
    __syncthreads();
    softmax256(sc, red, tid);
    float o = 0.f;
    const float* hqb = hq + (size_t)b*PL*256;
    for (int p = 0; p < PL; ++p) o += sc[p] * hqb[(size_t)p*256 + tid];
    agg[((size_t)b*QL + q)*1536 + 1024 + tid] = o;
}

// ---------------------------------------------------------------------------
// MFMA dms partial scores over a 64-row e-half:
// sc[b,q,p] = sum_{e in half} v[e]*tanh( sum_f W[e,f]*kv[b,p,f]*xq[b,q,f] )
// Caller passes Wmat/v already offset to the half. bfr[4][8]=128 VGPRs.
__global__ __launch_bounds__(256, 1) void k_dms_mfma(const float* __restrict__ kv, int P,
                                                     const float* __restrict__ Wmat,
                                                     const float* __restrict__ v,
                                                     const float* __restrict__ xsrc,
                                                     int qPerBlock,
                                                     float* __restrict__ sc){
    int pt = blockIdx.x, qc = blockIdx.y, b = blockIdx.z;
    int tid = threadIdx.x;
    int w = tid >> 6, lane = tid & 63, m = lane & 15, quad = lane >> 4;

    __shared__ unsigned Hlds[64 * 132];
    __shared__ float hpq[256];

    {
        const float* hr = kv + ((size_t)b * P + pt * 64 + w * 16 + m) * 256;
        unsigned* dst = &Hlds[(w * 16 + m) * 132];
        #pragma unroll
        for (int k0 = 0; k0 < 8; ++k0){
            const float* p0 = hr + k0 * 32 + quad * 8;
            float4 x0 = *(const float4*)p0;
            float4 x1 = *(const float4*)(p0 + 4);
            uint4 u;
            u.x = pk2(x0.x, x0.y); u.y = pk2(x0.z, x0.w);
            u.z = pk2(x1.x, x1.y); u.w = pk2(x1.z, x1.w);
            *(uint4*)&dst[k0 * 16 + quad * 4] = u;
        }
    }

    bf16x8 bfr[4][8];
    #pragma unroll
    for (int et = 0; et < 4; ++et){
        const float* wr = Wmat + (size_t)(et * 16 + m) * 256;
        #pragma unroll
        for (int k0 = 0; k0 < 8; ++k0){
            const float* p0 = wr + k0 * 32 + quad * 8;
            float4 x0 = *(const float4*)p0;
            float4 x1 = *(const float4*)(p0 + 4);
            U4 uu;
            uu.u.x = pk2(x0.x, x0.y); uu.u.y = pk2(x0.z, x0.w);
            uu.u.z = pk2(x1.x, x1.y); uu.u.w = pk2(x1.z, x1.w);
            bfr[et][k0] = uu.v;
        }
    }
    float vreg[4];
    #pragma unroll
    for (int et = 0; et < 4; ++et) vreg[et] = v[et * 16 + m];

    __syncthreads();

    const unsigned* hrow = &Hlds[(w * 16 + m) * 132];

    for (int qi = 0; qi < qPerBlock; ++qi){
        int q = qc * qPerBlock + qi;
        __syncthreads();
        hpq[tid] = xsrc[((size_t)b * QL + q) * 256 + tid];
        __syncthreads();

        bf16x8 afr[8];
        #pragma unroll
        for (int k0 = 0; k0 < 8; ++k0){
            uint4 hv = *(const uint4*)&hrow[k0 * 16 + quad * 4];
            const float* hf = &hpq[k0 * 32 + quad * 8];
            float f0 = __uint_as_float(hv.x << 16)         * hf[0];
            float f1 = __uint_as_float(hv.x & 0xffff0000u) * hf[1];
            float f2 = __uint_as_float(hv.y << 16)         * hf[2];
            float f3 = __uint_as_float(hv.y & 0xffff0000u) * hf[3];
            float f4 = __uint_as_float(hv.z << 16)         * hf[4];
            float f5 = __uint_as_float(hv.z & 0xffff0000u) * hf[5];
            float f6 = __uint_as_float(hv.w << 16)         * hf[6];
            float f7 = __uint_as_float(hv.w & 0xffff0000u) * hf[7];
            U4 uu;
            uu.u.x = pk2(f0, f1); uu.u.y = pk2(f2, f3);
            uu.u.z = pk2(f4, f5); uu.u.w = pk2(f6, f7);
            afr[k0] = uu.v;
        }

        f32x4 acc[4];
        #pragma unroll
        for (int et = 0; et < 4; ++et){
            acc[et][0] = 0.f; acc[et][1] = 0.f; acc[et][2] = 0.f; acc[et][3] = 0.f;
        }
        #pragma unroll
        for (int k0 = 0; k0 < 8; ++k0)
            #pragma unroll
            for (int et = 0; et < 4; ++et)
                acc[et] = __builtin_amdgcn_mfma_f32_16x16x32_bf16(afr[k0], bfr[et][k0], acc[et], 0, 0, 0);

        float p0 = 0.f, p1 = 0.f, p2 = 0.f, p3 = 0.f;
        #pragma unroll
        for (int et = 0; et < 4; ++et){
            p0 += vreg[et] * tanh_fast(acc[et][0]);
            p1 += vreg[et] * tanh_fast(acc[et][1]);
            p2 += vreg[et] * tanh_fast(acc[et][2]);
            p3 += vreg[et] * tanh_fast(acc[et][3]);
        }
        p0 = dpp_xadd12(p0); p0 += __shfl_xor(p0, 4); p0 += __shfl_xor(p0, 8);
        p1 = dpp_xadd12(p1); p1 += __shfl_xor(p1, 4); p1 += __shfl_xor(p1, 8);
        p2 = dpp_xadd12(p2); p2 += __shfl_xor(p2, 4); p2 += __shfl_xor(p2, 8);
        p3 = dpp_xadd12(p3); p3 += __shfl_xor(p3, 4); p3 += __shfl_xor(p3, 8);
        if (m == 0){
            float4 o = make_float4(p0, p1, p2, p3);
            *(float4*)&sc[((size_t)b * QL + q) * P + pt * 64 + w * 16 + quad * 4] = o;
        }
    }
}

// softmax over summed half-scores + weighted sum
__global__ __launch_bounds__(256) void k_att_apply(const float* __restrict__ sc0,
                                                   const float* __restrict__ sc1,
                                                   const float* __restrict__ kv, int P,
                                                   int outOff, float* __restrict__ agg){
    int b = blockIdx.x >> 7, q = blockIdx.x & 127, tid = threadIdx.x;
    __shared__ float w[256], red[256];
    size_t si = ((size_t)b*QL + q)*P + tid;
    w[tid] = (tid < P) ? (sc0[si] + sc1[si]) : -1e30f;
    __syncthreads();
    softmax256(w, red, tid);
    const float* kvb = kv + (size_t)b*P*256;
    float o = 0.f;
    #pragma unroll 4
    for (int p = 0; p < P; ++p) o += w[p] * kvb[(size_t)p*256 + tid];
    agg[((size_t)b*QL + q)*1536 + outOff + tid] = o;
}

// ---------------------------------------------------------------------------
__global__ __launch_bounds__(256) void k_q_att(const float* __restrict__ Cq,
                                               const float* __restrict__ vq,
                                               const float* __restrict__ hq,
                                               float* __restrict__ rq){
    int b = blockIdx.x, tid = threadIdx.x;
    __shared__ float vv[EE], sc[256], red[256];
    if (tid < EE) vv[tid] = vq[tid];
    __syncthreads();
    const float* cb = Cq + ((size_t)b*PL + tid)*EE;
    float s = 0.f;
    #pragma unroll 4
    for (int e = 0; e < EE; ++e) s += vv[e] * tanh_fast(cb[e]);
    sc[tid] = s;
    __syncthreads();
    softmax256(sc, red, tid);
    float o = 0.f;
    const float* hqb = hq + (size_t)b*PL*256;
    for (int p = 0; p < PL; ++p) o += sc[p] * hqb[(size_t)p*256 + tid];
    rq[(size_t)b*256 + tid] = o;
}

__global__ __launch_bounds__(256) void k_p_att(const float* __restrict__ Gp,
                                               const float* __restrict__ vp,
                                               const float* __restrict__ rqW,
                                               const float* __restrict__ agg_rep,
                                               float* __restrict__ rp){
    int b = blockIdx.x, tid = threadIdx.x;
    __shared__ float vv[EE], rw[EE], sc[256], red[256];
    if (tid < EE){
        vv[tid] = vp[tid];
        rw[tid] = rqW[(size_t)b*EE + tid];
    }
    if (tid >= 128) sc[tid] = -1e30f;
    __syncthreads();
    if (tid < QL){
        const float* gp = Gp + ((size_t)b*QL + tid)*EE;
        float s = 0.f;
        for (int e = 0; e < EE; ++e) s += vv[e] * (gp[e] + rw[e]);
        sc[tid] = s;
    }
    __syncthreads();
    softmax256(sc, red, tid);
    float o = 0.f;
    const float* ab = agg_rep + (size_t)b*QL*256;
    for (int q = 0; q < QL; ++q) o += sc[q] * ab[(size_t)q*256 + tid];
    rp[(size_t)b*256 + tid] = o;
}

__global__ __launch_bounds__(256) void k_final(const float* __restrict__ rp,
                                               const float* __restrict__ Wpred,
                                               const float* __restrict__ a_emb,
                                               float* __restrict__ out){
    int b = blockIdx.x, tid = threadIdx.x;
    __shared__ float rpv[256], enc[256];
    rpv[tid] = rp[(size_t)b*256 + tid];
    __syncthreads();
    const float* wr = Wpred + (size_t)tid*256;
    float s = 0.f;
    #pragma unroll 4
    for (int e = 0; e < 256; ++e) s += wr[e] * rpv[e];
    enc[tid] = (s > 0.f) ? s : 0.01f * s;
    __syncthreads();
    if (tid < 3){
        const float* ae = a_emb + ((size_t)b*3 + tid)*256;
        float o = 0.f;
        for (int e = 0; e < 256; ++e) o += ae[e] * enc[e];
        out[b*3 + tid] = o;
    }
}

// ---------------------------------------------------------------------------
extern "C" void kernel_launch(void* const* d_in, const int* in_sizes, int n_in,
                              void* d_out, int out_size, void* d_ws, size_t ws_size,
                              hipStream_t stream){
    const float* emb   = (const float*)d_in[0];
    const float* a_att = (const float*)d_in[1];
    const float* Wc1   = (const float*)d_in[2];
    const float* Wc2   = (const float*)d_in[3];
    const float* vc    = (const float*)d_in[4];
    const float* Wb    = (const float*)d_in[5];
    const float* Wd    = (const float*)d_in[6];
    const float* vd    = (const float*)d_in[7];
    const float* Wm    = (const float*)d_in[8];
    const float* vm    = (const float*)d_in[9];
    const float* Ws    = (const float*)d_in[10];
    const float* vs    = (const float*)d_in[11];
    const float* Wq    = (const float*)d_in[12];
    const float* vq    = (const float*)d_in[13];
    const float* Wp1   = (const float*)d_in[14];
    const float* Wp2   = (const float*)d_in[15];
    const float* vp    = (const float*)d_in[16];
    const float* Wpred = (const float*)d_in[17];
    const float* q_Wih = (const float*)d_in[18];
    const float* q_Whh = (const float*)d_in[19];
    const float* q_bih = (const float*)d_in[20];
    const float* q_bhh = (const float*)d_in[21];
    const float* p_Wih = (const float*)d_in[22];
    const float* p_Whh = (const float*)d_in[23];
    const float* p_bih = (const float*)d_in[24];
    const float* p_bhh = (const float*)d_in[25];
    const float* a_Wih = (const float*)d_in[26];
    const float* a_Whh = (const float*)d_in[27];
    const float* a_bih = (const float*)d_in[28];
    const float* a_bhh = (const float*)d_in[29];
    const float* g_Wih = (const float*)d_in[30];
    const float* g_Whh = (const float*)d_in[31];
    const float* g_bih = (const float*)d_in[32];
    const float* g_bhh = (const float*)d_in[33];
    const int* query   = (const int*)d_in[34];
    const int* passage = (const int*)d_in[35];
    const int* cneg    = (const int*)d_in[36];
    const int* cpos    = (const int*)d_in[37];
    const int* cna     = (const int*)d_in[38];

    float* ws = (float*)d_ws;

    // 1. embedding gathers (fused)
    k_gather_all<<<3312, 256, 0, stream>>>(passage, query, cneg, cpos, cna, emb, ws);

    // 2. input preactivations (x @ Wih^T + bih)
    k_gemm_v2<<<dim3(6,32,2), 256, 0, stream>>>(ws+O_XPASS, q_Wih, q_bih, ws+O_PREQ,
                                                2048, 384, 256, 98304LL, 786432LL, 384LL, 0);
    k_gemm_v2<<<dim3(6,16,2), 256, 0, stream>>>(ws+O_XQUERY, p_Wih, p_bih, ws+O_PREP,
                                                1024, 384, 256, 98304LL, 393216LL, 384LL, 0);
    k_gemm_v2<<<dim3(6,2,6), 256, 0, stream>>>(ws+O_XCAND, a_Wih, a_bih, ws+O_PREA,
                                               80, 384, 256, 98304LL, 30720LL, 384LL, 1);

    // 3. forward GRU scans (q || p || cand in one dispatch)
    k_gru_fwd<<<80, 512, 0, stream>>>(ws, q_Whh, q_bhh, p_Whh, p_bhh, a_Whh, a_bhh);

    // 4. candidate pooling
    k_cand_att<<<24, 256, 0, stream>>>(ws+O_HCAND, a_att, ws+O_AEMB);

    // 5. projection GEMMs
    k_gemm_v2<<<dim3(2,32,1), 256, 0, stream>>>(ws+O_HQ, Wc1, nullptr, ws+O_AQ, 2048,128,256, 0,0,0, 0);
    k_gemm_v2<<<dim3(2,16,1), 256, 0, stream>>>(ws+O_HP, Wc2, nullptr, ws+O_AP, 1024,128,256, 0,0,0, 0);
    k_gemm_v2<<<dim3(4,32,1), 256, 0, stream>>>(ws+O_HQ, Wb,  nullptr, ws+O_BQ, 2048,256,256, 0,0,0, 0);
    k_gemm_v2<<<dim3(2,32,1), 256, 0, stream>>>(ws+O_HQ, Wq,  nullptr, ws+O_CQ, 2048,128,256, 0,0,0, 0);

    // 6. attention blocks -> agg slices
    k_att_cm<<<1024, 256, 0, stream>>>(ws+O_AQ, ws+O_AP, vc, ws+O_HQ, 1.f, 512, ws+O_AGG);
    k_att_b<<<1024, 256, 0, stream>>>(ws+O_BQ, ws+O_HP, ws+O_HQ, ws+O_AGG);
    // dot (qtd -> 768): two e-half dispatches, summed in apply
    k_dms_mfma<<<dim3(4,8,8), 256, 0, stream>>>(ws+O_HQ, 256, Wd,          vd,    ws+O_HP, 16, ws+O_SCD0);
    k_dms_mfma<<<dim3(4,8,8), 256, 0, stream>>>(ws+O_HQ, 256, Wd + 16384,  vd+64, ws+O_HP, 16, ws+O_SCD1);
    k_att_apply<<<1024, 256, 0, stream>>>(ws+O_SCD0, ws+O_SCD1, ws+O_HQ, 256, 768, ws+O_AGG);
    // minus, factored (qtm -> 1280)
    k_gemm_v2<<<dim3(2,32,1), 256, 0, stream>>>(ws+O_HQ, Wm, nullptr, ws+O_MQ, 2048,128,256, 0,0,0, 0);
    k_gemm_v2<<<dim3(2,16,1), 256, 0, stream>>>(ws+O_HP, Wm, nullptr, ws+O_MP, 1024,128,256, 0,0,0, 0);
    k_att_cm<<<1024, 256, 0, stream>>>(ws+O_MQ, ws+O_MP, vm, ws+O_HQ, -1.f, 1280, ws+O_AGG);
    // self (qts -> 256): two e-half dispatches
    k_dms_mfma<<<dim3(2,16,8), 256, 0, stream>>>(ws+O_HP, 128, Ws,         vs,    ws+O_HP, 8, ws+O_SCS0);
    k_dms_mfma<<<dim3(2,16,8), 256, 0, stream>>>(ws+O_HP, 128, Ws + 16384, vs+64, ws+O_HP, 8, ws+O_SCS1);
    k_att_apply<<<1024, 256, 0, stream>>>(ws+O_SCS0, ws+O_SCS1, ws+O_HP, 128, 256, ws+O_AGG);

    // 7. aggregation bigru
    k_gemm_v2<<<dim3(6,16,2), 256, 0, stream>>>(ws+O_AGG, g_Wih, g_bih, ws+O_PREG,
                                                1024, 384, 1536, 589824LL, 393216LL, 384LL, 0);
    k_gru_scan<<<16, 512, 0, stream>>>(ws+O_PREG, g_Whh, g_bhh, ws+O_AGGREP, 128);

    // 8. pooling + prediction
    k_q_att<<<8, 256, 0, stream>>>(ws+O_CQ, vq, ws+O_HQ, ws+O_RQ);
    k_gemm_v2<<<dim3(2,16,1), 256, 0, stream>>>(ws+O_AGGREP, Wp1, nullptr, ws+O_GP, 1024,128,256, 0,0,0, 0);
    k_gemm_v2<<<dim3(2,1,1),  256, 0, stream>>>(ws+O_RQ, Wp2, nullptr, ws+O_RQW, 8,128,256, 0,0,0, 0);
    k_p_att<<<8, 256, 0, stream>>>(ws+O_GP, vp, ws+O_RQW, ws+O_AGGREP, ws+O_RP);
    k_final<<<8, 256, 0, stream>>>(ws+O_RP, Wpred, ws+O_AEMB, (float*)d_out);
}